// Round 1
// baseline (957.389 us; speedup 1.0000x reference)
//
#include <hip/hip_runtime.h>
#include <math.h>

#define SZ 2097152  // 32768 rows * 64 d, per tensor slice
#define COVS (1.0f/8.000001f)

__device__ __forceinline__ unsigned short f2b(float x) {
  unsigned int u = __float_as_uint(x);
  u = (u + 0x7fffu + ((u >> 16) & 1u)) >> 16;  // RNE
  return (unsigned short)u;
}
#define B2FL(u) __uint_as_float(((unsigned)(u)) << 16)
#define B2FH(u) __uint_as_float(((unsigned)(u)) & 0xffff0000u)

__device__ __forceinline__ float wredsum(float v) {
  #pragma unroll
  for (int o = 32; o; o >>= 1) v += __shfl_xor(v, o);
  return v;
}

// ---------------- K0: zero stat accumulators ----------------
__global__ void k_zero(double* __restrict__ stats) {
  int i = threadIdx.x;
  if (i < 72) stats[i] = 0.0;
}

// ---------------- K1: f = LN(x) @ W_in, for q/k/v ----------------
// grid (256, 3), block 256. 16 rows per block. F layout: [t][h][b][n][d] fp32
__global__ __launch_bounds__(256) void k_proj(
    const float* __restrict__ q, const float* __restrict__ k, const float* __restrict__ v,
    const float* __restrict__ ln_g, const float* __restrict__ ln_b,
    const float* __restrict__ W, float* __restrict__ F)
{
  __shared__ float xn[16][513];
  const int t = blockIdx.y;
  const float* x = (t == 0) ? q : (t == 1) ? k : v;
  const int row0 = blockIdx.x * 16;
  const int tid = threadIdx.x;
  const int wv = tid >> 6, lane = tid & 63;
  #pragma unroll
  for (int rr = 0; rr < 4; ++rr) {
    const int r = wv * 4 + rr;
    const float* xr = x + (size_t)(row0 + r) * 512;
    float vals[8];
    float s = 0.f, ss = 0.f;
    #pragma unroll
    for (int u = 0; u < 8; ++u) { float xv = xr[lane + (u << 6)]; vals[u] = xv; s += xv; ss += xv * xv; }
    #pragma unroll
    for (int o = 32; o; o >>= 1) { s += __shfl_xor(s, o); ss += __shfl_xor(ss, o); }
    const float mu = s * (1.f / 512.f);
    const float rstd = rsqrtf(ss * (1.f / 512.f) - mu * mu + 1e-5f);
    #pragma unroll
    for (int u = 0; u < 8; ++u) {
      int i = lane + (u << 6);
      xn[r][i] = (vals[u] - mu) * rstd * ln_g[i] + ln_b[i];
    }
  }
  __syncthreads();
  const int rg = tid >> 6, c = tid & 63;
  float acc[4][8];
  #pragma unroll
  for (int a = 0; a < 4; ++a) {
    #pragma unroll
    for (int b = 0; b < 8; ++b) acc[a][b] = 0.f;
  }
  for (int i = 0; i < 512; ++i) {
    const float a0 = xn[rg * 4 + 0][i], a1 = xn[rg * 4 + 1][i];
    const float a2 = xn[rg * 4 + 2][i], a3 = xn[rg * 4 + 3][i];
    const float* wr = W + (size_t)i * 512 + c;
    #pragma unroll
    for (int cc = 0; cc < 8; ++cc) {
      const float wvv = wr[cc << 6];
      acc[0][cc] += a0 * wvv; acc[1][cc] += a1 * wvv;
      acc[2][cc] += a2 * wvv; acc[3][cc] += a3 * wvv;
    }
  }
  float* Fo = F + (size_t)t * SZ;
  #pragma unroll
  for (int rr = 0; rr < 4; ++rr) {
    const int grow = row0 + rg * 4 + rr;
    const int b = grow >> 10, n2 = grow & 1023;
    #pragma unroll
    for (int cc = 0; cc < 8; ++cc) {  // col j = cc*64 + c -> h=cc, d=c
      Fo[(((size_t)(cc * 4 + b) << 10) + n2) * 64 + c] = acc[rr][cc];
    }
  }
}

// ---------------- K2: per-(h,b,d) sums over n, for q (feat) and k (centering) ----------------
// grid (32, 2), block 256
__global__ void k_colsum(const float* __restrict__ F, float* __restrict__ sums)
{
  const int pair = blockIdx.x, t = blockIdx.y;
  const float* f = F + (size_t)t * SZ + (size_t)pair * 65536;
  const int tid = threadIdx.x, d = tid & 63, g = tid >> 6;
  float s = 0.f;
  for (int n = g; n < 1024; n += 4) s += f[((size_t)n << 6) + d];
  __shared__ float red[4][64];
  red[g][d] = s;
  __syncthreads();
  if (g == 0) sums[(size_t)t * 2048 + pair * 64 + d] = red[0][d] + red[1][d] + red[2][d] + red[3][d];
}

// ---------------- K3: derived bf16 arrays ----------------
// grid (8192, 3), block 256 (4 rows/block, one wave per row)
// BF layout (ushort): [0]=fq_n, [SZ]=fk_n, [2SZ]=f_q_c, [3SZ]=f_k_c, [4SZ]=f_v
__global__ void k_derived(const float* __restrict__ F, const float* __restrict__ sums,
                          unsigned short* __restrict__ BF)
{
  const int t = blockIdx.y;
  const int tid = threadIdx.x, wv = tid >> 6, lane = tid & 63;
  const int row = blockIdx.x * 4 + wv;
  const float val = F[(size_t)t * SZ + ((size_t)row << 6) + lane];
  if (t == 2) { BF[(size_t)4 * SZ + ((size_t)row << 6) + lane] = f2b(val); return; }
  float s = val, ss = val * val;
  #pragma unroll
  for (int o = 32; o; o >>= 1) { s += __shfl_xor(s, o); ss += __shfl_xor(ss, o); }
  const float inv = 1.f / (sqrtf(ss) + 1e-8f);
  const float ctr = (t == 0) ? s * (1.f / 64.f)
                             : sums[2048 + (row >> 10) * 64 + lane] * (1.f / 1024.f);
  BF[(size_t)t * SZ + ((size_t)row << 6) + lane] = f2b(val * inv);
  BF[(size_t)(2 + t) * SZ + ((size_t)row << 6) + lane] = f2b(val - ctr);
}

// swizzled LDS index for (row r, 8-elem chunk c): spreads stride-row b64/b128 reads
__device__ __forceinline__ int lidx(int r, int c) { return (r << 6) + (((c) ^ (r & 7)) << 3); }

// ---------------- K5: score stats pass ----------------
// grid (16 rowtiles, 32 pairs), block 256. 64 q-rows x 64 keys per tile, 4r x 4k per thread.
// stats[h*9 + i]: 0=SX 1=SXX 2=SC 3=SCC 4=SXC 5=SZ 6=SZZ 7=SZ*SXrow 8=SZ*SCrow
__global__ __launch_bounds__(256) void k_stats(const unsigned short* __restrict__ BF,
                                               double* __restrict__ stats)
{
  __shared__ __align__(16) unsigned short qn_s[4096], qc_s[4096], kn_s[4096], kc_s[4096];
  __shared__ float part[9][4];
  const int pair = blockIdx.y, h = pair >> 2;
  const int r0 = blockIdx.x * 64;
  const int tid = threadIdx.x;
  const int wv = tid >> 6, lane = tid & 63;
  const size_t pb = (size_t)pair * 65536;
  const unsigned short* fqn = BF + pb;
  const unsigned short* fkn = BF + (size_t)SZ + pb;
  const unsigned short* fqc = BF + (size_t)2 * SZ + pb;
  const unsigned short* fkc = BF + (size_t)3 * SZ + pb;

  for (int u = tid; u < 512; u += 256) {
    const int r = u >> 3, c = u & 7;
    const int li = lidx(r, c);
    const size_t gi = ((size_t)(r0 + r) << 6) + (c << 3);
    *reinterpret_cast<uint4*>(&qn_s[li]) = *reinterpret_cast<const uint4*>(&fqn[gi]);
    *reinterpret_cast<uint4*>(&qc_s[li]) = *reinterpret_cast<const uint4*>(&fqc[gi]);
  }

  const int tg = tid >> 4, kg = tid & 15;
  float sx = 0.f, sxx = 0.f, scv = 0.f, scc = 0.f, sxc = 0.f;
  float rxs[4] = {0, 0, 0, 0}, rcs[4] = {0, 0, 0, 0}, rms[4] = {0, 0, 0, 0};

  for (int m0 = 0; m0 < 1024; m0 += 64) {
    __syncthreads();
    for (int u = tid; u < 512; u += 256) {
      const int r = u >> 3, c = u & 7;
      const int li = lidx(r, c);
      const size_t gi = ((size_t)(m0 + r) << 6) + (c << 3);
      *reinterpret_cast<uint4*>(&kn_s[li]) = *reinterpret_cast<const uint4*>(&fkn[gi]);
      *reinterpret_cast<uint4*>(&kc_s[li]) = *reinterpret_cast<const uint4*>(&fkc[gi]);
    }
    __syncthreads();

    float dn[4][4], dc[4][4];
    #pragma unroll
    for (int a = 0; a < 4; ++a) {
      #pragma unroll
      for (int b = 0; b < 4; ++b) { dn[a][b] = 0.f; dc[a][b] = 0.f; }
    }
    for (int ch = 0; ch < 16; ++ch) {
      const int c8 = ch >> 1, h4 = (ch & 1) << 2;
      float qnf[4][4], qcf[4][4];
      #pragma unroll
      for (int rr = 0; rr < 4; ++rr) {
        const int r = (tg << 2) | rr;
        const int li = lidx(r, c8) + h4;
        const uint2 un = *reinterpret_cast<const uint2*>(&qn_s[li]);
        const uint2 uc = *reinterpret_cast<const uint2*>(&qc_s[li]);
        qnf[rr][0] = B2FL(un.x); qnf[rr][1] = B2FH(un.x); qnf[rr][2] = B2FL(un.y); qnf[rr][3] = B2FH(un.y);
        qcf[rr][0] = B2FL(uc.x); qcf[rr][1] = B2FH(uc.x); qcf[rr][2] = B2FL(uc.y); qcf[rr][3] = B2FH(uc.y);
      }
      #pragma unroll
      for (int kk = 0; kk < 4; ++kk) {
        const int m = (kg << 2) | kk;
        const int li = lidx(m, c8) + h4;
        const uint2 un = *reinterpret_cast<const uint2*>(&kn_s[li]);
        const uint2 uc = *reinterpret_cast<const uint2*>(&kc_s[li]);
        const float knf[4] = {B2FL(un.x), B2FH(un.x), B2FL(un.y), B2FH(un.y)};
        const float kcf[4] = {B2FL(uc.x), B2FH(uc.x), B2FL(uc.y), B2FH(uc.y)};
        #pragma unroll
        for (int rr = 0; rr < 4; ++rr) {
          #pragma unroll
          for (int dd = 0; dd < 4; ++dd) {
            dn[rr][kk] += qnf[rr][dd] * knf[dd];
            dc[rr][kk] += qcf[rr][dd] * kcf[dd];
          }
        }
      }
    }
    #pragma unroll
    for (int rr = 0; rr < 4; ++rr) {
      #pragma unroll
      for (int kk = 0; kk < 4; ++kk) {
        const float X = fminf(fmaxf(dn[rr][kk], -0.98f), 0.98f);
        const float cv = dc[rr][kk] * COVS;
        sx += X; sxx += X * X; scv += cv; scc += cv * cv; sxc += X * cv;
        rxs[rr] += X; rcs[rr] += cv; rms[rr] += fmaxf(0.01f - X, 0.f);
      }
    }
  }
  const float g0 = wredsum(sx), g1 = wredsum(sxx), g2 = wredsum(scv), g3 = wredsum(scc), g4 = wredsum(sxc);
  #pragma unroll
  for (int rr = 0; rr < 4; ++rr) {
    #pragma unroll
    for (int o = 1; o < 16; o <<= 1) {
      rxs[rr] += __shfl_xor(rxs[rr], o);
      rcs[rr] += __shfl_xor(rcs[rr], o);
      rms[rr] += __shfl_xor(rms[rr], o);
    }
  }
  float z1 = 0.f, z2 = 0.f, z3 = 0.f, z4 = 0.f;
  if (kg == 0) {
    #pragma unroll
    for (int rr = 0; rr < 4; ++rr) {
      const float Z = rms[rr] * (1.f / 1024.f);
      z1 += Z; z2 += Z * Z; z3 += Z * rxs[rr]; z4 += Z * rcs[rr];
    }
  }
  z1 = wredsum(z1); z2 = wredsum(z2); z3 = wredsum(z3); z4 = wredsum(z4);
  if (lane == 0) {
    part[0][wv] = g0; part[1][wv] = g1; part[2][wv] = g2; part[3][wv] = g3; part[4][wv] = g4;
    part[5][wv] = z1; part[6][wv] = z2; part[7][wv] = z3; part[8][wv] = z4;
  }
  __syncthreads();
  if (tid == 0) {
    #pragma unroll
    for (int i = 0; i < 9; ++i) {
      const double s = (double)part[i][0] + part[i][1] + part[i][2] + part[i][3];
      atomicAdd(&stats[h * 9 + i], s);
    }
  }
}

// ---------------- K6: weight-MLP + global std finalize -> per-head coefs ----------------
__global__ __launch_bounds__(256) void k_finalize(
    const float* __restrict__ sums, const double* __restrict__ stats,
    const float* __restrict__ W1, const float* __restrict__ b1,
    const float* __restrict__ lng, const float* __restrict__ lnb,
    const float* __restrict__ W2, const float* __restrict__ b2,
    const float* __restrict__ W3, const float* __restrict__ b3,
    const float* __restrict__ w_temp, float* __restrict__ coefs)
{
  __shared__ float feat[128], y1[192], h1[192], y2[128];
  __shared__ float muvar[2];
  __shared__ float wsm[8][3];
  const int tid = threadIdx.x;
  for (int h = 0; h < 8; ++h) {
    if (tid < 64) {
      float sq = 0.f, sk = 0.f;
      for (int b = 0; b < 4; ++b) {
        sq += sums[(h * 4 + b) * 64 + tid];
        sk += sums[2048 + (h * 4 + b) * 64 + tid];
      }
      feat[tid] = sq * (1.f / 4096.f);
      feat[64 + tid] = sk * (1.f / 4096.f);
    }
    __syncthreads();
    if (tid < 192) {
      float a = b1[tid];
      for (int i = 0; i < 128; ++i) a += feat[i] * W1[i * 192 + tid];
      y1[tid] = a;
    }
    __syncthreads();
    if (tid == 0) {
      float s = 0.f, ss = 0.f;
      for (int i = 0; i < 192; ++i) { const float vv = y1[i]; s += vv; ss += vv * vv; }
      const float mu = s / 192.f;
      muvar[0] = mu; muvar[1] = ss / 192.f - mu * mu;
    }
    __syncthreads();
    if (tid < 192) {
      const float vv = (y1[tid] - muvar[0]) * rsqrtf(muvar[1] + 1e-5f) * lng[tid] + lnb[tid];
      h1[tid] = fmaxf(vv, 0.f);
    }
    __syncthreads();
    if (tid < 128) {
      float a = b2[tid];
      for (int i = 0; i < 192; ++i) a += h1[i] * W2[i * 128 + tid];
      y2[tid] = fmaxf(a, 0.f);
    }
    __syncthreads();
    if (tid == 0) {
      float l[3];
      for (int c = 0; c < 3; ++c) {
        float a = b3[c];
        for (int i = 0; i < 128; ++i) a += y2[i] * W3[i * 3 + c];
        l[c] = a;
      }
      float mx = fmaxf(l[0], fmaxf(l[1], l[2]));
      float e0 = expf(l[0] - mx), e1 = expf(l[1] - mx), e2 = expf(l[2] - mx);
      float se = e0 + e1 + e2;
      const float p0 = e0 / se, p1 = e1 / se, p2 = e2 / se;
      const float wt = fminf(fmaxf(w_temp[0], 0.05f), 3.f);
      const float q0 = p0 / wt, q1 = p1 / wt, q2 = p2 / wt;
      mx = fmaxf(q0, fmaxf(q1, q2));
      e0 = expf(q0 - mx); e1 = expf(q1 - mx); e2 = expf(q2 - mx);
      se = e0 + e1 + e2;
      float w0 = e0 / se, w1 = e1 / se, w2 = e2 / se;
      w0 = fminf(fmaxf(w0, 0.05f), 0.85f);
      w1 = fminf(fmaxf(w1, 0.05f), 0.85f);
      w2 = fminf(fmaxf(w2, 0.05f), 0.85f);
      const float swt = w0 + w1 + w2;
      wsm[h][0] = w0 / swt; wsm[h][1] = w1 / swt; wsm[h][2] = w2 / swt;
    }
    __syncthreads();
  }
  if (tid == 0) {
    const double n = 33554432.0, M = 1024.0;
    double S[8][9], T[9];
    for (int i = 0; i < 9; ++i) T[i] = 0.0;
    for (int h = 0; h < 8; ++h)
      for (int i = 0; i < 9; ++i) { S[h][i] = stats[h * 9 + i]; T[i] += S[h][i]; }
    const double cos_norm = sqrt(fmax((T[1] - T[0] * T[0] / n) / (n - 1.0), 0.0)) + 1e-6;
    const double health = sqrt(fmax((T[3] - T[2] * T[2] / n) / (n - 1.0), 0.0));
    const double base = 0.001 / 1024.0;
    const double reg = (health < 1e-5) ? base * 8.0 : ((health < 1e-3) ? base * 3.0 : base);
    const double cov_norm = reg * health + 1e-6;  // clip(+-30) provably inactive
    const double zvar = (M * T[6] - (M * T[5]) * (M * T[5]) / n) / (n - 1.0);
    const double var_norm = sqrt(fmax(zvar, 0.0)) + 1e-6;
    const double cos_h = fmin(cos_norm, 1.2);
    const double cov_h = fmin(cov_norm * 12.0, 1.2);
    const double var_h = fmin(var_norm * 12.0, 1.2);
    double D1 = 0.0, D2 = 0.0, Ah[8], Bh[8];
    for (int h = 0; h < 8; ++h) {
      const double A = (double)wsm[h][0] * cos_h / cos_norm;
      const double Bc = (double)wsm[h][1] * 0.5 * cov_h / cov_norm * reg;
      const double C = (double)wsm[h][2] * 0.5 * var_h / var_norm;
      Ah[h] = A; Bh[h] = Bc;
      D1 += A * S[h][0] + Bc * S[h][2] + C * M * S[h][5];
      D2 += A * A * S[h][1] + Bc * Bc * S[h][3] + C * C * M * S[h][6]
          + 2.0 * A * Bc * S[h][4] + 2.0 * A * C * S[h][7] + 2.0 * Bc * C * S[h][8];
    }
    const double divv = sqrt(fmax((D2 - D1 * D1 / n) / (n - 1.0), 0.0));
    const double temp = (divv < 5e-6) ? 0.03 : ((divv < 5e-4) ? 0.15 : 0.4);
    for (int h = 0; h < 8; ++h) {
      coefs[h] = (float)(Ah[h] / temp);       // multiplies X
      coefs[8 + h] = (float)(Bh[h] / temp);   // multiplies cov_b
    }
  }
}

// ---------------- K7: attention pass (recompute scores, online softmax, PV) ----------------
// grid (16 rowtiles, 32 pairs), block 256. Var-term is row-constant -> cancels in softmax.
__global__ __launch_bounds__(256) void k_attn(const unsigned short* __restrict__ BF,
                                              const float* __restrict__ coefs,
                                              float* __restrict__ OUTF)
{
  __shared__ __align__(16) unsigned short qn_s[4096], qc_s[4096], kn_s[4096], kc_s[4096], fv_s[4096];
  __shared__ float pexp_s[4160];  // [64][65]
  const int pair = blockIdx.y, h = pair >> 2;
  const int r0 = blockIdx.x * 64;
  const int tid = threadIdx.x;
  const size_t pb = (size_t)pair * 65536;
  const unsigned short* fqn = BF + pb;
  const unsigned short* fkn = BF + (size_t)SZ + pb;
  const unsigned short* fqc = BF + (size_t)2 * SZ + pb;
  const unsigned short* fkc = BF + (size_t)3 * SZ + pb;
  const unsigned short* fvv = BF + (size_t)4 * SZ + pb;
  const float P = coefs[h], Qc = coefs[8 + h];

  for (int u = tid; u < 512; u += 256) {
    const int r = u >> 3, c = u & 7;
    const int li = lidx(r, c);
    const size_t gi = ((size_t)(r0 + r) << 6) + (c << 3);
    *reinterpret_cast<uint4*>(&qn_s[li]) = *reinterpret_cast<const uint4*>(&fqn[gi]);
    *reinterpret_cast<uint4*>(&qc_s[li]) = *reinterpret_cast<const uint4*>(&fqc[gi]);
  }

  const int tg = tid >> 4, kg = tid & 15;
  const int d0 = kg << 2;
  float m_r[4] = {-1e30f, -1e30f, -1e30f, -1e30f};
  float l_r[4] = {0.f, 0.f, 0.f, 0.f};
  float acc[4][4];
  #pragma unroll
  for (int a = 0; a < 4; ++a) {
    #pragma unroll
    for (int b = 0; b < 4; ++b) acc[a][b] = 0.f;
  }

  for (int m0 = 0; m0 < 1024; m0 += 64) {
    __syncthreads();
    for (int u = tid; u < 512; u += 256) {
      const int r = u >> 3, c = u & 7;
      const int li = lidx(r, c);
      const size_t gi = ((size_t)(m0 + r) << 6) + (c << 3);
      *reinterpret_cast<uint4*>(&kn_s[li]) = *reinterpret_cast<const uint4*>(&fkn[gi]);
      *reinterpret_cast<uint4*>(&kc_s[li]) = *reinterpret_cast<const uint4*>(&fkc[gi]);
      *reinterpret_cast<uint4*>(&fv_s[(r << 6) + (c << 3)]) = *reinterpret_cast<const uint4*>(&fvv[gi]);
    }
    __syncthreads();

    float dn[4][4], dc[4][4];
    #pragma unroll
    for (int a = 0; a < 4; ++a) {
      #pragma unroll
      for (int b = 0; b < 4; ++b) { dn[a][b] = 0.f; dc[a][b] = 0.f; }
    }
    for (int ch = 0; ch < 16; ++ch) {
      const int c8 = ch >> 1, h4 = (ch & 1) << 2;
      float qnf[4][4], qcf[4][4];
      #pragma unroll
      for (int rr = 0; rr < 4; ++rr) {
        const int r = (tg << 2) | rr;
        const int li = lidx(r, c8) + h4;
        const uint2 un = *reinterpret_cast<const uint2*>(&qn_s[li]);
        const uint2 uc = *reinterpret_cast<const uint2*>(&qc_s[li]);
        qnf[rr][0] = B2FL(un.x); qnf[rr][1] = B2FH(un.x); qnf[rr][2] = B2FL(un.y); qnf[rr][3] = B2FH(un.y);
        qcf[rr][0] = B2FL(uc.x); qcf[rr][1] = B2FH(uc.x); qcf[rr][2] = B2FL(uc.y); qcf[rr][3] = B2FH(uc.y);
      }
      #pragma unroll
      for (int kk = 0; kk < 4; ++kk) {
        const int m = (kg << 2) | kk;
        const int li = lidx(m, c8) + h4;
        const uint2 un = *reinterpret_cast<const uint2*>(&kn_s[li]);
        const uint2 uc = *reinterpret_cast<const uint2*>(&kc_s[li]);
        const float knf[4] = {B2FL(un.x), B2FH(un.x), B2FL(un.y), B2FH(un.y)};
        const float kcf[4] = {B2FL(uc.x), B2FH(uc.x), B2FL(uc.y), B2FH(uc.y)};
        #pragma unroll
        for (int rr = 0; rr < 4; ++rr) {
          #pragma unroll
          for (int dd = 0; dd < 4; ++dd) {
            dn[rr][kk] += qnf[rr][dd] * knf[dd];
            dc[rr][kk] += qcf[rr][dd] * kcf[dd];
          }
        }
      }
    }
    // scores -> online softmax
    float s[4][4], mxr[4], al[4], ps[4];
    #pragma unroll
    for (int rr = 0; rr < 4; ++rr) {
      #pragma unroll
      for (int kk = 0; kk < 4; ++kk) {
        const float X = fminf(fmaxf(dn[rr][kk], -0.98f), 0.98f);
        const float cv = dc[rr][kk] * COVS;
        s[rr][kk] = P * X + Qc * cv;
      }
      mxr[rr] = fmaxf(fmaxf(s[rr][0], s[rr][1]), fmaxf(s[rr][2], s[rr][3]));
    }
    #pragma unroll
    for (int o = 1; o < 16; o <<= 1) {
      #pragma unroll
      for (int rr = 0; rr < 4; ++rr) mxr[rr] = fmaxf(mxr[rr], __shfl_xor(mxr[rr], o));
    }
    #pragma unroll
    for (int rr = 0; rr < 4; ++rr) {
      const float mn = fmaxf(m_r[rr], mxr[rr]);
      al[rr] = expf(m_r[rr] - mn);
      m_r[rr] = mn;
      ps[rr] = 0.f;
    }
    #pragma unroll
    for (int rr = 0; rr < 4; ++rr) {
      #pragma unroll
      for (int kk = 0; kk < 4; ++kk) {
        const float e = expf(s[rr][kk] - m_r[rr]);
        ps[rr] += e;
        pexp_s[((tg << 2) | rr) * 65 + ((kg << 2) | kk)] = e;
      }
    }
    #pragma unroll
    for (int o = 1; o < 16; o <<= 1) {
      #pragma unroll
      for (int rr = 0; rr < 4; ++rr) ps[rr] += __shfl_xor(ps[rr], o);
    }
    #pragma unroll
    for (int rr = 0; rr < 4; ++rr) {
      l_r[rr] = l_r[rr] * al[rr] + ps[rr];
      #pragma unroll
      for (int dj = 0; dj < 4; ++dj) acc[rr][dj] *= al[rr];
    }
    __syncthreads();
    // PV
    for (int m = 0; m < 64; ++m) {
      const float p0 = pexp_s[((tg << 2) | 0) * 65 + m];
      const float p1 = pexp_s[((tg << 2) | 1) * 65 + m];
      const float p2 = pexp_s[((tg << 2) | 2) * 65 + m];
      const float p3 = pexp_s[((tg << 2) | 3) * 65 + m];
      const uint2 fb = *reinterpret_cast<const uint2*>(&fv_s[(m << 6) + d0]);
      const float f0 = B2FL(fb.x), f1 = B2FH(fb.x), f2 = B2FL(fb.y), f3 = B2FH(fb.y);
      acc[0][0] += p0 * f0; acc[0][1] += p0 * f1; acc[0][2] += p0 * f2; acc[0][3] += p0 * f3;
      acc[1][0] += p1 * f0; acc[1][1] += p1 * f1; acc[1][2] += p1 * f2; acc[1][3] += p1 * f3;
      acc[2][0] += p2 * f0; acc[2][1] += p2 * f1; acc[2][2] += p2 * f2; acc[2][3] += p2 * f3;
      acc[3][0] += p3 * f0; acc[3][1] += p3 * f1; acc[3][2] += p3 * f2; acc[3][3] += p3 * f3;
    }
  }
  #pragma unroll
  for (int rr = 0; rr < 4; ++rr) {
    const float inv = 1.f / l_r[rr];
    #pragma unroll
    for (int dj = 0; dj < 4; ++dj) {
      OUTF[pb + ((size_t)(r0 + ((tg << 2) | rr)) << 6) + d0 + dj] = acc[rr][dj] * inv;
    }
  }
}

// ---------------- K8: out @ W_out + b_out ----------------
__global__ __launch_bounds__(256) void k_out(const float* __restrict__ OUTF,
                                             const float* __restrict__ W,
                                             const float* __restrict__ bias,
                                             float* __restrict__ out)
{
  __shared__ float a[16][513];
  const int row0 = blockIdx.x * 16;
  const int tid = threadIdx.x;
  for (int u = tid; u < 16 * 512; u += 256) {
    const int r = u >> 9, j = u & 511;
    const int grow = row0 + r, b = grow >> 10, n2 = grow & 1023;
    a[r][j] = OUTF[(((size_t)((j >> 6) * 4 + b) << 10) + n2) * 64 + (j & 63)];
  }
  __syncthreads();
  const int rg = tid >> 6, c = tid & 63;
  float acc[4][8];
  #pragma unroll
  for (int a2 = 0; a2 < 4; ++a2) {
    #pragma unroll
    for (int b2 = 0; b2 < 8; ++b2) acc[a2][b2] = 0.f;
  }
  for (int i = 0; i < 512; ++i) {
    const float a0 = a[rg * 4 + 0][i], a1 = a[rg * 4 + 1][i];
    const float a2v = a[rg * 4 + 2][i], a3 = a[rg * 4 + 3][i];
    const float* wr = W + (size_t)i * 512 + c;
    #pragma unroll
    for (int cc = 0; cc < 8; ++cc) {
      const float wvv = wr[cc << 6];
      acc[0][cc] += a0 * wvv; acc[1][cc] += a1 * wvv;
      acc[2][cc] += a2v * wvv; acc[3][cc] += a3 * wvv;
    }
  }
  #pragma unroll
  for (int rr = 0; rr < 4; ++rr) {
    const int grow = row0 + rg * 4 + rr;
    #pragma unroll
    for (int cc = 0; cc < 8; ++cc) {
      out[(size_t)grow * 512 + (cc << 6) + c] = acc[rr][cc] + bias[(cc << 6) + c];
    }
  }
}

extern "C" void kernel_launch(void* const* d_in, const int* in_sizes, int n_in,
                              void* d_out, int out_size, void* d_ws, size_t ws_size,
                              hipStream_t stream) {
  (void)in_sizes; (void)n_in; (void)out_size; (void)ws_size;
  const float* q      = (const float*)d_in[0];
  const float* k      = (const float*)d_in[1];
  const float* v      = (const float*)d_in[2];
  const float* ln_g   = (const float*)d_in[3];
  const float* ln_b   = (const float*)d_in[4];
  const float* W_in   = (const float*)d_in[5];
  const float* wp_W1  = (const float*)d_in[6];
  const float* wp_b1  = (const float*)d_in[7];
  const float* wp_lng = (const float*)d_in[8];
  const float* wp_lnb = (const float*)d_in[9];
  const float* wp_W2  = (const float*)d_in[10];
  const float* wp_b2  = (const float*)d_in[11];
  const float* wp_W3  = (const float*)d_in[12];
  const float* wp_b3  = (const float*)d_in[13];
  const float* w_temp = (const float*)d_in[14];
  const float* W_out  = (const float*)d_in[15];
  const float* b_out  = (const float*)d_in[16];

  float* ws = (float*)d_ws;
  float* F    = ws;                                  // fp32 f_q/f_k/f_v: 3*SZ floats
  float* OUTF = ws + (size_t)3 * SZ;                 // fp32 attn output: SZ floats
  unsigned short* BF = (unsigned short*)(ws + (size_t)4 * SZ);  // 5*SZ ushorts
  float* AUX  = ws + (size_t)13631488;               // = 6.5*SZ
  float* sums  = AUX;                                // 4096 floats (qsum, ksum)
  float* coefs = AUX + 4096;                         // 64 floats
  double* stats = (double*)(AUX + 4160);             // 72 doubles

  k_zero<<<1, 128, 0, stream>>>(stats);
  k_proj<<<dim3(256, 3), 256, 0, stream>>>(q, k, v, ln_g, ln_b, W_in, F);
  k_colsum<<<dim3(32, 2), 256, 0, stream>>>(F, sums);
  k_derived<<<dim3(8192, 3), 256, 0, stream>>>(F, sums, BF);
  k_stats<<<dim3(16, 32), 256, 0, stream>>>(BF, stats);
  k_finalize<<<1, 256, 0, stream>>>(sums, stats, wp_W1, wp_b1, wp_lng, wp_lnb,
                                    wp_W2, wp_b2, wp_W3, wp_b3, w_temp, coefs);
  k_attn<<<dim3(16, 32), 256, 0, stream>>>(BF, coefs, OUTF);
  k_out<<<256, 256, 0, stream>>>(OUTF, W_out, b_out, (float*)d_out);
}

// Round 2
// 427.347 us; speedup vs baseline: 2.2403x; 2.2403x over previous
//
#include <hip/hip_runtime.h>
#include <math.h>

#define SZ 2097152  // 32768 rows * 64 d, per tensor slice
#define COVS (1.0f/8.000001f)

typedef __attribute__((ext_vector_type(8))) short bf16x8;
typedef __attribute__((ext_vector_type(4))) float f32x4;
#define MFMA16(A,B,C) __builtin_amdgcn_mfma_f32_16x16x32_bf16(A,B,C,0,0,0)

__device__ __forceinline__ unsigned short f2b(float x) {
  unsigned int u = __float_as_uint(x);
  u = (u + 0x7fffu + ((u >> 16) & 1u)) >> 16;  // RNE
  return (unsigned short)u;
}
#define B2FL(u) __uint_as_float(((unsigned)(u)) << 16)

__device__ __forceinline__ float wredsum(float v) {
  #pragma unroll
  for (int o = 32; o; o >>= 1) v += __shfl_xor(v, o);
  return v;
}

// swizzled ushort index into a [64 row][64 col] bf16 LDS tile (rows = 8 chunks of 16B)
__device__ __forceinline__ int swz(int r, int c) { return (r << 6) + ((c ^ (r & 7)) << 3); }

__device__ __forceinline__ bf16x8 ldfrag(const unsigned short* s, int row, int chunk) {
  return *reinterpret_cast<const bf16x8*>(&s[swz(row, chunk)]);
}

// ---------------- K0: zero stat accumulators ----------------
__global__ void k_zero(double* __restrict__ stats) {
  int i = threadIdx.x;
  if (i < 72) stats[i] = 0.0;
}

// ---------------- K1: f = LN(x) @ W_in, for q/k/v ----------------
// grid (256, 3), block 256. 16 rows per block. F layout: [t][h][b][n][d] fp32
__global__ __launch_bounds__(256) void k_proj(
    const float* __restrict__ q, const float* __restrict__ k, const float* __restrict__ v,
    const float* __restrict__ ln_g, const float* __restrict__ ln_b,
    const float* __restrict__ W, float* __restrict__ F)
{
  __shared__ float xn[16][513];
  const int t = blockIdx.y;
  const float* x = (t == 0) ? q : (t == 1) ? k : v;
  const int row0 = blockIdx.x * 16;
  const int tid = threadIdx.x;
  const int wv = tid >> 6, lane = tid & 63;
  #pragma unroll
  for (int rr = 0; rr < 4; ++rr) {
    const int r = wv * 4 + rr;
    const float* xr = x + (size_t)(row0 + r) * 512;
    float vals[8];
    float s = 0.f, ss = 0.f;
    #pragma unroll
    for (int u = 0; u < 8; ++u) { float xv = xr[lane + (u << 6)]; vals[u] = xv; s += xv; ss += xv * xv; }
    #pragma unroll
    for (int o = 32; o; o >>= 1) { s += __shfl_xor(s, o); ss += __shfl_xor(ss, o); }
    const float mu = s * (1.f / 512.f);
    const float rstd = rsqrtf(ss * (1.f / 512.f) - mu * mu + 1e-5f);
    #pragma unroll
    for (int u = 0; u < 8; ++u) {
      int i = lane + (u << 6);
      xn[r][i] = (vals[u] - mu) * rstd * ln_g[i] + ln_b[i];
    }
  }
  __syncthreads();
  const int rg = tid >> 6, c = tid & 63;
  float acc[4][8];
  #pragma unroll
  for (int a = 0; a < 4; ++a) {
    #pragma unroll
    for (int b = 0; b < 8; ++b) acc[a][b] = 0.f;
  }
  for (int i = 0; i < 512; ++i) {
    const float a0 = xn[rg * 4 + 0][i], a1 = xn[rg * 4 + 1][i];
    const float a2 = xn[rg * 4 + 2][i], a3 = xn[rg * 4 + 3][i];
    const float* wr = W + (size_t)i * 512 + c;
    #pragma unroll
    for (int cc = 0; cc < 8; ++cc) {
      const float wvv = wr[cc << 6];
      acc[0][cc] += a0 * wvv; acc[1][cc] += a1 * wvv;
      acc[2][cc] += a2 * wvv; acc[3][cc] += a3 * wvv;
    }
  }
  float* Fo = F + (size_t)t * SZ;
  #pragma unroll
  for (int rr = 0; rr < 4; ++rr) {
    const int grow = row0 + rg * 4 + rr;
    const int b = grow >> 10, n2 = grow & 1023;
    #pragma unroll
    for (int cc = 0; cc < 8; ++cc) {  // col j = cc*64 + c -> h=cc, d=c
      Fo[(((size_t)(cc * 4 + b) << 10) + n2) * 64 + c] = acc[rr][cc];
    }
  }
}

// ---------------- K2: per-(h,b,d) sums over n, for q (feat) and k (centering) ----------------
// grid (32, 2), block 256
__global__ void k_colsum(const float* __restrict__ F, float* __restrict__ sums)
{
  const int pair = blockIdx.x, t = blockIdx.y;
  const float* f = F + (size_t)t * SZ + (size_t)pair * 65536;
  const int tid = threadIdx.x, d = tid & 63, g = tid >> 6;
  float s = 0.f;
  for (int n = g; n < 1024; n += 4) s += f[((size_t)n << 6) + d];
  __shared__ float red[4][64];
  red[g][d] = s;
  __syncthreads();
  if (g == 0) sums[(size_t)t * 2048 + pair * 64 + d] = red[0][d] + red[1][d] + red[2][d] + red[3][d];
}

// ---------------- K3: derived bf16 arrays for q,k ----------------
// grid (8192, 2), block 256 (4 rows/block, one wave per row)
// BF layout (ushort): [0]=fq_n, [SZ]=fk_n, [2SZ]=f_q_c, [3SZ]=f_k_c, [4SZ]=f_v^T (from k_vt)
__global__ void k_derived(const float* __restrict__ F, const float* __restrict__ sums,
                          unsigned short* __restrict__ BF)
{
  const int t = blockIdx.y;
  const int tid = threadIdx.x, wv = tid >> 6, lane = tid & 63;
  const int row = blockIdx.x * 4 + wv;
  const float val = F[(size_t)t * SZ + ((size_t)row << 6) + lane];
  float s = val, ss = val * val;
  #pragma unroll
  for (int o = 32; o; o >>= 1) { s += __shfl_xor(s, o); ss += __shfl_xor(ss, o); }
  const float inv = 1.f / (sqrtf(ss) + 1e-8f);
  const float ctr = (t == 0) ? s * (1.f / 64.f)
                             : sums[2048 + (row >> 10) * 64 + lane] * (1.f / 1024.f);
  BF[(size_t)t * SZ + ((size_t)row << 6) + lane] = f2b(val * inv);
  BF[(size_t)(2 + t) * SZ + ((size_t)row << 6) + lane] = f2b(val - ctr);
}

// ---------------- K4: V transpose -> bf16 [pair][d=64][n=1024] ----------------
// grid (16, 32), block 256
__global__ void k_vt(const float* __restrict__ F, unsigned short* __restrict__ FVT)
{
  __shared__ float t[64][65];
  const int pair = blockIdx.y, n0 = blockIdx.x * 64;
  const int tid = threadIdx.x;
  const float* src = F + (size_t)2 * SZ + (size_t)pair * 65536 + (size_t)n0 * 64;
  for (int u = tid; u < 4096; u += 256) {
    const int r = u >> 6, d = u & 63;
    t[d][r] = src[r * 64 + d];
  }
  __syncthreads();
  unsigned short* dst = FVT + (size_t)pair * 65536;
  for (int u = tid; u < 4096; u += 256) {
    const int d = u >> 6, c = u & 63;
    dst[(size_t)d * 1024 + n0 + c] = f2b(t[d][c]);
  }
}

// ---------------- K5: score stats pass (MFMA) ----------------
// grid (16 rowtiles, 32 pairs), block 256 (4 waves, 16 q-rows each).
// stats[h*9 + i]: 0=SX 1=SXX 2=SC 3=SCC 4=SXC 5=SZ 6=SZZ 7=SZ*SXrow 8=SZ*SCrow
__global__ __launch_bounds__(256) void k_stats(const unsigned short* __restrict__ BF,
                                               double* __restrict__ stats)
{
  __shared__ __align__(16) unsigned short kn_s[4096], kc_s[4096];
  __shared__ float part[9][4];
  const int pair = blockIdx.y, h = pair >> 2;
  const int r0 = blockIdx.x * 64;
  const int tid = threadIdx.x;
  const int w = tid >> 6, lane = tid & 63;
  const int lr = lane & 15, lg = lane >> 4;
  const size_t pb = (size_t)pair * 65536;
  const unsigned short* fqn = BF + pb;
  const unsigned short* fkn = BF + (size_t)SZ + pb;
  const unsigned short* fqc = BF + (size_t)2 * SZ + pb;
  const unsigned short* fkc = BF + (size_t)3 * SZ + pb;

  // Q fragments from global (loop-invariant)
  const int qrow = r0 + w * 16 + lr;
  const unsigned short* qnp = fqn + (size_t)qrow * 64;
  const unsigned short* qcp = fqc + (size_t)qrow * 64;
  const bf16x8 qn0 = *reinterpret_cast<const bf16x8*>(qnp + lg * 8);
  const bf16x8 qn1 = *reinterpret_cast<const bf16x8*>(qnp + 32 + lg * 8);
  const bf16x8 qc0 = *reinterpret_cast<const bf16x8*>(qcp + lg * 8);
  const bf16x8 qc1 = *reinterpret_cast<const bf16x8*>(qcp + 32 + lg * 8);

  float sx = 0.f, sxx = 0.f, scv = 0.f, scc = 0.f, sxc = 0.f;
  float rxs[4] = {0, 0, 0, 0}, rcs[4] = {0, 0, 0, 0}, rms[4] = {0, 0, 0, 0};

  for (int m0 = 0; m0 < 1024; m0 += 64) {
    __syncthreads();
    for (int u = tid; u < 512; u += 256) {
      const int r = u >> 3, c = u & 7;
      const int li = swz(r, c);
      const size_t gi = ((size_t)(m0 + r) << 6) + (c << 3);
      *reinterpret_cast<uint4*>(&kn_s[li]) = *reinterpret_cast<const uint4*>(&fkn[gi]);
      *reinterpret_cast<uint4*>(&kc_s[li]) = *reinterpret_cast<const uint4*>(&fkc[gi]);
    }
    __syncthreads();
    #pragma unroll
    for (int nt = 0; nt < 4; ++nt) {
      const int krow = nt * 16 + lr;
      f32x4 dn = {0.f, 0.f, 0.f, 0.f}, dc = {0.f, 0.f, 0.f, 0.f};
      dn = MFMA16(qn0, ldfrag(kn_s, krow, lg), dn);
      dn = MFMA16(qn1, ldfrag(kn_s, 4 + lg == lg ? lg : 4 + lg, 0), dn);  // placeholder fixed below
      dc = MFMA16(qc0, ldfrag(kc_s, krow, lg), dc);
      dc = MFMA16(qc1, ldfrag(kc_s, krow, 4 + lg), dc);
      // fix dn second term properly:
      // (note: the line above for dn used wrong args; recompute cleanly)
      dn = f32x4{0.f, 0.f, 0.f, 0.f};
      dn = MFMA16(qn0, ldfrag(kn_s, krow, lg), dn);
      dn = MFMA16(qn1, ldfrag(kn_s, krow, 4 + lg), dn);
      #pragma unroll
      for (int r = 0; r < 4; ++r) {
        const float X = fminf(fmaxf(dn[r], -0.98f), 0.98f);
        const float cv = dc[r] * COVS;
        sx += X; sxx += X * X; scv += cv; scc += cv * cv; sxc += X * cv;
        rxs[r] += X; rcs[r] += cv; rms[r] += fmaxf(0.01f - X, 0.f);
      }
    }
  }
  const float g0 = wredsum(sx), g1 = wredsum(sxx), g2 = wredsum(scv), g3 = wredsum(scc), g4 = wredsum(sxc);
  #pragma unroll
  for (int r = 0; r < 4; ++r) {
    #pragma unroll
    for (int o = 1; o < 16; o <<= 1) {
      rxs[r] += __shfl_xor(rxs[r], o);
      rcs[r] += __shfl_xor(rcs[r], o);
      rms[r] += __shfl_xor(rms[r], o);
    }
  }
  float z1 = 0.f, z2 = 0.f, z3 = 0.f, z4 = 0.f;
  if (lr == 0) {
    #pragma unroll
    for (int r = 0; r < 4; ++r) {
      const float Z = rms[r] * (1.f / 1024.f);
      z1 += Z; z2 += Z * Z; z3 += Z * rxs[r]; z4 += Z * rcs[r];
    }
  }
  z1 = wredsum(z1); z2 = wredsum(z2); z3 = wredsum(z3); z4 = wredsum(z4);
  if (lane == 0) {
    part[0][w] = g0; part[1][w] = g1; part[2][w] = g2; part[3][w] = g3; part[4][w] = g4;
    part[5][w] = z1; part[6][w] = z2; part[7][w] = z3; part[8][w] = z4;
  }
  __syncthreads();
  if (tid == 0) {
    #pragma unroll
    for (int i = 0; i < 9; ++i) {
      const double s = (double)part[i][0] + part[i][1] + part[i][2] + part[i][3];
      atomicAdd(&stats[h * 9 + i], s);
    }
  }
}

// ---------------- K6: weight-MLP + global std finalize -> per-head coefs ----------------
__global__ __launch_bounds__(256) void k_finalize(
    const float* __restrict__ sums, const double* __restrict__ stats,
    const float* __restrict__ W1, const float* __restrict__ b1,
    const float* __restrict__ lng, const float* __restrict__ lnb,
    const float* __restrict__ W2, const float* __restrict__ b2,
    const float* __restrict__ W3, const float* __restrict__ b3,
    const float* __restrict__ w_temp, float* __restrict__ coefs)
{
  __shared__ float feat[128], y1[192], h1[192], y2[128];
  __shared__ float muvar[2];
  __shared__ float wsm[8][3];
  const int tid = threadIdx.x;
  for (int h = 0; h < 8; ++h) {
    if (tid < 64) {
      float sq = 0.f, sk = 0.f;
      for (int b = 0; b < 4; ++b) {
        sq += sums[(h * 4 + b) * 64 + tid];
        sk += sums[2048 + (h * 4 + b) * 64 + tid];
      }
      feat[tid] = sq * (1.f / 4096.f);
      feat[64 + tid] = sk * (1.f / 4096.f);
    }
    __syncthreads();
    if (tid < 192) {
      float a = b1[tid];
      for (int i = 0; i < 128; ++i) a += feat[i] * W1[i * 192 + tid];
      y1[tid] = a;
    }
    __syncthreads();
    if (tid == 0) {
      float s = 0.f, ss = 0.f;
      for (int i = 0; i < 192; ++i) { const float vv = y1[i]; s += vv; ss += vv * vv; }
      const float mu = s / 192.f;
      muvar[0] = mu; muvar[1] = ss / 192.f - mu * mu;
    }
    __syncthreads();
    if (tid < 192) {
      const float vv = (y1[tid] - muvar[0]) * rsqrtf(muvar[1] + 1e-5f) * lng[tid] + lnb[tid];
      h1[tid] = fmaxf(vv, 0.f);
    }
    __syncthreads();
    if (tid < 128) {
      float a = b2[tid];
      for (int i = 0; i < 192; ++i) a += h1[i] * W2[i * 128 + tid];
      y2[tid] = fmaxf(a, 0.f);
    }
    __syncthreads();
    if (tid == 0) {
      float l[3];
      for (int c = 0; c < 3; ++c) {
        float a = b3[c];
        for (int i = 0; i < 128; ++i) a += y2[i] * W3[i * 3 + c];
        l[c] = a;
      }
      float mx = fmaxf(l[0], fmaxf(l[1], l[2]));
      float e0 = expf(l[0] - mx), e1 = expf(l[1] - mx), e2 = expf(l[2] - mx);
      float se = e0 + e1 + e2;
      const float p0 = e0 / se, p1 = e1 / se, p2 = e2 / se;
      const float wt = fminf(fmaxf(w_temp[0], 0.05f), 3.f);
      const float q0 = p0 / wt, q1 = p1 / wt, q2 = p2 / wt;
      mx = fmaxf(q0, fmaxf(q1, q2));
      e0 = expf(q0 - mx); e1 = expf(q1 - mx); e2 = expf(q2 - mx);
      se = e0 + e1 + e2;
      float w0 = e0 / se, w1 = e1 / se, w2 = e2 / se;
      w0 = fminf(fmaxf(w0, 0.05f), 0.85f);
      w1 = fminf(fmaxf(w1, 0.05f), 0.85f);
      w2 = fminf(fmaxf(w2, 0.05f), 0.85f);
      const float swt = w0 + w1 + w2;
      wsm[h][0] = w0 / swt; wsm[h][1] = w1 / swt; wsm[h][2] = w2 / swt;
    }
    __syncthreads();
  }
  if (tid == 0) {
    const double n = 33554432.0, M = 1024.0;
    double S[8][9], T[9];
    for (int i = 0; i < 9; ++i) T[i] = 0.0;
    for (int h = 0; h < 8; ++h)
      for (int i = 0; i < 9; ++i) { S[h][i] = stats[h * 9 + i]; T[i] += S[h][i]; }
    const double cos_norm = sqrt(fmax((T[1] - T[0] * T[0] / n) / (n - 1.0), 0.0)) + 1e-6;
    const double health = sqrt(fmax((T[3] - T[2] * T[2] / n) / (n - 1.0), 0.0));
    const double base = 0.001 / 1024.0;
    const double reg = (health < 1e-5) ? base * 8.0 : ((health < 1e-3) ? base * 3.0 : base);
    const double cov_norm = reg * health + 1e-6;  // clip(+-30) provably inactive
    const double zvar = (M * T[6] - (M * T[5]) * (M * T[5]) / n) / (n - 1.0);
    const double var_norm = sqrt(fmax(zvar, 0.0)) + 1e-6;
    const double cos_h = fmin(cos_norm, 1.2);
    const double cov_h = fmin(cov_norm * 12.0, 1.2);
    const double var_h = fmin(var_norm * 12.0, 1.2);
    double D1 = 0.0, D2 = 0.0, Ah[8], Bh[8];
    for (int h = 0; h < 8; ++h) {
      const double A = (double)wsm[h][0] * cos_h / cos_norm;
      const double Bc = (double)wsm[h][1] * 0.5 * cov_h / cov_norm * reg;
      const double C = (double)wsm[h][2] * 0.5 * var_h / var_norm;
      Ah[h] = A; Bh[h] = Bc;
      D1 += A * S[h][0] + Bc * S[h][2] + C * M * S[h][5];
      D2 += A * A * S[h][1] + Bc * Bc * S[h][3] + C * C * M * S[h][6]
          + 2.0 * A * Bc * S[h][4] + 2.0 * A * C * S[h][7] + 2.0 * Bc * C * S[h][8];
    }
    const double divv = sqrt(fmax((D2 - D1 * D1 / n) / (n - 1.0), 0.0));
    const double temp = (divv < 5e-6) ? 0.03 : ((divv < 5e-4) ? 0.15 : 0.4);
    for (int h = 0; h < 8; ++h) {
      coefs[h] = (float)(Ah[h] / temp);       // multiplies X
      coefs[8 + h] = (float)(Bh[h] / temp);   // multiplies cov_b
    }
  }
}

// ---------------- K7: attention pass (MFMA scores + online softmax + MFMA PV) ----------------
// grid (16 rowtiles, 32 pairs), block 256 (4 waves x 16 q-rows).
__global__ __launch_bounds__(256) void k_attn(const unsigned short* __restrict__ BF,
                                              const float* __restrict__ coefs,
                                              float* __restrict__ OUTF)
{
  __shared__ __align__(16) unsigned short kn_s[4096], kc_s[4096], vt_s[4096], P_s[4096];
  const int pair = blockIdx.y, h = pair >> 2;
  const int r0 = blockIdx.x * 64;
  const int tid = threadIdx.x;
  const int w = tid >> 6, lane = tid & 63;
  const int lr = lane & 15, lg = lane >> 4;
  const size_t pb = (size_t)pair * 65536;
  const unsigned short* fqn = BF + pb;
  const unsigned short* fkn = BF + (size_t)SZ + pb;
  const unsigned short* fqc = BF + (size_t)2 * SZ + pb;
  const unsigned short* fkc = BF + (size_t)3 * SZ + pb;
  const unsigned short* fvt = BF + (size_t)4 * SZ + pb;  // [d=64][n=1024]
  const float P = coefs[h], Qc = coefs[8 + h];

  // Q fragments from global (loop-invariant)
  const int qrow = r0 + w * 16 + lr;
  const unsigned short* qnp = fqn + (size_t)qrow * 64;
  const unsigned short* qcp = fqc + (size_t)qrow * 64;
  const bf16x8 qn0 = *reinterpret_cast<const bf16x8*>(qnp + lg * 8);
  const bf16x8 qn1 = *reinterpret_cast<const bf16x8*>(qnp + 32 + lg * 8);
  const bf16x8 qc0 = *reinterpret_cast<const bf16x8*>(qcp + lg * 8);
  const bf16x8 qc1 = *reinterpret_cast<const bf16x8*>(qcp + 32 + lg * 8);

  float m_r[4] = {-1e30f, -1e30f, -1e30f, -1e30f};
  float l_r[4] = {0.f, 0.f, 0.f, 0.f};
  f32x4 o[4];
  #pragma unroll
  for (int i = 0; i < 4; ++i) o[i] = f32x4{0.f, 0.f, 0.f, 0.f};

  for (int m0 = 0; m0 < 1024; m0 += 64) {
    __syncthreads();
    for (int u = tid; u < 512; u += 256) {
      const int r = u >> 3, c = u & 7;
      const int li = swz(r, c);
      const size_t gk = ((size_t)(m0 + r) << 6) + (c << 3);
      *reinterpret_cast<uint4*>(&kn_s[li]) = *reinterpret_cast<const uint4*>(&fkn[gk]);
      *reinterpret_cast<uint4*>(&kc_s[li]) = *reinterpret_cast<const uint4*>(&fkc[gk]);
      const size_t gv = (size_t)r * 1024 + m0 + (c << 3);
      *reinterpret_cast<uint4*>(&vt_s[li]) = *reinterpret_cast<const uint4*>(&fvt[gv]);
    }
    __syncthreads();

    // scores: sc[nt][r] for (q = 4*lg + r, key = nt*16 + lr)
    float sc[4][4];
    #pragma unroll
    for (int nt = 0; nt < 4; ++nt) {
      const int krow = nt * 16 + lr;
      f32x4 dn = {0.f, 0.f, 0.f, 0.f}, dc = {0.f, 0.f, 0.f, 0.f};
      dn = MFMA16(qn0, ldfrag(kn_s, krow, lg), dn);
      dn = MFMA16(qn1, ldfrag(kn_s, krow, 4 + lg), dn);
      dc = MFMA16(qc0, ldfrag(kc_s, krow, lg), dc);
      dc = MFMA16(qc1, ldfrag(kc_s, krow, 4 + lg), dc);
      #pragma unroll
      for (int r = 0; r < 4; ++r) {
        const float X = fminf(fmaxf(dn[r], -0.98f), 0.98f);
        const float cv = dc[r] * COVS;
        sc[nt][r] = P * X + Qc * cv;
      }
    }
    // online softmax over this 64-key tile
    float mxr[4], al[4], ps[4];
    #pragma unroll
    for (int r = 0; r < 4; ++r)
      mxr[r] = fmaxf(fmaxf(sc[0][r], sc[1][r]), fmaxf(sc[2][r], sc[3][r]));
    #pragma unroll
    for (int o2 = 1; o2 < 16; o2 <<= 1) {
      #pragma unroll
      for (int r = 0; r < 4; ++r) mxr[r] = fmaxf(mxr[r], __shfl_xor(mxr[r], o2));
    }
    #pragma unroll
    for (int r = 0; r < 4; ++r) {
      const float mn = fmaxf(m_r[r], mxr[r]);
      al[r] = __expf(m_r[r] - mn);
      m_r[r] = mn;
      ps[r] = 0.f;
    }
    // exp, write P (bf16) into A-frag-layout LDS tile, accumulate row sums
    #pragma unroll
    for (int nt = 0; nt < 4; ++nt) {
      #pragma unroll
      for (int r = 0; r < 4; ++r) {
        const float e = __expf(sc[nt][r] - m_r[r]);
        ps[r] += e;
        const int qb = w * 16 + 4 * lg + r;
        const int key = nt * 16 + lr;
        const int chunk = key >> 3;
        P_s[(qb << 6) + (((chunk ^ (qb & 7))) << 3) + (key & 7)] = f2b(e);
      }
    }
    #pragma unroll
    for (int o2 = 1; o2 < 16; o2 <<= 1) {
      #pragma unroll
      for (int r = 0; r < 4; ++r) ps[r] += __shfl_xor(ps[r], o2);
    }
    #pragma unroll
    for (int r = 0; r < 4; ++r) {
      l_r[r] = l_r[r] * al[r] + ps[r];
      #pragma unroll
      for (int nt2 = 0; nt2 < 4; ++nt2) o[nt2][r] *= al[r];
    }
    // PV: A = P (16q x 64key), B = V^T-tile (key x dv)
    const int parow = w * 16 + lr;
    const bf16x8 pa0 = ldfrag(P_s, parow, lg);
    const bf16x8 pa1 = ldfrag(P_s, parow, 4 + lg);
    #pragma unroll
    for (int nt2 = 0; nt2 < 4; ++nt2) {
      const int vrow = nt2 * 16 + lr;
      o[nt2] = MFMA16(pa0, ldfrag(vt_s, vrow, lg), o[nt2]);
      o[nt2] = MFMA16(pa1, ldfrag(vt_s, vrow, 4 + lg), o[nt2]);
    }
  }
  #pragma unroll
  for (int r = 0; r < 4; ++r) {
    const float inv = 1.f / l_r[r];
    const size_t orow = pb + ((size_t)(r0 + w * 16 + 4 * lg + r) << 6);
    #pragma unroll
    for (int nt2 = 0; nt2 < 4; ++nt2) {
      OUTF[orow + nt2 * 16 + lr] = o[nt2][r] * inv;
    }
  }
}

// ---------------- K8: out @ W_out + b_out ----------------
__global__ __launch_bounds__(256) void k_out(const float* __restrict__ OUTF,
                                             const float* __restrict__ W,
                                             const float* __restrict__ bias,
                                             float* __restrict__ out)
{
  __shared__ float a[16][513];
  const int row0 = blockIdx.x * 16;
  const int tid = threadIdx.x;
  for (int u = tid; u < 16 * 512; u += 256) {
    const int r = u >> 9, j = u & 511;
    const int grow = row0 + r, b = grow >> 10, n2 = grow & 1023;
    a[r][j] = OUTF[(((size_t)((j >> 6) * 4 + b) << 10) + n2) * 64 + (j & 63)];
  }
  __syncthreads();
  const int rg = tid >> 6, c = tid & 63;
  float acc[4][8];
  #pragma unroll
  for (int a2 = 0; a2 < 4; ++a2) {
    #pragma unroll
    for (int b2 = 0; b2 < 8; ++b2) acc[a2][b2] = 0.f;
  }
  for (int i = 0; i < 512; ++i) {
    const float a0 = a[rg * 4 + 0][i], a1 = a[rg * 4 + 1][i];
    const float a2v = a[rg * 4 + 2][i], a3 = a[rg * 4 + 3][i];
    const float* wr = W + (size_t)i * 512 + c;
    #pragma unroll
    for (int cc = 0; cc < 8; ++cc) {
      const float wvv = wr[cc << 6];
      acc[0][cc] += a0 * wvv; acc[1][cc] += a1 * wvv;
      acc[2][cc] += a2v * wvv; acc[3][cc] += a3 * wvv;
    }
  }
  #pragma unroll
  for (int rr = 0; rr < 4; ++rr) {
    const int grow = row0 + rg * 4 + rr;
    #pragma unroll
    for (int cc = 0; cc < 8; ++cc) {
      out[(size_t)grow * 512 + (cc << 6) + c] = acc[rr][cc] + bias[(cc << 6) + c];
    }
  }
}

extern "C" void kernel_launch(void* const* d_in, const int* in_sizes, int n_in,
                              void* d_out, int out_size, void* d_ws, size_t ws_size,
                              hipStream_t stream) {
  (void)in_sizes; (void)n_in; (void)out_size; (void)ws_size;
  const float* q      = (const float*)d_in[0];
  const float* k      = (const float*)d_in[1];
  const float* v      = (const float*)d_in[2];
  const float* ln_g   = (const float*)d_in[3];
  const float* ln_b   = (const float*)d_in[4];
  const float* W_in   = (const float*)d_in[5];
  const float* wp_W1  = (const float*)d_in[6];
  const float* wp_b1  = (const float*)d_in[7];
  const float* wp_lng = (const float*)d_in[8];
  const float* wp_lnb = (const float*)d_in[9];
  const float* wp_W2  = (const float*)d_in[10];
  const float* wp_b2  = (const float*)d_in[11];
  const float* wp_W3  = (const float*)d_in[12];
  const float* wp_b3  = (const float*)d_in[13];
  const float* w_temp = (const float*)d_in[14];
  const float* W_out  = (const float*)d_in[15];
  const float* b_out  = (const float*)d_in[16];

  float* ws = (float*)d_ws;
  float* F    = ws;                                  // fp32 f_q/f_k/f_v: 3*SZ floats
  float* OUTF = ws + (size_t)3 * SZ;                 // fp32 attn output: SZ floats
  unsigned short* BF = (unsigned short*)(ws + (size_t)4 * SZ);  // 5*SZ ushorts
  unsigned short* FVT = BF + (size_t)4 * SZ;         // V^T slice within BF
  float* AUX  = ws + (size_t)13631488;               // = 6.5*SZ
  float* sums  = AUX;                                // 4096 floats (qsum, ksum)
  float* coefs = AUX + 4096;                         // 64 floats
  double* stats = (double*)(AUX + 4160);             // 72 doubles

  k_zero<<<1, 128, 0, stream>>>(stats);
  k_proj<<<dim3(256, 3), 256, 0, stream>>>(q, k, v, ln_g, ln_b, W_in, F);
  k_colsum<<<dim3(32, 2), 256, 0, stream>>>(F, sums);
  k_derived<<<dim3(8192, 2), 256, 0, stream>>>(F, sums, BF);
  k_vt<<<dim3(16, 32), 256, 0, stream>>>(F, FVT);
  k_stats<<<dim3(16, 32), 256, 0, stream>>>(BF, stats);
  k_finalize<<<1, 256, 0, stream>>>(sums, stats, wp_W1, wp_b1, wp_lng, wp_lnb,
                                    wp_W2, wp_b2, wp_W3, wp_b3, w_temp, coefs);
  k_attn<<<dim3(16, 32), 256, 0, stream>>>(BF, coefs, OUTF);
  k_out<<<256, 256, 0, stream>>>(OUTF, W_out, b_out, (float*)d_out);
}

// Round 3
// 322.444 us; speedup vs baseline: 2.9692x; 1.3253x over previous
//
#include <hip/hip_runtime.h>
#include <math.h>

#define SZ 2097152  // 32768 rows * 64 d, per tensor slice
#define COVS (1.0f/8.000001f)

typedef __attribute__((ext_vector_type(8))) short bf16x8;
typedef __attribute__((ext_vector_type(4))) float f32x4;
#define MFMA16(A,B,C) __builtin_amdgcn_mfma_f32_16x16x32_bf16(A,B,C,0,0,0)

__device__ __forceinline__ unsigned short f2b(float x) {
  unsigned int u = __float_as_uint(x);
  u = (u + 0x7fffu + ((u >> 16) & 1u)) >> 16;  // RNE
  return (unsigned short)u;
}
__device__ __forceinline__ unsigned int pk2(float a, float b) {
  return (unsigned int)f2b(a) | ((unsigned int)f2b(b) << 16);
}
#define B2FL(u) __uint_as_float(((unsigned)(u)) << 16)

__device__ __forceinline__ float wredsum(float v) {
  #pragma unroll
  for (int o = 32; o; o >>= 1) v += __shfl_xor(v, o);
  return v;
}

// swizzled ushort index into a [rows][64 col] bf16 LDS tile (row = 8 chunks of 16B)
__device__ __forceinline__ int swz(int r, int c) { return (r << 6) + ((c ^ (r & 7)) << 3); }

__device__ __forceinline__ bf16x8 ldfrag(const unsigned short* s, int row, int chunk) {
  return *reinterpret_cast<const bf16x8*>(&s[swz(row, chunk)]);
}

// ---------------- K0: zero stat accumulators ----------------
__global__ void k_zero(double* __restrict__ stats) {
  int i = threadIdx.x;
  if (i < 72) stats[i] = 0.0;
}

// ---------------- K_cvt: WT[n][k] = bf16(W[k][n]) for W_in and W_out ----------------
// grid (64, 2), block 256
__global__ void k_cvt(const float* __restrict__ Win, const float* __restrict__ Wout,
                      unsigned short* __restrict__ WT)
{
  __shared__ float t[64][65];
  const int k0 = (blockIdx.x & 7) << 6, n0 = (blockIdx.x >> 3) << 6;
  const float* W = blockIdx.y ? Wout : Win;
  unsigned short* dst = WT + (size_t)blockIdx.y * 262144;
  const int tid = threadIdx.x;
  for (int u = tid; u < 4096; u += 256) {
    const int r = u >> 6, c = u & 63;
    t[c][r] = W[(size_t)(k0 + r) * 512 + n0 + c];
  }
  __syncthreads();
  for (int u = tid; u < 4096; u += 256) {
    const int r = u >> 6, c = u & 63;
    dst[(size_t)(n0 + r) * 512 + k0 + c] = f2b(t[r][c]);
  }
}

// ---------------- K_ln: A_bf[row][512] = bf16(LN(x)) for q,k,v rows ----------------
// grid 3072, block 256 (1 wave per row)
__global__ __launch_bounds__(256) void k_ln(
    const float* __restrict__ q, const float* __restrict__ k, const float* __restrict__ v,
    const float* __restrict__ ln_g, const float* __restrict__ ln_b,
    unsigned short* __restrict__ A_bf)
{
  const int tid = threadIdx.x, wv = tid >> 6, lane = tid & 63;
  const int row = blockIdx.x * 4 + wv;
  const int t = row >> 12, g = row & 4095;
  const float* x = (t == 0) ? q : (t == 1) ? k : v;
  const float4* xr = reinterpret_cast<const float4*>(x + (size_t)g * 512);
  const float4 a0 = xr[2 * lane], a1 = xr[2 * lane + 1];
  float s  = a0.x + a0.y + a0.z + a0.w + a1.x + a1.y + a1.z + a1.w;
  float ss = a0.x*a0.x + a0.y*a0.y + a0.z*a0.z + a0.w*a0.w
           + a1.x*a1.x + a1.y*a1.y + a1.z*a1.z + a1.w*a1.w;
  #pragma unroll
  for (int o = 32; o; o >>= 1) { s += __shfl_xor(s, o); ss += __shfl_xor(ss, o); }
  const float mu = s * (1.f / 512.f);
  const float rstd = rsqrtf(ss * (1.f / 512.f) - mu * mu + 1e-5f);
  const float4* gg = reinterpret_cast<const float4*>(ln_g);
  const float4* bb = reinterpret_cast<const float4*>(ln_b);
  const float4 g0 = gg[2 * lane], g1 = gg[2 * lane + 1];
  const float4 b0 = bb[2 * lane], b1 = bb[2 * lane + 1];
  uint4 o4;
  o4.x = pk2((a0.x - mu) * rstd * g0.x + b0.x, (a0.y - mu) * rstd * g0.y + b0.y);
  o4.y = pk2((a0.z - mu) * rstd * g0.z + b0.z, (a0.w - mu) * rstd * g0.w + b0.w);
  o4.z = pk2((a1.x - mu) * rstd * g1.x + b1.x, (a1.y - mu) * rstd * g1.y + b1.y);
  o4.w = pk2((a1.z - mu) * rstd * g1.z + b1.z, (a1.w - mu) * rstd * g1.w + b1.w);
  *reinterpret_cast<uint4*>(&A_bf[(size_t)row * 512 + lane * 8]) = o4;
}

// ---------------- K_gemm_proj: F = A_bf @ W_inT^T  (MFMA) ----------------
// grid (192, 4), block 256 (2x2 waves, 64x128 tile, K=512 in chunks of 64)
__global__ __launch_bounds__(256) void k_gemm_proj(
    const unsigned short* __restrict__ A_bf, const unsigned short* __restrict__ WT,
    float* __restrict__ F)
{
  __shared__ __align__(16) unsigned short As[4096], Bs[8192];
  const int m0 = blockIdx.x * 64;
  const int n0b = blockIdx.y * 128;
  const int tid = threadIdx.x;
  const int w = tid >> 6, lane = tid & 63;
  const int wm = w >> 1, wn = w & 1;
  const int lr = lane & 15, lg = lane >> 4;
  f32x4 acc[2][4];
  #pragma unroll
  for (int mi = 0; mi < 2; ++mi)
    #pragma unroll
    for (int ni = 0; ni < 4; ++ni) acc[mi][ni] = f32x4{0.f, 0.f, 0.f, 0.f};

  for (int k0 = 0; k0 < 512; k0 += 64) {
    __syncthreads();
    for (int u = tid; u < 512; u += 256) {
      const int r = u >> 3, c = u & 7;
      *reinterpret_cast<uint4*>(&As[swz(r, c)]) =
        *reinterpret_cast<const uint4*>(&A_bf[(size_t)(m0 + r) * 512 + k0 + c * 8]);
    }
    for (int u = tid; u < 1024; u += 256) {
      const int r = u >> 3, c = u & 7;
      *reinterpret_cast<uint4*>(&Bs[swz(r, c)]) =
        *reinterpret_cast<const uint4*>(&WT[(size_t)(n0b + r) * 512 + k0 + c * 8]);
    }
    __syncthreads();
    bf16x8 a[2][2];
    #pragma unroll
    for (int mi = 0; mi < 2; ++mi) {
      const int ar = wm * 32 + mi * 16 + lr;
      a[mi][0] = ldfrag(As, ar, lg);
      a[mi][1] = ldfrag(As, ar, 4 + lg);
    }
    #pragma unroll
    for (int ni = 0; ni < 4; ++ni) {
      const int br = wn * 64 + ni * 16 + lr;
      const bf16x8 b0 = ldfrag(Bs, br, lg);
      const bf16x8 b1 = ldfrag(Bs, br, 4 + lg);
      acc[0][ni] = MFMA16(a[0][0], b0, acc[0][ni]);
      acc[0][ni] = MFMA16(a[0][1], b1, acc[0][ni]);
      acc[1][ni] = MFMA16(a[1][0], b0, acc[1][ni]);
      acc[1][ni] = MFMA16(a[1][1], b1, acc[1][ni]);
    }
  }
  const int trow = m0 >> 12;
  float* Fo = F + (size_t)trow * SZ;
  const int gmb = (m0 & 4095) + wm * 32;
  #pragma unroll
  for (int mi = 0; mi < 2; ++mi) {
    #pragma unroll
    for (int ni = 0; ni < 4; ++ni) {
      const int j = n0b + wn * 64 + ni * 16 + lr;
      const int h = j >> 6, d = j & 63;
      #pragma unroll
      for (int reg = 0; reg < 4; ++reg) {
        const int g = gmb + mi * 16 + lg * 4 + reg;
        Fo[(size_t)((((h << 2) + (g >> 10)) << 10) | (g & 1023)) * 64 + d] = acc[mi][ni][reg];
      }
    }
  }
}

// ---------------- K2: per-(h,b,d) sums over n, for q (feat) and k (centering) ----------------
// grid (32, 2), block 256
__global__ void k_colsum(const float* __restrict__ F, float* __restrict__ sums)
{
  const int pair = blockIdx.x, t = blockIdx.y;
  const float* f = F + (size_t)t * SZ + (size_t)pair * 65536;
  const int tid = threadIdx.x, d = tid & 63, g = tid >> 6;
  float s = 0.f;
  for (int n = g; n < 1024; n += 4) s += f[((size_t)n << 6) + d];
  __shared__ float red[4][64];
  red[g][d] = s;
  __syncthreads();
  if (g == 0) sums[(size_t)t * 2048 + pair * 64 + d] = red[0][d] + red[1][d] + red[2][d] + red[3][d];
}

// ---------------- K3: derived bf16 arrays for q,k ----------------
// grid (8192, 2), block 256 (4 rows/block, one wave per row)
// BF layout (ushort): [0]=fq_n, [SZ]=fk_n, [2SZ]=f_q_c, [3SZ]=f_k_c, [4SZ]=f_v^T (from k_vt)
__global__ void k_derived(const float* __restrict__ F, const float* __restrict__ sums,
                          unsigned short* __restrict__ BF)
{
  const int t = blockIdx.y;
  const int tid = threadIdx.x, wv = tid >> 6, lane = tid & 63;
  const int row = blockIdx.x * 4 + wv;
  const float val = F[(size_t)t * SZ + ((size_t)row << 6) + lane];
  float s = val, ss = val * val;
  #pragma unroll
  for (int o = 32; o; o >>= 1) { s += __shfl_xor(s, o); ss += __shfl_xor(ss, o); }
  const float inv = 1.f / (sqrtf(ss) + 1e-8f);
  const float ctr = (t == 0) ? s * (1.f / 64.f)
                             : sums[2048 + (row >> 10) * 64 + lane] * (1.f / 1024.f);
  BF[(size_t)t * SZ + ((size_t)row << 6) + lane] = f2b(val * inv);
  BF[(size_t)(2 + t) * SZ + ((size_t)row << 6) + lane] = f2b(val - ctr);
}

// ---------------- K4: V transpose -> bf16 [pair][d=64][n=1024] ----------------
// grid (16, 32), block 256
__global__ void k_vt(const float* __restrict__ F, unsigned short* __restrict__ FVT)
{
  __shared__ float t[64][65];
  const int pair = blockIdx.y, n0 = blockIdx.x * 64;
  const int tid = threadIdx.x;
  const float* src = F + (size_t)2 * SZ + (size_t)pair * 65536 + (size_t)n0 * 64;
  for (int u = tid; u < 4096; u += 256) {
    const int r = u >> 6, d = u & 63;
    t[d][r] = src[r * 64 + d];
  }
  __syncthreads();
  unsigned short* dst = FVT + (size_t)pair * 65536;
  for (int u = tid; u < 4096; u += 256) {
    const int d = u >> 6, c = u & 63;
    dst[(size_t)d * 1024 + n0 + c] = f2b(t[d][c]);
  }
}

// ---------------- K5: score stats pass (MFMA) ----------------
// grid (16 rowtiles, 32 pairs), block 256 (4 waves, 16 q-rows each).
// stats[h*9 + i]: 0=SX 1=SXX 2=SC 3=SCC 4=SXC 5=SZ 6=SZZ 7=SZ*SXrow 8=SZ*SCrow
__global__ __launch_bounds__(256) void k_stats(const unsigned short* __restrict__ BF,
                                               double* __restrict__ stats)
{
  __shared__ __align__(16) unsigned short kn_s[4096], kc_s[4096];
  __shared__ float part[9][4];
  const int pair = blockIdx.y, h = pair >> 2;
  const int r0 = blockIdx.x * 64;
  const int tid = threadIdx.x;
  const int w = tid >> 6, lane = tid & 63;
  const int lr = lane & 15, lg = lane >> 4;
  const size_t pb = (size_t)pair * 65536;
  const unsigned short* fqn = BF + pb;
  const unsigned short* fkn = BF + (size_t)SZ + pb;
  const unsigned short* fqc = BF + (size_t)2 * SZ + pb;
  const unsigned short* fkc = BF + (size_t)3 * SZ + pb;

  // Q fragments from global (loop-invariant)
  const int qrow = r0 + w * 16 + lr;
  const unsigned short* qnp = fqn + (size_t)qrow * 64;
  const unsigned short* qcp = fqc + (size_t)qrow * 64;
  const bf16x8 qn0 = *reinterpret_cast<const bf16x8*>(qnp + lg * 8);
  const bf16x8 qn1 = *reinterpret_cast<const bf16x8*>(qnp + 32 + lg * 8);
  const bf16x8 qc0 = *reinterpret_cast<const bf16x8*>(qcp + lg * 8);
  const bf16x8 qc1 = *reinterpret_cast<const bf16x8*>(qcp + 32 + lg * 8);

  float sx = 0.f, sxx = 0.f, scv = 0.f, scc = 0.f, sxc = 0.f;
  float rxs[4] = {0, 0, 0, 0}, rcs[4] = {0, 0, 0, 0}, rms[4] = {0, 0, 0, 0};

  for (int m0 = 0; m0 < 1024; m0 += 64) {
    __syncthreads();
    for (int u = tid; u < 512; u += 256) {
      const int r = u >> 3, c = u & 7;
      const int li = swz(r, c);
      const size_t gi = ((size_t)(m0 + r) << 6) + (c << 3);
      *reinterpret_cast<uint4*>(&kn_s[li]) = *reinterpret_cast<const uint4*>(&fkn[gi]);
      *reinterpret_cast<uint4*>(&kc_s[li]) = *reinterpret_cast<const uint4*>(&fkc[gi]);
    }
    __syncthreads();
    #pragma unroll
    for (int nt = 0; nt < 4; ++nt) {
      const int krow = nt * 16 + lr;
      f32x4 dn = {0.f, 0.f, 0.f, 0.f}, dc = {0.f, 0.f, 0.f, 0.f};
      dn = MFMA16(qn0, ldfrag(kn_s, krow, lg), dn);
      dn = MFMA16(qn1, ldfrag(kn_s, krow, 4 + lg), dn);
      dc = MFMA16(qc0, ldfrag(kc_s, krow, lg), dc);
      dc = MFMA16(qc1, ldfrag(kc_s, krow, 4 + lg), dc);
      #pragma unroll
      for (int r = 0; r < 4; ++r) {
        const float X = fminf(fmaxf(dn[r], -0.98f), 0.98f);
        const float cv = dc[r] * COVS;
        sx += X; sxx += X * X; scv += cv; scc += cv * cv; sxc += X * cv;
        rxs[r] += X; rcs[r] += cv; rms[r] += fmaxf(0.01f - X, 0.f);
      }
    }
  }
  const float g0 = wredsum(sx), g1 = wredsum(sxx), g2 = wredsum(scv), g3 = wredsum(scc), g4 = wredsum(sxc);
  #pragma unroll
  for (int r = 0; r < 4; ++r) {
    #pragma unroll
    for (int o = 1; o < 16; o <<= 1) {
      rxs[r] += __shfl_xor(rxs[r], o);
      rcs[r] += __shfl_xor(rcs[r], o);
      rms[r] += __shfl_xor(rms[r], o);
    }
  }
  float z1 = 0.f, z2 = 0.f, z3 = 0.f, z4 = 0.f;
  if (lr == 0) {
    #pragma unroll
    for (int r = 0; r < 4; ++r) {
      const float Z = rms[r] * (1.f / 1024.f);
      z1 += Z; z2 += Z * Z; z3 += Z * rxs[r]; z4 += Z * rcs[r];
    }
  }
  z1 = wredsum(z1); z2 = wredsum(z2); z3 = wredsum(z3); z4 = wredsum(z4);
  if (lane == 0) {
    part[0][w] = g0; part[1][w] = g1; part[2][w] = g2; part[3][w] = g3; part[4][w] = g4;
    part[5][w] = z1; part[6][w] = z2; part[7][w] = z3; part[8][w] = z4;
  }
  __syncthreads();
  if (tid == 0) {
    #pragma unroll
    for (int i = 0; i < 9; ++i) {
      const double s = (double)part[i][0] + part[i][1] + part[i][2] + part[i][3];
      atomicAdd(&stats[h * 9 + i], s);
    }
  }
}

// ---------------- K6: weight-MLP + global std finalize -> per-head coefs ----------------
__global__ __launch_bounds__(256) void k_finalize(
    const float* __restrict__ sums, const double* __restrict__ stats,
    const float* __restrict__ W1, const float* __restrict__ b1,
    const float* __restrict__ lng, const float* __restrict__ lnb,
    const float* __restrict__ W2, const float* __restrict__ b2,
    const float* __restrict__ W3, const float* __restrict__ b3,
    const float* __restrict__ w_temp, float* __restrict__ coefs)
{
  __shared__ float feat[128], y1[192], h1[192], y2[128];
  __shared__ float muvar[2];
  __shared__ float wsm[8][3];
  const int tid = threadIdx.x;
  for (int h = 0; h < 8; ++h) {
    if (tid < 64) {
      float sq = 0.f, sk = 0.f;
      for (int b = 0; b < 4; ++b) {
        sq += sums[(h * 4 + b) * 64 + tid];
        sk += sums[2048 + (h * 4 + b) * 64 + tid];
      }
      feat[tid] = sq * (1.f / 4096.f);
      feat[64 + tid] = sk * (1.f / 4096.f);
    }
    __syncthreads();
    if (tid < 192) {
      float a = b1[tid];
      for (int i = 0; i < 128; ++i) a += feat[i] * W1[i * 192 + tid];
      y1[tid] = a;
    }
    __syncthreads();
    if (tid == 0) {
      float s = 0.f, ss = 0.f;
      for (int i = 0; i < 192; ++i) { const float vv = y1[i]; s += vv; ss += vv * vv; }
      const float mu = s / 192.f;
      muvar[0] = mu; muvar[1] = ss / 192.f - mu * mu;
    }
    __syncthreads();
    if (tid < 192) {
      const float vv = (y1[tid] - muvar[0]) * rsqrtf(muvar[1] + 1e-5f) * lng[tid] + lnb[tid];
      h1[tid] = fmaxf(vv, 0.f);
    }
    __syncthreads();
    if (tid < 128) {
      float a = b2[tid];
      for (int i = 0; i < 192; ++i) a += h1[i] * W2[i * 128 + tid];
      y2[tid] = fmaxf(a, 0.f);
    }
    __syncthreads();
    if (tid == 0) {
      float l[3];
      for (int c = 0; c < 3; ++c) {
        float a = b3[c];
        for (int i = 0; i < 128; ++i) a += y2[i] * W3[i * 3 + c];
        l[c] = a;
      }
      float mx = fmaxf(l[0], fmaxf(l[1], l[2]));
      float e0 = expf(l[0] - mx), e1 = expf(l[1] - mx), e2 = expf(l[2] - mx);
      float se = e0 + e1 + e2;
      const float p0 = e0 / se, p1 = e1 / se, p2 = e2 / se;
      const float wt = fminf(fmaxf(w_temp[0], 0.05f), 3.f);
      const float q0 = p0 / wt, q1 = p1 / wt, q2 = p2 / wt;
      mx = fmaxf(q0, fmaxf(q1, q2));
      e0 = expf(q0 - mx); e1 = expf(q1 - mx); e2 = expf(q2 - mx);
      se = e0 + e1 + e2;
      float w0 = e0 / se, w1 = e1 / se, w2 = e2 / se;
      w0 = fminf(fmaxf(w0, 0.05f), 0.85f);
      w1 = fminf(fmaxf(w1, 0.05f), 0.85f);
      w2 = fminf(fmaxf(w2, 0.05f), 0.85f);
      const float swt = w0 + w1 + w2;
      wsm[h][0] = w0 / swt; wsm[h][1] = w1 / swt; wsm[h][2] = w2 / swt;
    }
    __syncthreads();
  }
  if (tid == 0) {
    const double n = 33554432.0, M = 1024.0;
    double S[8][9], T[9];
    for (int i = 0; i < 9; ++i) T[i] = 0.0;
    for (int h = 0; h < 8; ++h)
      for (int i = 0; i < 9; ++i) { S[h][i] = stats[h * 9 + i]; T[i] += S[h][i]; }
    const double cos_norm = sqrt(fmax((T[1] - T[0] * T[0] / n) / (n - 1.0), 0.0)) + 1e-6;
    const double health = sqrt(fmax((T[3] - T[2] * T[2] / n) / (n - 1.0), 0.0));
    const double base = 0.001 / 1024.0;
    const double reg = (health < 1e-5) ? base * 8.0 : ((health < 1e-3) ? base * 3.0 : base);
    const double cov_norm = reg * health + 1e-6;  // clip(+-30) provably inactive
    const double zvar = (M * T[6] - (M * T[5]) * (M * T[5]) / n) / (n - 1.0);
    const double var_norm = sqrt(fmax(zvar, 0.0)) + 1e-6;
    const double cos_h = fmin(cos_norm, 1.2);
    const double cov_h = fmin(cov_norm * 12.0, 1.2);
    const double var_h = fmin(var_norm * 12.0, 1.2);
    double D1 = 0.0, D2 = 0.0, Ah[8], Bh[8];
    for (int h = 0; h < 8; ++h) {
      const double A = (double)wsm[h][0] * cos_h / cos_norm;
      const double Bc = (double)wsm[h][1] * 0.5 * cov_h / cov_norm * reg;
      const double C = (double)wsm[h][2] * 0.5 * var_h / var_norm;
      Ah[h] = A; Bh[h] = Bc;
      D1 += A * S[h][0] + Bc * S[h][2] + C * M * S[h][5];
      D2 += A * A * S[h][1] + Bc * Bc * S[h][3] + C * C * M * S[h][6]
          + 2.0 * A * Bc * S[h][4] + 2.0 * A * C * S[h][7] + 2.0 * Bc * C * S[h][8];
    }
    const double divv = sqrt(fmax((D2 - D1 * D1 / n) / (n - 1.0), 0.0));
    const double temp = (divv < 5e-6) ? 0.03 : ((divv < 5e-4) ? 0.15 : 0.4);
    for (int h = 0; h < 8; ++h) {
      coefs[h] = (float)(Ah[h] / temp);       // multiplies X
      coefs[8 + h] = (float)(Bh[h] / temp);   // multiplies cov_b
    }
  }
}

// ---------------- K7: attention pass (MFMA scores + online softmax + MFMA PV) ----------------
// grid (16 rowtiles, 32 pairs), block 256 (4 waves x 16 q-rows).
__global__ __launch_bounds__(256) void k_attn(const unsigned short* __restrict__ BF,
                                              const float* __restrict__ coefs,
                                              float* __restrict__ OUTF)
{
  __shared__ __align__(16) unsigned short kn_s[4096], kc_s[4096], vt_s[4096], P_s[4096];
  const int pair = blockIdx.y, h = pair >> 2;
  const int r0 = blockIdx.x * 64;
  const int tid = threadIdx.x;
  const int w = tid >> 6, lane = tid & 63;
  const int lr = lane & 15, lg = lane >> 4;
  const size_t pb = (size_t)pair * 65536;
  const unsigned short* fqn = BF + pb;
  const unsigned short* fkn = BF + (size_t)SZ + pb;
  const unsigned short* fqc = BF + (size_t)2 * SZ + pb;
  const unsigned short* fkc = BF + (size_t)3 * SZ + pb;
  const unsigned short* fvt = BF + (size_t)4 * SZ + pb;  // [d=64][n=1024]
  const float P = coefs[h], Qc = coefs[8 + h];

  // Q fragments from global (loop-invariant)
  const int qrow = r0 + w * 16 + lr;
  const unsigned short* qnp = fqn + (size_t)qrow * 64;
  const unsigned short* qcp = fqc + (size_t)qrow * 64;
  const bf16x8 qn0 = *reinterpret_cast<const bf16x8*>(qnp + lg * 8);
  const bf16x8 qn1 = *reinterpret_cast<const bf16x8*>(qnp + 32 + lg * 8);
  const bf16x8 qc0 = *reinterpret_cast<const bf16x8*>(qcp + lg * 8);
  const bf16x8 qc1 = *reinterpret_cast<const bf16x8*>(qcp + 32 + lg * 8);

  float m_r[4] = {-1e30f, -1e30f, -1e30f, -1e30f};
  float l_r[4] = {0.f, 0.f, 0.f, 0.f};
  f32x4 o[4];
  #pragma unroll
  for (int i = 0; i < 4; ++i) o[i] = f32x4{0.f, 0.f, 0.f, 0.f};

  for (int m0 = 0; m0 < 1024; m0 += 64) {
    __syncthreads();
    for (int u = tid; u < 512; u += 256) {
      const int r = u >> 3, c = u & 7;
      const int li = swz(r, c);
      const size_t gk = ((size_t)(m0 + r) << 6) + (c << 3);
      *reinterpret_cast<uint4*>(&kn_s[li]) = *reinterpret_cast<const uint4*>(&fkn[gk]);
      *reinterpret_cast<uint4*>(&kc_s[li]) = *reinterpret_cast<const uint4*>(&fkc[gk]);
      const size_t gv = (size_t)r * 1024 + m0 + (c << 3);
      *reinterpret_cast<uint4*>(&vt_s[li]) = *reinterpret_cast<const uint4*>(&fvt[gv]);
    }
    __syncthreads();

    // scores: sc[nt][r] for (q = 4*lg + r, key = nt*16 + lr)
    float sc[4][4];
    #pragma unroll
    for (int nt = 0; nt < 4; ++nt) {
      const int krow = nt * 16 + lr;
      f32x4 dn = {0.f, 0.f, 0.f, 0.f}, dc = {0.f, 0.f, 0.f, 0.f};
      dn = MFMA16(qn0, ldfrag(kn_s, krow, lg), dn);
      dn = MFMA16(qn1, ldfrag(kn_s, krow, 4 + lg), dn);
      dc = MFMA16(qc0, ldfrag(kc_s, krow, lg), dc);
      dc = MFMA16(qc1, ldfrag(kc_s, krow, 4 + lg), dc);
      #pragma unroll
      for (int r = 0; r < 4; ++r) {
        const float X = fminf(fmaxf(dn[r], -0.98f), 0.98f);
        const float cv = dc[r] * COVS;
        sc[nt][r] = P * X + Qc * cv;
      }
    }
    // online softmax over this 64-key tile
    float mxr[4], al[4], ps[4];
    #pragma unroll
    for (int r = 0; r < 4; ++r)
      mxr[r] = fmaxf(fmaxf(sc[0][r], sc[1][r]), fmaxf(sc[2][r], sc[3][r]));
    #pragma unroll
    for (int o2 = 1; o2 < 16; o2 <<= 1) {
      #pragma unroll
      for (int r = 0; r < 4; ++r) mxr[r] = fmaxf(mxr[r], __shfl_xor(mxr[r], o2));
    }
    #pragma unroll
    for (int r = 0; r < 4; ++r) {
      const float mn = fmaxf(m_r[r], mxr[r]);
      al[r] = __expf(m_r[r] - mn);
      m_r[r] = mn;
      ps[r] = 0.f;
    }
    // exp, write P (bf16) into A-frag-layout LDS tile, accumulate row sums
    #pragma unroll
    for (int nt = 0; nt < 4; ++nt) {
      #pragma unroll
      for (int r = 0; r < 4; ++r) {
        const float e = __expf(sc[nt][r] - m_r[r]);
        ps[r] += e;
        const int qb = w * 16 + 4 * lg + r;
        const int key = nt * 16 + lr;
        const int chunk = key >> 3;
        P_s[(qb << 6) + (((chunk ^ (qb & 7))) << 3) + (key & 7)] = f2b(e);
      }
    }
    #pragma unroll
    for (int o2 = 1; o2 < 16; o2 <<= 1) {
      #pragma unroll
      for (int r = 0; r < 4; ++r) ps[r] += __shfl_xor(ps[r], o2);
    }
    #pragma unroll
    for (int r = 0; r < 4; ++r) {
      l_r[r] = l_r[r] * al[r] + ps[r];
      #pragma unroll
      for (int nt2 = 0; nt2 < 4; ++nt2) o[nt2][r] *= al[r];
    }
    // PV: A = P (16q x 64key), B = V^T-tile (key x dv)
    const int parow = w * 16 + lr;
    const bf16x8 pa0 = ldfrag(P_s, parow, lg);
    const bf16x8 pa1 = ldfrag(P_s, parow, 4 + lg);
    #pragma unroll
    for (int nt2 = 0; nt2 < 4; ++nt2) {
      const int vrow = nt2 * 16 + lr;
      o[nt2] = MFMA16(pa0, ldfrag(vt_s, vrow, lg), o[nt2]);
      o[nt2] = MFMA16(pa1, ldfrag(vt_s, vrow, 4 + lg), o[nt2]);
    }
  }
  #pragma unroll
  for (int r = 0; r < 4; ++r) {
    const float inv = 1.f / l_r[r];
    const size_t orow = pb + ((size_t)(r0 + w * 16 + 4 * lg + r) << 6);
    #pragma unroll
    for (int nt2 = 0; nt2 < 4; ++nt2) {
      OUTF[orow + nt2 * 16 + lr] = o[nt2][r] * inv;
    }
  }
}

// ---------------- K_gemm_out: out = gather(OUTF) @ W_outT^T + b  (MFMA) ----------------
// grid (64, 4), block 256
__global__ __launch_bounds__(256) void k_gemm_out(
    const float* __restrict__ OUTF, const unsigned short* __restrict__ WT,
    const float* __restrict__ bias, float* __restrict__ out)
{
  __shared__ __align__(16) unsigned short As[4096], Bs[8192];
  const int m0 = blockIdx.x * 64;
  const int n0b = blockIdx.y * 128;
  const int tid = threadIdx.x;
  const int w = tid >> 6, lane = tid & 63;
  const int wm = w >> 1, wn = w & 1;
  const int lr = lane & 15, lg = lane >> 4;
  f32x4 acc[2][4];
  #pragma unroll
  for (int mi = 0; mi < 2; ++mi)
    #pragma unroll
    for (int ni = 0; ni < 4; ++ni) acc[mi][ni] = f32x4{0.f, 0.f, 0.f, 0.f};

  for (int k0 = 0; k0 < 512; k0 += 64) {
    __syncthreads();
    for (int u = tid; u < 512; u += 256) {
      const int r = u >> 3, c = u & 7;
      const int g = m0 + r;
      const int j = k0 + c * 8;
      const float4* src = reinterpret_cast<const float4*>(
          OUTF + (size_t)(((((j >> 6) << 2) + (g >> 10)) << 10) | (g & 1023)) * 64 + (j & 63));
      const float4 f0 = src[0], f1 = src[1];
      uint4 o4;
      o4.x = pk2(f0.x, f0.y); o4.y = pk2(f0.z, f0.w);
      o4.z = pk2(f1.x, f1.y); o4.w = pk2(f1.z, f1.w);
      *reinterpret_cast<uint4*>(&As[swz(r, c)]) = o4;
    }
    for (int u = tid; u < 1024; u += 256) {
      const int r = u >> 3, c = u & 7;
      *reinterpret_cast<uint4*>(&Bs[swz(r, c)]) =
        *reinterpret_cast<const uint4*>(&WT[(size_t)(n0b + r) * 512 + k0 + c * 8]);
    }
    __syncthreads();
    bf16x8 a[2][2];
    #pragma unroll
    for (int mi = 0; mi < 2; ++mi) {
      const int ar = wm * 32 + mi * 16 + lr;
      a[mi][0] = ldfrag(As, ar, lg);
      a[mi][1] = ldfrag(As, ar, 4 + lg);
    }
    #pragma unroll
    for (int ni = 0; ni < 4; ++ni) {
      const int br = wn * 64 + ni * 16 + lr;
      const bf16x8 b0 = ldfrag(Bs, br, lg);
      const bf16x8 b1 = ldfrag(Bs, br, 4 + lg);
      acc[0][ni] = MFMA16(a[0][0], b0, acc[0][ni]);
      acc[0][ni] = MFMA16(a[0][1], b1, acc[0][ni]);
      acc[1][ni] = MFMA16(a[1][0], b0, acc[1][ni]);
      acc[1][ni] = MFMA16(a[1][1], b1, acc[1][ni]);
    }
  }
  #pragma unroll
  for (int mi = 0; mi < 2; ++mi) {
    #pragma unroll
    for (int ni = 0; ni < 4; ++ni) {
      const int j = n0b + wn * 64 + ni * 16 + lr;
      const float bj = bias[j];
      #pragma unroll
      for (int reg = 0; reg < 4; ++reg) {
        const int g = m0 + wm * 32 + mi * 16 + lg * 4 + reg;
        out[(size_t)g * 512 + j] = acc[mi][ni][reg] + bj;
      }
    }
  }
}

extern "C" void kernel_launch(void* const* d_in, const int* in_sizes, int n_in,
                              void* d_out, int out_size, void* d_ws, size_t ws_size,
                              hipStream_t stream) {
  (void)in_sizes; (void)n_in; (void)out_size; (void)ws_size;
  const float* q      = (const float*)d_in[0];
  const float* k      = (const float*)d_in[1];
  const float* v      = (const float*)d_in[2];
  const float* ln_g   = (const float*)d_in[3];
  const float* ln_b   = (const float*)d_in[4];
  const float* W_in   = (const float*)d_in[5];
  const float* wp_W1  = (const float*)d_in[6];
  const float* wp_b1  = (const float*)d_in[7];
  const float* wp_lng = (const float*)d_in[8];
  const float* wp_lnb = (const float*)d_in[9];
  const float* wp_W2  = (const float*)d_in[10];
  const float* wp_b2  = (const float*)d_in[11];
  const float* wp_W3  = (const float*)d_in[12];
  const float* wp_b3  = (const float*)d_in[13];
  const float* w_temp = (const float*)d_in[14];
  const float* W_out  = (const float*)d_in[15];
  const float* b_out  = (const float*)d_in[16];

  float* ws = (float*)d_ws;
  float* F    = ws;                                  // [0, 3SZ) fp32 f_q/f_k/f_v
  float* OUTF = ws + (size_t)3 * SZ;                 // [3SZ, 4SZ) fp32 attn output
  // A_bf overlaps OUTF + fq_n region: lifetime k_ln -> k_gemm_proj, both dead then
  unsigned short* A_bf = (unsigned short*)(ws + (size_t)3 * SZ);  // 12288*512 ushorts
  unsigned short* BF = (unsigned short*)(ws + (size_t)4 * SZ);    // 5*SZ ushorts
  unsigned short* FVT = BF + (size_t)4 * SZ;         // V^T slice within BF
  float* AUX  = ws + (size_t)13631488;               // = 6.5*SZ
  float* sums  = AUX;                                // 4096 floats (qsum, ksum)
  float* coefs = AUX + 4096;                         // 64 floats
  double* stats = (double*)(AUX + 4160);             // 72 doubles
  unsigned short* WT = (unsigned short*)(AUX + 8192);  // 2 x 512x512 bf16 (WinT, WoutT)

  k_zero<<<1, 128, 0, stream>>>(stats);
  k_cvt<<<dim3(64, 2), 256, 0, stream>>>(W_in, W_out, WT);
  k_ln<<<3072, 256, 0, stream>>>(q, k, v, ln_g, ln_b, A_bf);
  k_gemm_proj<<<dim3(192, 4), 256, 0, stream>>>(A_bf, WT, F);
  k_colsum<<<dim3(32, 2), 256, 0, stream>>>(F, sums);
  k_derived<<<dim3(8192, 2), 256, 0, stream>>>(F, sums, BF);
  k_vt<<<dim3(16, 32), 256, 0, stream>>>(F, FVT);
  k_stats<<<dim3(16, 32), 256, 0, stream>>>(BF, stats);
  k_finalize<<<1, 256, 0, stream>>>(sums, stats, wp_W1, wp_b1, wp_lng, wp_lnb,
                                    wp_W2, wp_b2, wp_W3, wp_b3, w_temp, coefs);
  k_attn<<<dim3(16, 32), 256, 0, stream>>>(BF, coefs, OUTF);
  k_gemm_out<<<dim3(64, 4), 256, 0, stream>>>(OUTF, WT + 262144, b_out, (float*)d_out);
}

// Round 4
// 255.333 us; speedup vs baseline: 3.7496x; 1.2628x over previous
//
#include <hip/hip_runtime.h>
#include <math.h>

#define SZ 2097152  // 32768 rows * 64 d, per tensor slice
#define COVS (1.0f/8.000001f)

typedef __attribute__((ext_vector_type(8))) short bf16x8;
typedef __attribute__((ext_vector_type(4))) float f32x4;
#define MFMA16(A,B,C) __builtin_amdgcn_mfma_f32_16x16x32_bf16(A,B,C,0,0,0)

__device__ __forceinline__ unsigned short f2b(float x) {
  unsigned int u = __float_as_uint(x);
  u = (u + 0x7fffu + ((u >> 16) & 1u)) >> 16;  // RNE
  return (unsigned short)u;
}
__device__ __forceinline__ unsigned int pk2(float a, float b) {
  return (unsigned int)f2b(a) | ((unsigned int)f2b(b) << 16);
}
#define B2FL(u) __uint_as_float(((unsigned)(u)) << 16)

__device__ __forceinline__ float wredsum(float v) {
  #pragma unroll
  for (int o = 32; o; o >>= 1) v += __shfl_xor(v, o);
  return v;
}

// swizzled ushort index into a [rows][64 col] bf16 LDS tile (row = 8 chunks of 16B)
__device__ __forceinline__ int swz(int r, int c) { return (r << 6) + ((c ^ (r & 7)) << 3); }

__device__ __forceinline__ bf16x8 ldfrag(const unsigned short* s, int row, int chunk) {
  return *reinterpret_cast<const bf16x8*>(&s[swz(row, chunk)]);
}

// ---------------- K0: zero stat accumulators ----------------
__global__ void k_zero(double* __restrict__ stats) {
  int i = threadIdx.x;
  if (i < 72) stats[i] = 0.0;
}

// ---------------- K_cvt: WT[n][k] = bf16(W[k][n]) for W_in and W_out ----------------
// grid (64, 2), block 256
__global__ void k_cvt(const float* __restrict__ Win, const float* __restrict__ Wout,
                      unsigned short* __restrict__ WT)
{
  __shared__ float t[64][65];
  const int k0 = (blockIdx.x & 7) << 6, n0 = (blockIdx.x >> 3) << 6;
  const float* W = blockIdx.y ? Wout : Win;
  unsigned short* dst = WT + (size_t)blockIdx.y * 262144;
  const int tid = threadIdx.x;
  for (int u = tid; u < 4096; u += 256) {
    const int r = u >> 6, c = u & 63;
    t[c][r] = W[(size_t)(k0 + r) * 512 + n0 + c];
  }
  __syncthreads();
  for (int u = tid; u < 4096; u += 256) {
    const int r = u >> 6, c = u & 63;
    dst[(size_t)(n0 + r) * 512 + k0 + c] = f2b(t[r][c]);
  }
}

// ---------------- K_ln: A_bf[row][512] = bf16(LN(x)) for q,k,v rows ----------------
// grid 3072, block 256 (1 wave per row)
__global__ __launch_bounds__(256) void k_ln(
    const float* __restrict__ q, const float* __restrict__ k, const float* __restrict__ v,
    const float* __restrict__ ln_g, const float* __restrict__ ln_b,
    unsigned short* __restrict__ A_bf)
{
  const int tid = threadIdx.x, wv = tid >> 6, lane = tid & 63;
  const int row = blockIdx.x * 4 + wv;
  const int t = row >> 12, g = row & 4095;
  const float* x = (t == 0) ? q : (t == 1) ? k : v;
  const float4* xr = reinterpret_cast<const float4*>(x + (size_t)g * 512);
  const float4 a0 = xr[2 * lane], a1 = xr[2 * lane + 1];
  float s  = a0.x + a0.y + a0.z + a0.w + a1.x + a1.y + a1.z + a1.w;
  float ss = a0.x*a0.x + a0.y*a0.y + a0.z*a0.z + a0.w*a0.w
           + a1.x*a1.x + a1.y*a1.y + a1.z*a1.z + a1.w*a1.w;
  #pragma unroll
  for (int o = 32; o; o >>= 1) { s += __shfl_xor(s, o); ss += __shfl_xor(ss, o); }
  const float mu = s * (1.f / 512.f);
  const float rstd = rsqrtf(ss * (1.f / 512.f) - mu * mu + 1e-5f);
  const float4* gg = reinterpret_cast<const float4*>(ln_g);
  const float4* bb = reinterpret_cast<const float4*>(ln_b);
  const float4 g0 = gg[2 * lane], g1 = gg[2 * lane + 1];
  const float4 b0 = bb[2 * lane], b1 = bb[2 * lane + 1];
  uint4 o4;
  o4.x = pk2((a0.x - mu) * rstd * g0.x + b0.x, (a0.y - mu) * rstd * g0.y + b0.y);
  o4.y = pk2((a0.z - mu) * rstd * g0.z + b0.z, (a0.w - mu) * rstd * g0.w + b0.w);
  o4.z = pk2((a1.x - mu) * rstd * g1.x + b1.x, (a1.y - mu) * rstd * g1.y + b1.y);
  o4.w = pk2((a1.z - mu) * rstd * g1.z + b1.z, (a1.w - mu) * rstd * g1.w + b1.w);
  *reinterpret_cast<uint4*>(&A_bf[(size_t)row * 512 + lane * 8]) = o4;
}

// ---------------- K_gemm_proj: F = A_bf @ W_inT^T  (MFMA) ----------------
// grid (192, 4), block 256 (2x2 waves, 64x128 tile, K=512 in chunks of 64)
__global__ __launch_bounds__(256) void k_gemm_proj(
    const unsigned short* __restrict__ A_bf, const unsigned short* __restrict__ WT,
    float* __restrict__ F)
{
  __shared__ __align__(16) unsigned short As[4096], Bs[8192];
  const int m0 = blockIdx.x * 64;
  const int n0b = blockIdx.y * 128;
  const int tid = threadIdx.x;
  const int w = tid >> 6, lane = tid & 63;
  const int wm = w >> 1, wn = w & 1;
  const int lr = lane & 15, lg = lane >> 4;
  f32x4 acc[2][4];
  #pragma unroll
  for (int mi = 0; mi < 2; ++mi)
    #pragma unroll
    for (int ni = 0; ni < 4; ++ni) acc[mi][ni] = f32x4{0.f, 0.f, 0.f, 0.f};

  for (int k0 = 0; k0 < 512; k0 += 64) {
    __syncthreads();
    for (int u = tid; u < 512; u += 256) {
      const int r = u >> 3, c = u & 7;
      *reinterpret_cast<uint4*>(&As[swz(r, c)]) =
        *reinterpret_cast<const uint4*>(&A_bf[(size_t)(m0 + r) * 512 + k0 + c * 8]);
    }
    for (int u = tid; u < 1024; u += 256) {
      const int r = u >> 3, c = u & 7;
      *reinterpret_cast<uint4*>(&Bs[swz(r, c)]) =
        *reinterpret_cast<const uint4*>(&WT[(size_t)(n0b + r) * 512 + k0 + c * 8]);
    }
    __syncthreads();
    bf16x8 a[2][2];
    #pragma unroll
    for (int mi = 0; mi < 2; ++mi) {
      const int ar = wm * 32 + mi * 16 + lr;
      a[mi][0] = ldfrag(As, ar, lg);
      a[mi][1] = ldfrag(As, ar, 4 + lg);
    }
    #pragma unroll
    for (int ni = 0; ni < 4; ++ni) {
      const int br = wn * 64 + ni * 16 + lr;
      const bf16x8 b0 = ldfrag(Bs, br, lg);
      const bf16x8 b1 = ldfrag(Bs, br, 4 + lg);
      acc[0][ni] = MFMA16(a[0][0], b0, acc[0][ni]);
      acc[0][ni] = MFMA16(a[0][1], b1, acc[0][ni]);
      acc[1][ni] = MFMA16(a[1][0], b0, acc[1][ni]);
      acc[1][ni] = MFMA16(a[1][1], b1, acc[1][ni]);
    }
  }
  const int trow = m0 >> 12;
  float* Fo = F + (size_t)trow * SZ;
  const int gmb = (m0 & 4095) + wm * 32;
  #pragma unroll
  for (int mi = 0; mi < 2; ++mi) {
    #pragma unroll
    for (int ni = 0; ni < 4; ++ni) {
      const int j = n0b + wn * 64 + ni * 16 + lr;
      const int h = j >> 6, d = j & 63;
      #pragma unroll
      for (int reg = 0; reg < 4; ++reg) {
        const int g = gmb + mi * 16 + lg * 4 + reg;
        Fo[(size_t)((((h << 2) + (g >> 10)) << 10) | (g & 1023)) * 64 + d] = acc[mi][ni][reg];
      }
    }
  }
}

// ---------------- K2: per-(h,b,d) sums over n, for q (feat) and k (centering) ----------------
// grid (32, 2), block 256
__global__ void k_colsum(const float* __restrict__ F, float* __restrict__ sums)
{
  const int pair = blockIdx.x, t = blockIdx.y;
  const float* f = F + (size_t)t * SZ + (size_t)pair * 65536;
  const int tid = threadIdx.x, d = tid & 63, g = tid >> 6;
  float s = 0.f;
  for (int n = g; n < 1024; n += 4) s += f[((size_t)n << 6) + d];
  __shared__ float red[4][64];
  red[g][d] = s;
  __syncthreads();
  if (g == 0) sums[(size_t)t * 2048 + pair * 64 + d] = red[0][d] + red[1][d] + red[2][d] + red[3][d];
}

// ---------------- K3: derived bf16 arrays for q,k ----------------
// grid (8192, 2), block 256 (4 rows/block, one wave per row)
// BF layout (ushort): [0]=fq_n, [SZ]=fk_n, [2SZ]=f_q_c, [3SZ]=f_k_c, [4SZ]=f_v^T (from k_vt)
__global__ void k_derived(const float* __restrict__ F, const float* __restrict__ sums,
                          unsigned short* __restrict__ BF)
{
  const int t = blockIdx.y;
  const int tid = threadIdx.x, wv = tid >> 6, lane = tid & 63;
  const int row = blockIdx.x * 4 + wv;
  const float val = F[(size_t)t * SZ + ((size_t)row << 6) + lane];
  float s = val, ss = val * val;
  #pragma unroll
  for (int o = 32; o; o >>= 1) { s += __shfl_xor(s, o); ss += __shfl_xor(ss, o); }
  const float inv = 1.f / (sqrtf(ss) + 1e-8f);
  const float ctr = (t == 0) ? s * (1.f / 64.f)
                             : sums[2048 + (row >> 10) * 64 + lane] * (1.f / 1024.f);
  BF[(size_t)t * SZ + ((size_t)row << 6) + lane] = f2b(val * inv);
  BF[(size_t)(2 + t) * SZ + ((size_t)row << 6) + lane] = f2b(val - ctr);
}

// ---------------- K4: V transpose -> bf16 [pair][d=64][n=1024] ----------------
// grid (16, 32), block 256
__global__ void k_vt(const float* __restrict__ F, unsigned short* __restrict__ FVT)
{
  __shared__ float t[64][65];
  const int pair = blockIdx.y, n0 = blockIdx.x * 64;
  const int tid = threadIdx.x;
  const float* src = F + (size_t)2 * SZ + (size_t)pair * 65536 + (size_t)n0 * 64;
  for (int u = tid; u < 4096; u += 256) {
    const int r = u >> 6, d = u & 63;
    t[d][r] = src[r * 64 + d];
  }
  __syncthreads();
  unsigned short* dst = FVT + (size_t)pair * 65536;
  for (int u = tid; u < 4096; u += 256) {
    const int d = u >> 6, c = u & 63;
    dst[(size_t)d * 1024 + n0 + c] = f2b(t[d][c]);
  }
}

// ---------------- K5: score stats pass (MFMA) ----------------
// grid (16 rowtiles, 32 pairs), block 256 (4 waves, 16 q-rows each).
// stats[h*9 + i]: 0=SX 1=SXX 2=SC 3=SCC 4=SXC 5=SZ 6=SZZ 7=SZ*SXrow 8=SZ*SCrow
__global__ __launch_bounds__(256) void k_stats(const unsigned short* __restrict__ BF,
                                               double* __restrict__ stats)
{
  __shared__ __align__(16) unsigned short kn_s[4096], kc_s[4096];
  __shared__ float part[9][4];
  const int pair = blockIdx.y, h = pair >> 2;
  const int r0 = blockIdx.x * 64;
  const int tid = threadIdx.x;
  const int w = tid >> 6, lane = tid & 63;
  const int lr = lane & 15, lg = lane >> 4;
  const size_t pb = (size_t)pair * 65536;
  const unsigned short* fqn = BF + pb;
  const unsigned short* fkn = BF + (size_t)SZ + pb;
  const unsigned short* fqc = BF + (size_t)2 * SZ + pb;
  const unsigned short* fkc = BF + (size_t)3 * SZ + pb;

  // Q fragments from global (loop-invariant)
  const int qrow = r0 + w * 16 + lr;
  const unsigned short* qnp = fqn + (size_t)qrow * 64;
  const unsigned short* qcp = fqc + (size_t)qrow * 64;
  const bf16x8 qn0 = *reinterpret_cast<const bf16x8*>(qnp + lg * 8);
  const bf16x8 qn1 = *reinterpret_cast<const bf16x8*>(qnp + 32 + lg * 8);
  const bf16x8 qc0 = *reinterpret_cast<const bf16x8*>(qcp + lg * 8);
  const bf16x8 qc1 = *reinterpret_cast<const bf16x8*>(qcp + 32 + lg * 8);

  float sx = 0.f, sxx = 0.f, scv = 0.f, scc = 0.f, sxc = 0.f;
  float rxs[4] = {0, 0, 0, 0}, rcs[4] = {0, 0, 0, 0}, rms[4] = {0, 0, 0, 0};

  for (int m0 = 0; m0 < 1024; m0 += 64) {
    __syncthreads();
    for (int u = tid; u < 512; u += 256) {
      const int r = u >> 3, c = u & 7;
      const int li = swz(r, c);
      const size_t gi = ((size_t)(m0 + r) << 6) + (c << 3);
      *reinterpret_cast<uint4*>(&kn_s[li]) = *reinterpret_cast<const uint4*>(&fkn[gi]);
      *reinterpret_cast<uint4*>(&kc_s[li]) = *reinterpret_cast<const uint4*>(&fkc[gi]);
    }
    __syncthreads();
    #pragma unroll
    for (int nt = 0; nt < 4; ++nt) {
      const int krow = nt * 16 + lr;
      f32x4 dn = {0.f, 0.f, 0.f, 0.f}, dc = {0.f, 0.f, 0.f, 0.f};
      dn = MFMA16(qn0, ldfrag(kn_s, krow, lg), dn);
      dn = MFMA16(qn1, ldfrag(kn_s, krow, 4 + lg), dn);
      dc = MFMA16(qc0, ldfrag(kc_s, krow, lg), dc);
      dc = MFMA16(qc1, ldfrag(kc_s, krow, 4 + lg), dc);
      #pragma unroll
      for (int r = 0; r < 4; ++r) {
        const float X = fminf(fmaxf(dn[r], -0.98f), 0.98f);
        const float cv = dc[r] * COVS;
        sx += X; sxx += X * X; scv += cv; scc += cv * cv; sxc += X * cv;
        rxs[r] += X; rcs[r] += cv; rms[r] += fmaxf(0.01f - X, 0.f);
      }
    }
  }
  const float g0 = wredsum(sx), g1 = wredsum(sxx), g2 = wredsum(scv), g3 = wredsum(scc), g4 = wredsum(sxc);
  #pragma unroll
  for (int r = 0; r < 4; ++r) {
    #pragma unroll
    for (int o = 1; o < 16; o <<= 1) {
      rxs[r] += __shfl_xor(rxs[r], o);
      rcs[r] += __shfl_xor(rcs[r], o);
      rms[r] += __shfl_xor(rms[r], o);
    }
  }
  float z1 = 0.f, z2 = 0.f, z3 = 0.f, z4 = 0.f;
  if (lr == 0) {
    #pragma unroll
    for (int r = 0; r < 4; ++r) {
      const float Z = rms[r] * (1.f / 1024.f);
      z1 += Z; z2 += Z * Z; z3 += Z * rxs[r]; z4 += Z * rcs[r];
    }
  }
  z1 = wredsum(z1); z2 = wredsum(z2); z3 = wredsum(z3); z4 = wredsum(z4);
  if (lane == 0) {
    part[0][w] = g0; part[1][w] = g1; part[2][w] = g2; part[3][w] = g3; part[4][w] = g4;
    part[5][w] = z1; part[6][w] = z2; part[7][w] = z3; part[8][w] = z4;
  }
  __syncthreads();
  if (tid == 0) {
    #pragma unroll
    for (int i = 0; i < 9; ++i) {
      const double s = (double)part[i][0] + part[i][1] + part[i][2] + part[i][3];
      atomicAdd(&stats[h * 9 + i], s);
    }
  }
}

// ---------------- K6: weight-MLP + global std finalize -> per-head coefs ----------------
// block 512 = 8 waves, one wave per head; then tid==0 fp64 epilogue.
__global__ __launch_bounds__(512) void k_finalize(
    const float* __restrict__ sums, const double* __restrict__ stats,
    const float* __restrict__ W1, const float* __restrict__ b1,
    const float* __restrict__ lng, const float* __restrict__ lnb,
    const float* __restrict__ W2, const float* __restrict__ b2,
    const float* __restrict__ W3, const float* __restrict__ b3,
    const float* __restrict__ w_temp, float* __restrict__ coefs)
{
  __shared__ float feat[8][128];
  __shared__ float h1[8][192];
  __shared__ float y2[8][128];
  __shared__ float wsm[8][3];
  const int tid = threadIdx.x;
  const int h = tid >> 6, lane = tid & 63;

  // feat: per-head mean of f_q/f_k over (B,N) from column sums
  {
    float sq = 0.f, sk = 0.f;
    #pragma unroll
    for (int b = 0; b < 4; ++b) {
      sq += sums[(h * 4 + b) * 64 + lane];
      sk += sums[2048 + (h * 4 + b) * 64 + lane];
    }
    feat[h][lane] = sq * (1.f / 4096.f);
    feat[h][64 + lane] = sk * (1.f / 4096.f);
  }
  // layer 1: y1[h][j], j = lane, lane+64, lane+128 (3 per lane); LN reduce via shfl
  float y1v[3];
  {
    float a0 = b1[lane], a1 = b1[lane + 64], a2 = b1[lane + 128];
    for (int i = 0; i < 128; ++i) {
      const float fv = feat[h][i];
      const float* wr = W1 + (size_t)i * 192;
      a0 += fv * wr[lane];
      a1 += fv * wr[lane + 64];
      a2 += fv * wr[lane + 128];
    }
    y1v[0] = a0; y1v[1] = a1; y1v[2] = a2;
  }
  float s = y1v[0] + y1v[1] + y1v[2];
  float ss = y1v[0]*y1v[0] + y1v[1]*y1v[1] + y1v[2]*y1v[2];
  s = wredsum(s); ss = wredsum(ss);
  const float mu = s * (1.f / 192.f);
  const float rstd = rsqrtf(ss * (1.f / 192.f) - mu * mu + 1e-5f);
  #pragma unroll
  for (int u = 0; u < 3; ++u) {
    const int j = lane + u * 64;
    h1[h][j] = fmaxf((y1v[u] - mu) * rstd * lng[j] + lnb[j], 0.f);
  }
  // layer 2: y2[h][c], c = lane, lane+64
  {
    float a0 = b2[lane], a1 = b2[lane + 64];
    for (int i = 0; i < 192; ++i) {
      const float hv = h1[h][i];
      const float* wr = W2 + (size_t)i * 128;
      a0 += hv * wr[lane];
      a1 += hv * wr[lane + 64];
    }
    y2[h][lane] = fmaxf(a0, 0.f);
    y2[h][lane + 64] = fmaxf(a1, 0.f);
  }
  // layer 3: l[c] = b3[c] + sum_i y2[h][i] * W3[i*3+c]; partial over i=lane, lane+64
  {
    float l0, l1, l2;
    const float va = y2[h][lane], vb = y2[h][lane + 64];
    const float* wa = W3 + (size_t)lane * 3;
    const float* wb = W3 + (size_t)(lane + 64) * 3;
    l0 = va * wa[0] + vb * wb[0];
    l1 = va * wa[1] + vb * wb[1];
    l2 = va * wa[2] + vb * wb[2];
    l0 = wredsum(l0); l1 = wredsum(l1); l2 = wredsum(l2);
    if (lane == 0) {
      l0 += b3[0]; l1 += b3[1]; l2 += b3[2];
      float mx = fmaxf(l0, fmaxf(l1, l2));
      float e0 = expf(l0 - mx), e1 = expf(l1 - mx), e2 = expf(l2 - mx);
      float se = e0 + e1 + e2;
      const float p0 = e0 / se, p1 = e1 / se, p2 = e2 / se;
      const float wt = fminf(fmaxf(w_temp[0], 0.05f), 3.f);
      const float q0 = p0 / wt, q1 = p1 / wt, q2 = p2 / wt;
      mx = fmaxf(q0, fmaxf(q1, q2));
      e0 = expf(q0 - mx); e1 = expf(q1 - mx); e2 = expf(q2 - mx);
      se = e0 + e1 + e2;
      float w0 = e0 / se, w1 = e1 / se, w2 = e2 / se;
      w0 = fminf(fmaxf(w0, 0.05f), 0.85f);
      w1 = fminf(fmaxf(w1, 0.05f), 0.85f);
      w2 = fminf(fmaxf(w2, 0.05f), 0.85f);
      const float swt = w0 + w1 + w2;
      wsm[h][0] = w0 / swt; wsm[h][1] = w1 / swt; wsm[h][2] = w2 / swt;
    }
  }
  __syncthreads();
  if (tid == 0) {
    const double n = 33554432.0, M = 1024.0;
    double S[8][9], T[9];
    for (int i = 0; i < 9; ++i) T[i] = 0.0;
    for (int hh = 0; hh < 8; ++hh)
      for (int i = 0; i < 9; ++i) { S[hh][i] = stats[hh * 9 + i]; T[i] += S[hh][i]; }
    const double cos_norm = sqrt(fmax((T[1] - T[0] * T[0] / n) / (n - 1.0), 0.0)) + 1e-6;
    const double health = sqrt(fmax((T[3] - T[2] * T[2] / n) / (n - 1.0), 0.0));
    const double base = 0.001 / 1024.0;
    const double reg = (health < 1e-5) ? base * 8.0 : ((health < 1e-3) ? base * 3.0 : base);
    const double cov_norm = reg * health + 1e-6;  // clip(+-30) provably inactive
    const double zvar = (M * T[6] - (M * T[5]) * (M * T[5]) / n) / (n - 1.0);
    const double var_norm = sqrt(fmax(zvar, 0.0)) + 1e-6;
    const double cos_h = fmin(cos_norm, 1.2);
    const double cov_h = fmin(cov_norm * 12.0, 1.2);
    const double var_h = fmin(var_norm * 12.0, 1.2);
    double D1 = 0.0, D2 = 0.0, Ah[8], Bh[8];
    for (int hh = 0; hh < 8; ++hh) {
      const double A = (double)wsm[hh][0] * cos_h / cos_norm;
      const double Bc = (double)wsm[hh][1] * 0.5 * cov_h / cov_norm * reg;
      const double C = (double)wsm[hh][2] * 0.5 * var_h / var_norm;
      Ah[hh] = A; Bh[hh] = Bc;
      D1 += A * S[hh][0] + Bc * S[hh][2] + C * M * S[hh][5];
      D2 += A * A * S[hh][1] + Bc * Bc * S[hh][3] + C * C * M * S[hh][6]
          + 2.0 * A * Bc * S[hh][4] + 2.0 * A * C * S[hh][7] + 2.0 * Bc * C * S[hh][8];
    }
    const double divv = sqrt(fmax((D2 - D1 * D1 / n) / (n - 1.0), 0.0));
    const double temp = (divv < 5e-6) ? 0.03 : ((divv < 5e-4) ? 0.15 : 0.4);
    for (int hh = 0; hh < 8; ++hh) {
      coefs[hh] = (float)(Ah[hh] / temp);       // multiplies X
      coefs[8 + hh] = (float)(Bh[hh] / temp);   // multiplies cov_b
    }
  }
}

// ---------------- K7: attention pass (MFMA scores + online softmax + MFMA PV) ----------------
// grid (16 rowtiles, 32 pairs), block 256 (4 waves x 16 q-rows).
__global__ __launch_bounds__(256) void k_attn(const unsigned short* __restrict__ BF,
                                              const float* __restrict__ coefs,
                                              float* __restrict__ OUTF)
{
  __shared__ __align__(16) unsigned short kn_s[4096], kc_s[4096], vt_s[4096], P_s[4096];
  const int pair = blockIdx.y, h = pair >> 2;
  const int r0 = blockIdx.x * 64;
  const int tid = threadIdx.x;
  const int w = tid >> 6, lane = tid & 63;
  const int lr = lane & 15, lg = lane >> 4;
  const size_t pb = (size_t)pair * 65536;
  const unsigned short* fqn = BF + pb;
  const unsigned short* fkn = BF + (size_t)SZ + pb;
  const unsigned short* fqc = BF + (size_t)2 * SZ + pb;
  const unsigned short* fkc = BF + (size_t)3 * SZ + pb;
  const unsigned short* fvt = BF + (size_t)4 * SZ + pb;  // [d=64][n=1024]
  const float P = coefs[h], Qc = coefs[8 + h];

  // Q fragments from global (loop-invariant)
  const int qrow = r0 + w * 16 + lr;
  const unsigned short* qnp = fqn + (size_t)qrow * 64;
  const unsigned short* qcp = fqc + (size_t)qrow * 64;
  const bf16x8 qn0 = *reinterpret_cast<const bf16x8*>(qnp + lg * 8);
  const bf16x8 qn1 = *reinterpret_cast<const bf16x8*>(qnp + 32 + lg * 8);
  const bf16x8 qc0 = *reinterpret_cast<const bf16x8*>(qcp + lg * 8);
  const bf16x8 qc1 = *reinterpret_cast<const bf16x8*>(qcp + 32 + lg * 8);

  float m_r[4] = {-1e30f, -1e30f, -1e30f, -1e30f};
  float l_r[4] = {0.f, 0.f, 0.f, 0.f};
  f32x4 o[4];
  #pragma unroll
  for (int i = 0; i < 4; ++i) o[i] = f32x4{0.f, 0.f, 0.f, 0.f};

  for (int m0 = 0; m0 < 1024; m0 += 64) {
    __syncthreads();
    for (int u = tid; u < 512; u += 256) {
      const int r = u >> 3, c = u & 7;
      const int li = swz(r, c);
      const size_t gk = ((size_t)(m0 + r) << 6) + (c << 3);
      *reinterpret_cast<uint4*>(&kn_s[li]) = *reinterpret_cast<const uint4*>(&fkn[gk]);
      *reinterpret_cast<uint4*>(&kc_s[li]) = *reinterpret_cast<const uint4*>(&fkc[gk]);
      const size_t gv = (size_t)r * 1024 + m0 + (c << 3);
      *reinterpret_cast<uint4*>(&vt_s[li]) = *reinterpret_cast<const uint4*>(&fvt[gv]);
    }
    __syncthreads();

    // scores: sc[nt][r] for (q = 4*lg + r, key = nt*16 + lr)
    float sc[4][4];
    #pragma unroll
    for (int nt = 0; nt < 4; ++nt) {
      const int krow = nt * 16 + lr;
      f32x4 dn = {0.f, 0.f, 0.f, 0.f}, dc = {0.f, 0.f, 0.f, 0.f};
      dn = MFMA16(qn0, ldfrag(kn_s, krow, lg), dn);
      dn = MFMA16(qn1, ldfrag(kn_s, krow, 4 + lg), dn);
      dc = MFMA16(qc0, ldfrag(kc_s, krow, lg), dc);
      dc = MFMA16(qc1, ldfrag(kc_s, krow, 4 + lg), dc);
      #pragma unroll
      for (int r = 0; r < 4; ++r) {
        const float X = fminf(fmaxf(dn[r], -0.98f), 0.98f);
        const float cv = dc[r] * COVS;
        sc[nt][r] = P * X + Qc * cv;
      }
    }
    // online softmax over this 64-key tile
    float mxr[4], al[4], ps[4];
    #pragma unroll
    for (int r = 0; r < 4; ++r)
      mxr[r] = fmaxf(fmaxf(sc[0][r], sc[1][r]), fmaxf(sc[2][r], sc[3][r]));
    #pragma unroll
    for (int o2 = 1; o2 < 16; o2 <<= 1) {
      #pragma unroll
      for (int r = 0; r < 4; ++r) mxr[r] = fmaxf(mxr[r], __shfl_xor(mxr[r], o2));
    }
    #pragma unroll
    for (int r = 0; r < 4; ++r) {
      const float mn = fmaxf(m_r[r], mxr[r]);
      al[r] = __expf(m_r[r] - mn);
      m_r[r] = mn;
      ps[r] = 0.f;
    }
    // exp, write P (bf16) into A-frag-layout LDS tile, accumulate row sums
    #pragma unroll
    for (int nt = 0; nt < 4; ++nt) {
      #pragma unroll
      for (int r = 0; r < 4; ++r) {
        const float e = __expf(sc[nt][r] - m_r[r]);
        ps[r] += e;
        const int qb = w * 16 + 4 * lg + r;
        const int key = nt * 16 + lr;
        const int chunk = key >> 3;
        P_s[(qb << 6) + (((chunk ^ (qb & 7))) << 3) + (key & 7)] = f2b(e);
      }
    }
    #pragma unroll
    for (int o2 = 1; o2 < 16; o2 <<= 1) {
      #pragma unroll
      for (int r = 0; r < 4; ++r) ps[r] += __shfl_xor(ps[r], o2);
    }
    #pragma unroll
    for (int r = 0; r < 4; ++r) {
      l_r[r] = l_r[r] * al[r] + ps[r];
      #pragma unroll
      for (int nt2 = 0; nt2 < 4; ++nt2) o[nt2][r] *= al[r];
    }
    // PV: A = P (16q x 64key), B = V^T-tile (key x dv)
    const int parow = w * 16 + lr;
    const bf16x8 pa0 = ldfrag(P_s, parow, lg);
    const bf16x8 pa1 = ldfrag(P_s, parow, 4 + lg);
    #pragma unroll
    for (int nt2 = 0; nt2 < 4; ++nt2) {
      const int vrow = nt2 * 16 + lr;
      o[nt2] = MFMA16(pa0, ldfrag(vt_s, vrow, lg), o[nt2]);
      o[nt2] = MFMA16(pa1, ldfrag(vt_s, vrow, 4 + lg), o[nt2]);
    }
  }
  #pragma unroll
  for (int r = 0; r < 4; ++r) {
    const float inv = 1.f / l_r[r];
    const size_t orow = pb + ((size_t)(r0 + w * 16 + 4 * lg + r) << 6);
    #pragma unroll
    for (int nt2 = 0; nt2 < 4; ++nt2) {
      OUTF[orow + nt2 * 16 + lr] = o[nt2][r] * inv;
    }
  }
}

// ---------------- K_gemm_out: out = gather(OUTF) @ W_outT^T + b  (MFMA) ----------------
// grid (64, 4), block 256
__global__ __launch_bounds__(256) void k_gemm_out(
    const float* __restrict__ OUTF, const unsigned short* __restrict__ WT,
    const float* __restrict__ bias, float* __restrict__ out)
{
  __shared__ __align__(16) unsigned short As[4096], Bs[8192];
  const int m0 = blockIdx.x * 64;
  const int n0b = blockIdx.y * 128;
  const int tid = threadIdx.x;
  const int w = tid >> 6, lane = tid & 63;
  const int wm = w >> 1, wn = w & 1;
  const int lr = lane & 15, lg = lane >> 4;
  f32x4 acc[2][4];
  #pragma unroll
  for (int mi = 0; mi < 2; ++mi)
    #pragma unroll
    for (int ni = 0; ni < 4; ++ni) acc[mi][ni] = f32x4{0.f, 0.f, 0.f, 0.f};

  for (int k0 = 0; k0 < 512; k0 += 64) {
    __syncthreads();
    for (int u = tid; u < 512; u += 256) {
      const int r = u >> 3, c = u & 7;
      const int g = m0 + r;
      const int j = k0 + c * 8;
      const float4* src = reinterpret_cast<const float4*>(
          OUTF + (size_t)(((((j >> 6) << 2) + (g >> 10)) << 10) | (g & 1023)) * 64 + (j & 63));
      const float4 f0 = src[0], f1 = src[1];
      uint4 o4;
      o4.x = pk2(f0.x, f0.y); o4.y = pk2(f0.z, f0.w);
      o4.z = pk2(f1.x, f1.y); o4.w = pk2(f1.z, f1.w);
      *reinterpret_cast<uint4*>(&As[swz(r, c)]) = o4;
    }
    for (int u = tid; u < 1024; u += 256) {
      const int r = u >> 3, c = u & 7;
      *reinterpret_cast<uint4*>(&Bs[swz(r, c)]) =
        *reinterpret_cast<const uint4*>(&WT[(size_t)(n0b + r) * 512 + k0 + c * 8]);
    }
    __syncthreads();
    bf16x8 a[2][2];
    #pragma unroll
    for (int mi = 0; mi < 2; ++mi) {
      const int ar = wm * 32 + mi * 16 + lr;
      a[mi][0] = ldfrag(As, ar, lg);
      a[mi][1] = ldfrag(As, ar, 4 + lg);
    }
    #pragma unroll
    for (int ni = 0; ni < 4; ++ni) {
      const int br = wn * 64 + ni * 16 + lr;
      const bf16x8 b0 = ldfrag(Bs, br, lg);
      const bf16x8 b1 = ldfrag(Bs, br, 4 + lg);
      acc[0][ni] = MFMA16(a[0][0], b0, acc[0][ni]);
      acc[0][ni] = MFMA16(a[0][1], b1, acc[0][ni]);
      acc[1][ni] = MFMA16(a[1][0], b0, acc[1][ni]);
      acc[1][ni] = MFMA16(a[1][1], b1, acc[1][ni]);
    }
  }
  #pragma unroll
  for (int mi = 0; mi < 2; ++mi) {
    #pragma unroll
    for (int ni = 0; ni < 4; ++ni) {
      const int j = n0b + wn * 64 + ni * 16 + lr;
      const float bj = bias[j];
      #pragma unroll
      for (int reg = 0; reg < 4; ++reg) {
        const int g = m0 + wm * 32 + mi * 16 + lg * 4 + reg;
        out[(size_t)g * 512 + j] = acc[mi][ni][reg] + bj;
      }
    }
  }
}

extern "C" void kernel_launch(void* const* d_in, const int* in_sizes, int n_in,
                              void* d_out, int out_size, void* d_ws, size_t ws_size,
                              hipStream_t stream) {
  (void)in_sizes; (void)n_in; (void)out_size; (void)ws_size;
  const float* q      = (const float*)d_in[0];
  const float* k      = (const float*)d_in[1];
  const float* v      = (const float*)d_in[2];
  const float* ln_g   = (const float*)d_in[3];
  const float* ln_b   = (const float*)d_in[4];
  const float* W_in   = (const float*)d_in[5];
  const float* wp_W1  = (const float*)d_in[6];
  const float* wp_b1  = (const float*)d_in[7];
  const float* wp_lng = (const float*)d_in[8];
  const float* wp_lnb = (const float*)d_in[9];
  const float* wp_W2  = (const float*)d_in[10];
  const float* wp_b2  = (const float*)d_in[11];
  const float* wp_W3  = (const float*)d_in[12];
  const float* wp_b3  = (const float*)d_in[13];
  const float* w_temp = (const float*)d_in[14];
  const float* W_out  = (const float*)d_in[15];
  const float* b_out  = (const float*)d_in[16];

  float* ws = (float*)d_ws;
  float* F    = ws;                                  // [0, 3SZ) fp32 f_q/f_k/f_v
  float* OUTF = ws + (size_t)3 * SZ;                 // [3SZ, 4SZ) fp32 attn output
  // A_bf overlaps OUTF + fq_n region: lifetime k_ln -> k_gemm_proj, both dead then
  unsigned short* A_bf = (unsigned short*)(ws + (size_t)3 * SZ);  // 12288*512 ushorts
  unsigned short* BF = (unsigned short*)(ws + (size_t)4 * SZ);    // 5*SZ ushorts
  unsigned short* FVT = BF + (size_t)4 * SZ;         // V^T slice within BF
  float* AUX  = ws + (size_t)13631488;               // = 6.5*SZ
  float* sums  = AUX;                                // 4096 floats (qsum, ksum)
  float* coefs = AUX + 4096;                         // 64 floats
  double* stats = (double*)(AUX + 4160);             // 72 doubles
  unsigned short* WT = (unsigned short*)(AUX + 8192);  // 2 x 512x512 bf16 (WinT, WoutT)

  k_zero<<<1, 128, 0, stream>>>(stats);
  k_cvt<<<dim3(64, 2), 256, 0, stream>>>(W_in, W_out, WT);
  k_ln<<<3072, 256, 0, stream>>>(q, k, v, ln_g, ln_b, A_bf);
  k_gemm_proj<<<dim3(192, 4), 256, 0, stream>>>(A_bf, WT, F);
  k_colsum<<<dim3(32, 2), 256, 0, stream>>>(F, sums);
  k_derived<<<dim3(8192, 2), 256, 0, stream>>>(F, sums, BF);
  k_vt<<<dim3(16, 32), 256, 0, stream>>>(F, FVT);
  k_stats<<<dim3(16, 32), 256, 0, stream>>>(BF, stats);
  k_finalize<<<1, 512, 0, stream>>>(sums, stats, wp_W1, wp_b1, wp_lng, wp_lnb,
                                    wp_W2, wp_b2, wp_W3, wp_b3, w_temp, coefs);
  k_attn<<<dim3(16, 32), 256, 0, stream>>>(BF, coefs, OUTF);
  k_gemm_out<<<dim3(64, 4), 256, 0, stream>>>(OUTF, WT + 262144, b_out, (float*)d_out);
}

// Round 5
// 201.307 us; speedup vs baseline: 4.7559x; 1.2684x over previous
//
#include <hip/hip_runtime.h>
#include <math.h>

#define SZ 2097152  // 32768 rows * 64 d, per tensor slice
#define COVS (1.0f/8.000001f)

typedef __attribute__((ext_vector_type(8))) short bf16x8;
typedef __attribute__((ext_vector_type(4))) float f32x4;
#define MFMA16(A,B,C) __builtin_amdgcn_mfma_f32_16x16x32_bf16(A,B,C,0,0,0)

__device__ __forceinline__ unsigned short f2b(float x) {
  unsigned int u = __float_as_uint(x);
  u = (u + 0x7fffu + ((u >> 16) & 1u)) >> 16;  // RNE
  return (unsigned short)u;
}
__device__ __forceinline__ unsigned int pk2(float a, float b) {
  return (unsigned int)f2b(a) | ((unsigned int)f2b(b) << 16);
}
#define B2FL(u) __uint_as_float(((unsigned)(u)) << 16)

__device__ __forceinline__ float wredsum(float v) {
  #pragma unroll
  for (int o = 32; o; o >>= 1) v += __shfl_xor(v, o);
  return v;
}

// swizzled ushort index into a [rows][64 col] bf16 LDS tile (row = 8 chunks of 16B)
__device__ __forceinline__ int swz(int r, int c) { return (r << 6) + ((c ^ (r & 7)) << 3); }

__device__ __forceinline__ bf16x8 ldfrag(const unsigned short* s, int row, int chunk) {
  return *reinterpret_cast<const bf16x8*>(&s[swz(row, chunk)]);
}

// ---------------- K0: zero stat accumulators ----------------
__global__ void k_zero(double* __restrict__ stats) {
  int i = threadIdx.x;
  if (i < 72) stats[i] = 0.0;
}

// ---------------- K_cvt: WT[n][k] = bf16(W[k][n]) for W_in and W_out ----------------
// grid (64, 2), block 256
__global__ void k_cvt(const float* __restrict__ Win, const float* __restrict__ Wout,
                      unsigned short* __restrict__ WT)
{
  __shared__ float t[64][65];
  const int k0 = (blockIdx.x & 7) << 6, n0 = (blockIdx.x >> 3) << 6;
  const float* W = blockIdx.y ? Wout : Win;
  unsigned short* dst = WT + (size_t)blockIdx.y * 262144;
  const int tid = threadIdx.x;
  for (int u = tid; u < 4096; u += 256) {
    const int r = u >> 6, c = u & 63;
    t[c][r] = W[(size_t)(k0 + r) * 512 + n0 + c];
  }
  __syncthreads();
  for (int u = tid; u < 4096; u += 256) {
    const int r = u >> 6, c = u & 63;
    dst[(size_t)(n0 + r) * 512 + k0 + c] = f2b(t[r][c]);
  }
}

// ---------------- K_ln: A_bf[row][512] = bf16(LN(x)) for q,k,v rows ----------------
// grid 3072, block 256 (1 wave per row)
__global__ __launch_bounds__(256) void k_ln(
    const float* __restrict__ q, const float* __restrict__ k, const float* __restrict__ v,
    const float* __restrict__ ln_g, const float* __restrict__ ln_b,
    unsigned short* __restrict__ A_bf)
{
  const int tid = threadIdx.x, wv = tid >> 6, lane = tid & 63;
  const int row = blockIdx.x * 4 + wv;
  const int t = row >> 12, g = row & 4095;
  const float* x = (t == 0) ? q : (t == 1) ? k : v;
  const float4* xr = reinterpret_cast<const float4*>(x + (size_t)g * 512);
  const float4 a0 = xr[2 * lane], a1 = xr[2 * lane + 1];
  float s  = a0.x + a0.y + a0.z + a0.w + a1.x + a1.y + a1.z + a1.w;
  float ss = a0.x*a0.x + a0.y*a0.y + a0.z*a0.z + a0.w*a0.w
           + a1.x*a1.x + a1.y*a1.y + a1.z*a1.z + a1.w*a1.w;
  #pragma unroll
  for (int o = 32; o; o >>= 1) { s += __shfl_xor(s, o); ss += __shfl_xor(ss, o); }
  const float mu = s * (1.f / 512.f);
  const float rstd = rsqrtf(ss * (1.f / 512.f) - mu * mu + 1e-5f);
  const float4* gg = reinterpret_cast<const float4*>(ln_g);
  const float4* bb = reinterpret_cast<const float4*>(ln_b);
  const float4 g0 = gg[2 * lane], g1 = gg[2 * lane + 1];
  const float4 b0 = bb[2 * lane], b1 = bb[2 * lane + 1];
  uint4 o4;
  o4.x = pk2((a0.x - mu) * rstd * g0.x + b0.x, (a0.y - mu) * rstd * g0.y + b0.y);
  o4.y = pk2((a0.z - mu) * rstd * g0.z + b0.z, (a0.w - mu) * rstd * g0.w + b0.w);
  o4.z = pk2((a1.x - mu) * rstd * g1.x + b1.x, (a1.y - mu) * rstd * g1.y + b1.y);
  o4.w = pk2((a1.z - mu) * rstd * g1.z + b1.z, (a1.w - mu) * rstd * g1.w + b1.w);
  *reinterpret_cast<uint4*>(&A_bf[(size_t)row * 512 + lane * 8]) = o4;
}

// ---------------- K_gemm_proj: F = A_bf @ W_inT^T  (MFMA) ----------------
// grid (192, 4), block 256 (2x2 waves, 64x128 tile, K=512 in chunks of 64)
__global__ __launch_bounds__(256) void k_gemm_proj(
    const unsigned short* __restrict__ A_bf, const unsigned short* __restrict__ WT,
    float* __restrict__ F)
{
  __shared__ __align__(16) unsigned short As[4096], Bs[8192];
  const int m0 = blockIdx.x * 64;
  const int n0b = blockIdx.y * 128;
  const int tid = threadIdx.x;
  const int w = tid >> 6, lane = tid & 63;
  const int wm = w >> 1, wn = w & 1;
  const int lr = lane & 15, lg = lane >> 4;
  f32x4 acc[2][4];
  #pragma unroll
  for (int mi = 0; mi < 2; ++mi)
    #pragma unroll
    for (int ni = 0; ni < 4; ++ni) acc[mi][ni] = f32x4{0.f, 0.f, 0.f, 0.f};

  for (int k0 = 0; k0 < 512; k0 += 64) {
    __syncthreads();
    for (int u = tid; u < 512; u += 256) {
      const int r = u >> 3, c = u & 7;
      *reinterpret_cast<uint4*>(&As[swz(r, c)]) =
        *reinterpret_cast<const uint4*>(&A_bf[(size_t)(m0 + r) * 512 + k0 + c * 8]);
    }
    for (int u = tid; u < 1024; u += 256) {
      const int r = u >> 3, c = u & 7;
      *reinterpret_cast<uint4*>(&Bs[swz(r, c)]) =
        *reinterpret_cast<const uint4*>(&WT[(size_t)(n0b + r) * 512 + k0 + c * 8]);
    }
    __syncthreads();
    bf16x8 a[2][2];
    #pragma unroll
    for (int mi = 0; mi < 2; ++mi) {
      const int ar = wm * 32 + mi * 16 + lr;
      a[mi][0] = ldfrag(As, ar, lg);
      a[mi][1] = ldfrag(As, ar, 4 + lg);
    }
    #pragma unroll
    for (int ni = 0; ni < 4; ++ni) {
      const int br = wn * 64 + ni * 16 + lr;
      const bf16x8 b0 = ldfrag(Bs, br, lg);
      const bf16x8 b1 = ldfrag(Bs, br, 4 + lg);
      acc[0][ni] = MFMA16(a[0][0], b0, acc[0][ni]);
      acc[0][ni] = MFMA16(a[0][1], b1, acc[0][ni]);
      acc[1][ni] = MFMA16(a[1][0], b0, acc[1][ni]);
      acc[1][ni] = MFMA16(a[1][1], b1, acc[1][ni]);
    }
  }
  const int trow = m0 >> 12;
  float* Fo = F + (size_t)trow * SZ;
  const int gmb = (m0 & 4095) + wm * 32;
  #pragma unroll
  for (int mi = 0; mi < 2; ++mi) {
    #pragma unroll
    for (int ni = 0; ni < 4; ++ni) {
      const int j = n0b + wn * 64 + ni * 16 + lr;
      const int h = j >> 6, d = j & 63;
      #pragma unroll
      for (int reg = 0; reg < 4; ++reg) {
        const int g = gmb + mi * 16 + lg * 4 + reg;
        Fo[(size_t)((((h << 2) + (g >> 10)) << 10) | (g & 1023)) * 64 + d] = acc[mi][ni][reg];
      }
    }
  }
}

// ---------------- K2a: split-K column-sum partials ----------------
// grid (32 pairs, 2 tensors, 8 segments), block 256; 128 rows per block
__global__ __launch_bounds__(256) void k_colsum_part(const float* __restrict__ F,
                                                     float* __restrict__ partial)
{
  const int pair = blockIdx.x, t = blockIdx.y, seg = blockIdx.z;
  const float* f = F + (size_t)t * SZ + (size_t)pair * 65536 + (size_t)seg * 128 * 64;
  const int tid = threadIdx.x, d = tid & 63, g = tid >> 6;
  float s = 0.f;
  #pragma unroll 4
  for (int n = g; n < 128; n += 4) s += f[((size_t)n << 6) + d];
  __shared__ float red[4][64];
  red[g][d] = s;
  __syncthreads();
  if (g == 0) {
    partial[(((size_t)t * 32 + pair) * 8 + seg) * 64 + d] =
        red[0][d] + red[1][d] + red[2][d] + red[3][d];
  }
}

// ---------------- K2b: reduce partials -> sums ----------------
// grid 16, block 256
__global__ void k_colsum_fin(const float* __restrict__ partial, float* __restrict__ sums)
{
  const int o = blockIdx.x * 256 + threadIdx.x;  // [0,4096)
  const int tp = o >> 6, d = o & 63;             // tp = t*32+pair
  const float* p = partial + ((size_t)tp * 8) * 64 + d;
  float s = 0.f;
  #pragma unroll
  for (int i = 0; i < 8; ++i) s += p[i * 64];
  sums[(size_t)tp * 64 + d] = s;
}

// ---------------- K3: derived bf16 arrays for q,k ----------------
// grid (8192, 2), block 256 (4 rows/block, one wave per row)
// BF layout (ushort): [0]=fq_n, [SZ]=fk_n, [2SZ]=f_q_c, [3SZ]=f_k_c, [4SZ]=f_v^T (from k_vt)
__global__ void k_derived(const float* __restrict__ F, const float* __restrict__ sums,
                          unsigned short* __restrict__ BF)
{
  const int t = blockIdx.y;
  const int tid = threadIdx.x, wv = tid >> 6, lane = tid & 63;
  const int row = blockIdx.x * 4 + wv;
  const float val = F[(size_t)t * SZ + ((size_t)row << 6) + lane];
  float s = val, ss = val * val;
  #pragma unroll
  for (int o = 32; o; o >>= 1) { s += __shfl_xor(s, o); ss += __shfl_xor(ss, o); }
  const float inv = 1.f / (sqrtf(ss) + 1e-8f);
  const float ctr = (t == 0) ? s * (1.f / 64.f)
                             : sums[2048 + (row >> 10) * 64 + lane] * (1.f / 1024.f);
  BF[(size_t)t * SZ + ((size_t)row << 6) + lane] = f2b(val * inv);
  BF[(size_t)(2 + t) * SZ + ((size_t)row << 6) + lane] = f2b(val - ctr);
}

// ---------------- K4: V transpose -> bf16 [pair][d=64][n=1024] ----------------
// grid (16, 32), block 256
__global__ void k_vt(const float* __restrict__ F, unsigned short* __restrict__ FVT)
{
  __shared__ float t[64][65];
  const int pair = blockIdx.y, n0 = blockIdx.x * 64;
  const int tid = threadIdx.x;
  const float* src = F + (size_t)2 * SZ + (size_t)pair * 65536 + (size_t)n0 * 64;
  for (int u = tid; u < 4096; u += 256) {
    const int r = u >> 6, d = u & 63;
    t[d][r] = src[r * 64 + d];
  }
  __syncthreads();
  unsigned short* dst = FVT + (size_t)pair * 65536;
  for (int u = tid; u < 4096; u += 256) {
    const int d = u >> 6, c = u & 63;
    dst[(size_t)d * 1024 + n0 + c] = f2b(t[d][c]);
  }
}

// ---------------- K5: score stats pass (MFMA) ----------------
// grid (16 rowtiles, 32 pairs), block 256 (4 waves, 16 q-rows each).
// stats[h*9 + i]: 0=SX 1=SXX 2=SC 3=SCC 4=SXC 5=SZ 6=SZZ 7=SZ*SXrow 8=SZ*SCrow
__global__ __launch_bounds__(256) void k_stats(const unsigned short* __restrict__ BF,
                                               double* __restrict__ stats)
{
  __shared__ __align__(16) unsigned short kn_s[4096], kc_s[4096];
  __shared__ float part[9][4];
  const int pair = blockIdx.y, h = pair >> 2;
  const int r0 = blockIdx.x * 64;
  const int tid = threadIdx.x;
  const int w = tid >> 6, lane = tid & 63;
  const int lr = lane & 15, lg = lane >> 4;
  const size_t pb = (size_t)pair * 65536;
  const unsigned short* fqn = BF + pb;
  const unsigned short* fkn = BF + (size_t)SZ + pb;
  const unsigned short* fqc = BF + (size_t)2 * SZ + pb;
  const unsigned short* fkc = BF + (size_t)3 * SZ + pb;

  // Q fragments from global (loop-invariant)
  const int qrow = r0 + w * 16 + lr;
  const unsigned short* qnp = fqn + (size_t)qrow * 64;
  const unsigned short* qcp = fqc + (size_t)qrow * 64;
  const bf16x8 qn0 = *reinterpret_cast<const bf16x8*>(qnp + lg * 8);
  const bf16x8 qn1 = *reinterpret_cast<const bf16x8*>(qnp + 32 + lg * 8);
  const bf16x8 qc0 = *reinterpret_cast<const bf16x8*>(qcp + lg * 8);
  const bf16x8 qc1 = *reinterpret_cast<const bf16x8*>(qcp + 32 + lg * 8);

  float sx = 0.f, sxx = 0.f, scv = 0.f, scc = 0.f, sxc = 0.f;
  float rxs[4] = {0, 0, 0, 0}, rcs[4] = {0, 0, 0, 0}, rms[4] = {0, 0, 0, 0};

  for (int m0 = 0; m0 < 1024; m0 += 64) {
    __syncthreads();
    for (int u = tid; u < 512; u += 256) {
      const int r = u >> 3, c = u & 7;
      const int li = swz(r, c);
      const size_t gi = ((size_t)(m0 + r) << 6) + (c << 3);
      *reinterpret_cast<uint4*>(&kn_s[li]) = *reinterpret_cast<const uint4*>(&fkn[gi]);
      *reinterpret_cast<uint4*>(&kc_s[li]) = *reinterpret_cast<const uint4*>(&fkc[gi]);
    }
    __syncthreads();
    #pragma unroll
    for (int nt = 0; nt < 4; ++nt) {
      const int krow = nt * 16 + lr;
      f32x4 dn = {0.f, 0.f, 0.f, 0.f}, dc = {0.f, 0.f, 0.f, 0.f};
      dn = MFMA16(qn0, ldfrag(kn_s, krow, lg), dn);
      dn = MFMA16(qn1, ldfrag(kn_s, krow, 4 + lg), dn);
      dc = MFMA16(qc0, ldfrag(kc_s, krow, lg), dc);
      dc = MFMA16(qc1, ldfrag(kc_s, krow, 4 + lg), dc);
      #pragma unroll
      for (int r = 0; r < 4; ++r) {
        const float X = fminf(fmaxf(dn[r], -0.98f), 0.98f);
        const float cv = dc[r] * COVS;
        sx += X; sxx += X * X; scv += cv; scc += cv * cv; sxc += X * cv;
        rxs[r] += X; rcs[r] += cv; rms[r] += fmaxf(0.01f - X, 0.f);
      }
    }
  }
  const float g0 = wredsum(sx), g1 = wredsum(sxx), g2 = wredsum(scv), g3 = wredsum(scc), g4 = wredsum(sxc);
  #pragma unroll
  for (int r = 0; r < 4; ++r) {
    #pragma unroll
    for (int o = 1; o < 16; o <<= 1) {
      rxs[r] += __shfl_xor(rxs[r], o);
      rcs[r] += __shfl_xor(rcs[r], o);
      rms[r] += __shfl_xor(rms[r], o);
    }
  }
  float z1 = 0.f, z2 = 0.f, z3 = 0.f, z4 = 0.f;
  if (lr == 0) {
    #pragma unroll
    for (int r = 0; r < 4; ++r) {
      const float Z = rms[r] * (1.f / 1024.f);
      z1 += Z; z2 += Z * Z; z3 += Z * rxs[r]; z4 += Z * rcs[r];
    }
  }
  z1 = wredsum(z1); z2 = wredsum(z2); z3 = wredsum(z3); z4 = wredsum(z4);
  if (lane == 0) {
    part[0][w] = g0; part[1][w] = g1; part[2][w] = g2; part[3][w] = g3; part[4][w] = g4;
    part[5][w] = z1; part[6][w] = z2; part[7][w] = z3; part[8][w] = z4;
  }
  __syncthreads();
  if (tid == 0) {
    #pragma unroll
    for (int i = 0; i < 9; ++i) {
      const double s = (double)part[i][0] + part[i][1] + part[i][2] + part[i][3];
      atomicAdd(&stats[h * 9 + i], s);
    }
  }
}

// ---------------- K6: weight-MLP + global std finalize -> per-head coefs ----------------
// block 512 = 8 waves, one wave per head; then tid==0 fp64 epilogue.
__global__ __launch_bounds__(512) void k_finalize(
    const float* __restrict__ sums, const double* __restrict__ stats,
    const float* __restrict__ W1, const float* __restrict__ b1,
    const float* __restrict__ lng, const float* __restrict__ lnb,
    const float* __restrict__ W2, const float* __restrict__ b2,
    const float* __restrict__ W3, const float* __restrict__ b3,
    const float* __restrict__ w_temp, float* __restrict__ coefs)
{
  __shared__ float feat[8][128];
  __shared__ float h1[8][192];
  __shared__ float y2[8][128];
  __shared__ float wsm[8][3];
  const int tid = threadIdx.x;
  const int h = tid >> 6, lane = tid & 63;

  {
    float sq = 0.f, sk = 0.f;
    #pragma unroll
    for (int b = 0; b < 4; ++b) {
      sq += sums[(h * 4 + b) * 64 + lane];
      sk += sums[2048 + (h * 4 + b) * 64 + lane];
    }
    feat[h][lane] = sq * (1.f / 4096.f);
    feat[h][64 + lane] = sk * (1.f / 4096.f);
  }
  float y1v[3];
  {
    float a0 = b1[lane], a1 = b1[lane + 64], a2 = b1[lane + 128];
    for (int i = 0; i < 128; ++i) {
      const float fv = feat[h][i];
      const float* wr = W1 + (size_t)i * 192;
      a0 += fv * wr[lane];
      a1 += fv * wr[lane + 64];
      a2 += fv * wr[lane + 128];
    }
    y1v[0] = a0; y1v[1] = a1; y1v[2] = a2;
  }
  float s = y1v[0] + y1v[1] + y1v[2];
  float ss = y1v[0]*y1v[0] + y1v[1]*y1v[1] + y1v[2]*y1v[2];
  s = wredsum(s); ss = wredsum(ss);
  const float mu = s * (1.f / 192.f);
  const float rstd = rsqrtf(ss * (1.f / 192.f) - mu * mu + 1e-5f);
  #pragma unroll
  for (int u = 0; u < 3; ++u) {
    const int j = lane + u * 64;
    h1[h][j] = fmaxf((y1v[u] - mu) * rstd * lng[j] + lnb[j], 0.f);
  }
  {
    float a0 = b2[lane], a1 = b2[lane + 64];
    for (int i = 0; i < 192; ++i) {
      const float hv = h1[h][i];
      const float* wr = W2 + (size_t)i * 128;
      a0 += hv * wr[lane];
      a1 += hv * wr[lane + 64];
    }
    y2[h][lane] = fmaxf(a0, 0.f);
    y2[h][lane + 64] = fmaxf(a1, 0.f);
  }
  {
    float l0, l1, l2;
    const float va = y2[h][lane], vb = y2[h][lane + 64];
    const float* wa = W3 + (size_t)lane * 3;
    const float* wb = W3 + (size_t)(lane + 64) * 3;
    l0 = va * wa[0] + vb * wb[0];
    l1 = va * wa[1] + vb * wb[1];
    l2 = va * wa[2] + vb * wb[2];
    l0 = wredsum(l0); l1 = wredsum(l1); l2 = wredsum(l2);
    if (lane == 0) {
      l0 += b3[0]; l1 += b3[1]; l2 += b3[2];
      float mx = fmaxf(l0, fmaxf(l1, l2));
      float e0 = expf(l0 - mx), e1 = expf(l1 - mx), e2 = expf(l2 - mx);
      float se = e0 + e1 + e2;
      const float p0 = e0 / se, p1 = e1 / se, p2 = e2 / se;
      const float wt = fminf(fmaxf(w_temp[0], 0.05f), 3.f);
      const float q0 = p0 / wt, q1 = p1 / wt, q2 = p2 / wt;
      mx = fmaxf(q0, fmaxf(q1, q2));
      e0 = expf(q0 - mx); e1 = expf(q1 - mx); e2 = expf(q2 - mx);
      se = e0 + e1 + e2;
      float w0 = e0 / se, w1 = e1 / se, w2 = e2 / se;
      w0 = fminf(fmaxf(w0, 0.05f), 0.85f);
      w1 = fminf(fmaxf(w1, 0.05f), 0.85f);
      w2 = fminf(fmaxf(w2, 0.05f), 0.85f);
      const float swt = w0 + w1 + w2;
      wsm[h][0] = w0 / swt; wsm[h][1] = w1 / swt; wsm[h][2] = w2 / swt;
    }
  }
  __syncthreads();
  if (tid == 0) {
    const double n = 33554432.0, M = 1024.0;
    double S[8][9], T[9];
    for (int i = 0; i < 9; ++i) T[i] = 0.0;
    for (int hh = 0; hh < 8; ++hh)
      for (int i = 0; i < 9; ++i) { S[hh][i] = stats[hh * 9 + i]; T[i] += S[hh][i]; }
    const double cos_norm = sqrt(fmax((T[1] - T[0] * T[0] / n) / (n - 1.0), 0.0)) + 1e-6;
    const double health = sqrt(fmax((T[3] - T[2] * T[2] / n) / (n - 1.0), 0.0));
    const double base = 0.001 / 1024.0;
    const double reg = (health < 1e-5) ? base * 8.0 : ((health < 1e-3) ? base * 3.0 : base);
    const double cov_norm = reg * health + 1e-6;  // clip(+-30) provably inactive
    const double zvar = (M * T[6] - (M * T[5]) * (M * T[5]) / n) / (n - 1.0);
    const double var_norm = sqrt(fmax(zvar, 0.0)) + 1e-6;
    const double cos_h = fmin(cos_norm, 1.2);
    const double cov_h = fmin(cov_norm * 12.0, 1.2);
    const double var_h = fmin(var_norm * 12.0, 1.2);
    double D1 = 0.0, D2 = 0.0, Ah[8], Bh[8];
    for (int hh = 0; hh < 8; ++hh) {
      const double A = (double)wsm[hh][0] * cos_h / cos_norm;
      const double Bc = (double)wsm[hh][1] * 0.5 * cov_h / cov_norm * reg;
      const double C = (double)wsm[hh][2] * 0.5 * var_h / var_norm;
      Ah[hh] = A; Bh[hh] = Bc;
      D1 += A * S[hh][0] + Bc * S[hh][2] + C * M * S[hh][5];
      D2 += A * A * S[hh][1] + Bc * Bc * S[hh][3] + C * C * M * S[hh][6]
          + 2.0 * A * Bc * S[hh][4] + 2.0 * A * C * S[hh][7] + 2.0 * Bc * C * S[hh][8];
    }
    const double divv = sqrt(fmax((D2 - D1 * D1 / n) / (n - 1.0), 0.0));
    const double temp = (divv < 5e-6) ? 0.03 : ((divv < 5e-4) ? 0.15 : 0.4);
    for (int hh = 0; hh < 8; ++hh) {
      coefs[hh] = (float)(Ah[hh] / temp);       // multiplies X
      coefs[8 + hh] = (float)(Bh[hh] / temp);   // multiplies cov_b
    }
  }
}

// ---------------- K7: attention pass (MFMA scores + online softmax + MFMA PV) ----------------
// grid (16 rowtiles, 32 pairs), block 256 (4 waves x 16 q-rows).
__global__ __launch_bounds__(256) void k_attn(const unsigned short* __restrict__ BF,
                                              const float* __restrict__ coefs,
                                              float* __restrict__ OUTF)
{
  __shared__ __align__(16) unsigned short kn_s[4096], kc_s[4096], vt_s[4096], P_s[4096];
  const int pair = blockIdx.y, h = pair >> 2;
  const int r0 = blockIdx.x * 64;
  const int tid = threadIdx.x;
  const int w = tid >> 6, lane = tid & 63;
  const int lr = lane & 15, lg = lane >> 4;
  const size_t pb = (size_t)pair * 65536;
  const unsigned short* fqn = BF + pb;
  const unsigned short* fkn = BF + (size_t)SZ + pb;
  const unsigned short* fqc = BF + (size_t)2 * SZ + pb;
  const unsigned short* fkc = BF + (size_t)3 * SZ + pb;
  const unsigned short* fvt = BF + (size_t)4 * SZ + pb;  // [d=64][n=1024]
  const float P = coefs[h], Qc = coefs[8 + h];

  // Q fragments from global (loop-invariant)
  const int qrow = r0 + w * 16 + lr;
  const unsigned short* qnp = fqn + (size_t)qrow * 64;
  const unsigned short* qcp = fqc + (size_t)qrow * 64;
  const bf16x8 qn0 = *reinterpret_cast<const bf16x8*>(qnp + lg * 8);
  const bf16x8 qn1 = *reinterpret_cast<const bf16x8*>(qnp + 32 + lg * 8);
  const bf16x8 qc0 = *reinterpret_cast<const bf16x8*>(qcp + lg * 8);
  const bf16x8 qc1 = *reinterpret_cast<const bf16x8*>(qcp + 32 + lg * 8);

  float m_r[4] = {-1e30f, -1e30f, -1e30f, -1e30f};
  float l_r[4] = {0.f, 0.f, 0.f, 0.f};
  f32x4 o[4];
  #pragma unroll
  for (int i = 0; i < 4; ++i) o[i] = f32x4{0.f, 0.f, 0.f, 0.f};

  for (int m0 = 0; m0 < 1024; m0 += 64) {
    __syncthreads();
    for (int u = tid; u < 512; u += 256) {
      const int r = u >> 3, c = u & 7;
      const int li = swz(r, c);
      const size_t gk = ((size_t)(m0 + r) << 6) + (c << 3);
      *reinterpret_cast<uint4*>(&kn_s[li]) = *reinterpret_cast<const uint4*>(&fkn[gk]);
      *reinterpret_cast<uint4*>(&kc_s[li]) = *reinterpret_cast<const uint4*>(&fkc[gk]);
      const size_t gv = (size_t)r * 1024 + m0 + (c << 3);
      *reinterpret_cast<uint4*>(&vt_s[li]) = *reinterpret_cast<const uint4*>(&fvt[gv]);
    }
    __syncthreads();

    // scores: sc[nt][r] for (q = 4*lg + r, key = nt*16 + lr)
    float sc[4][4];
    #pragma unroll
    for (int nt = 0; nt < 4; ++nt) {
      const int krow = nt * 16 + lr;
      f32x4 dn = {0.f, 0.f, 0.f, 0.f}, dc = {0.f, 0.f, 0.f, 0.f};
      dn = MFMA16(qn0, ldfrag(kn_s, krow, lg), dn);
      dn = MFMA16(qn1, ldfrag(kn_s, krow, 4 + lg), dn);
      dc = MFMA16(qc0, ldfrag(kc_s, krow, lg), dc);
      dc = MFMA16(qc1, ldfrag(kc_s, krow, 4 + lg), dc);
      #pragma unroll
      for (int r = 0; r < 4; ++r) {
        const float X = fminf(fmaxf(dn[r], -0.98f), 0.98f);
        const float cv = dc[r] * COVS;
        sc[nt][r] = P * X + Qc * cv;
      }
    }
    // online softmax over this 64-key tile
    float mxr[4], al[4], ps[4];
    #pragma unroll
    for (int r = 0; r < 4; ++r)
      mxr[r] = fmaxf(fmaxf(sc[0][r], sc[1][r]), fmaxf(sc[2][r], sc[3][r]));
    #pragma unroll
    for (int o2 = 1; o2 < 16; o2 <<= 1) {
      #pragma unroll
      for (int r = 0; r < 4; ++r) mxr[r] = fmaxf(mxr[r], __shfl_xor(mxr[r], o2));
    }
    #pragma unroll
    for (int r = 0; r < 4; ++r) {
      const float mn = fmaxf(m_r[r], mxr[r]);
      al[r] = __expf(m_r[r] - mn);
      m_r[r] = mn;
      ps[r] = 0.f;
    }
    // exp, write P (bf16) into A-frag-layout LDS tile, accumulate row sums
    #pragma unroll
    for (int nt = 0; nt < 4; ++nt) {
      #pragma unroll
      for (int r = 0; r < 4; ++r) {
        const float e = __expf(sc[nt][r] - m_r[r]);
        ps[r] += e;
        const int qb = w * 16 + 4 * lg + r;
        const int key = nt * 16 + lr;
        const int chunk = key >> 3;
        P_s[(qb << 6) + (((chunk ^ (qb & 7))) << 3) + (key & 7)] = f2b(e);
      }
    }
    #pragma unroll
    for (int o2 = 1; o2 < 16; o2 <<= 1) {
      #pragma unroll
      for (int r = 0; r < 4; ++r) ps[r] += __shfl_xor(ps[r], o2);
    }
    #pragma unroll
    for (int r = 0; r < 4; ++r) {
      l_r[r] = l_r[r] * al[r] + ps[r];
      #pragma unroll
      for (int nt2 = 0; nt2 < 4; ++nt2) o[nt2][r] *= al[r];
    }
    // PV: A = P (16q x 64key), B = V^T-tile (key x dv)
    const int parow = w * 16 + lr;
    const bf16x8 pa0 = ldfrag(P_s, parow, lg);
    const bf16x8 pa1 = ldfrag(P_s, parow, 4 + lg);
    #pragma unroll
    for (int nt2 = 0; nt2 < 4; ++nt2) {
      const int vrow = nt2 * 16 + lr;
      o[nt2] = MFMA16(pa0, ldfrag(vt_s, vrow, lg), o[nt2]);
      o[nt2] = MFMA16(pa1, ldfrag(vt_s, vrow, 4 + lg), o[nt2]);
    }
  }
  #pragma unroll
  for (int r = 0; r < 4; ++r) {
    const float inv = 1.f / l_r[r];
    const size_t orow = pb + ((size_t)(r0 + w * 16 + 4 * lg + r) << 6);
    #pragma unroll
    for (int nt2 = 0; nt2 < 4; ++nt2) {
      OUTF[orow + nt2 * 16 + lr] = o[nt2][r] * inv;
    }
  }
}

// ---------------- K_gemm_out: out = gather(OUTF) @ W_outT^T + b  (MFMA) ----------------
// grid (64, 4), block 256
__global__ __launch_bounds__(256) void k_gemm_out(
    const float* __restrict__ OUTF, const unsigned short* __restrict__ WT,
    const float* __restrict__ bias, float* __restrict__ out)
{
  __shared__ __align__(16) unsigned short As[4096], Bs[8192];
  const int m0 = blockIdx.x * 64;
  const int n0b = blockIdx.y * 128;
  const int tid = threadIdx.x;
  const int w = tid >> 6, lane = tid & 63;
  const int wm = w >> 1, wn = w & 1;
  const int lr = lane & 15, lg = lane >> 4;
  f32x4 acc[2][4];
  #pragma unroll
  for (int mi = 0; mi < 2; ++mi)
    #pragma unroll
    for (int ni = 0; ni < 4; ++ni) acc[mi][ni] = f32x4{0.f, 0.f, 0.f, 0.f};

  for (int k0 = 0; k0 < 512; k0 += 64) {
    __syncthreads();
    for (int u = tid; u < 512; u += 256) {
      const int r = u >> 3, c = u & 7;
      const int g = m0 + r;
      const int j = k0 + c * 8;
      const float4* src = reinterpret_cast<const float4*>(
          OUTF + (size_t)(((((j >> 6) << 2) + (g >> 10)) << 10) | (g & 1023)) * 64 + (j & 63));
      const float4 f0 = src[0], f1 = src[1];
      uint4 o4;
      o4.x = pk2(f0.x, f0.y); o4.y = pk2(f0.z, f0.w);
      o4.z = pk2(f1.x, f1.y); o4.w = pk2(f1.z, f1.w);
      *reinterpret_cast<uint4*>(&As[swz(r, c)]) = o4;
    }
    for (int u = tid; u < 1024; u += 256) {
      const int r = u >> 3, c = u & 7;
      *reinterpret_cast<uint4*>(&Bs[swz(r, c)]) =
        *reinterpret_cast<const uint4*>(&WT[(size_t)(n0b + r) * 512 + k0 + c * 8]);
    }
    __syncthreads();
    bf16x8 a[2][2];
    #pragma unroll
    for (int mi = 0; mi < 2; ++mi) {
      const int ar = wm * 32 + mi * 16 + lr;
      a[mi][0] = ldfrag(As, ar, lg);
      a[mi][1] = ldfrag(As, ar, 4 + lg);
    }
    #pragma unroll
    for (int ni = 0; ni < 4; ++ni) {
      const int br = wn * 64 + ni * 16 + lr;
      const bf16x8 b0 = ldfrag(Bs, br, lg);
      const bf16x8 b1 = ldfrag(Bs, br, 4 + lg);
      acc[0][ni] = MFMA16(a[0][0], b0, acc[0][ni]);
      acc[0][ni] = MFMA16(a[0][1], b1, acc[0][ni]);
      acc[1][ni] = MFMA16(a[1][0], b0, acc[1][ni]);
      acc[1][ni] = MFMA16(a[1][1], b1, acc[1][ni]);
    }
  }
  #pragma unroll
  for (int mi = 0; mi < 2; ++mi) {
    #pragma unroll
    for (int ni = 0; ni < 4; ++ni) {
      const int j = n0b + wn * 64 + ni * 16 + lr;
      const float bj = bias[j];
      #pragma unroll
      for (int reg = 0; reg < 4; ++reg) {
        const int g = m0 + wm * 32 + mi * 16 + lg * 4 + reg;
        out[(size_t)g * 512 + j] = acc[mi][ni][reg] + bj;
      }
    }
  }
}

extern "C" void kernel_launch(void* const* d_in, const int* in_sizes, int n_in,
                              void* d_out, int out_size, void* d_ws, size_t ws_size,
                              hipStream_t stream) {
  (void)in_sizes; (void)n_in; (void)out_size; (void)ws_size;
  const float* q      = (const float*)d_in[0];
  const float* k      = (const float*)d_in[1];
  const float* v      = (const float*)d_in[2];
  const float* ln_g   = (const float*)d_in[3];
  const float* ln_b   = (const float*)d_in[4];
  const float* W_in   = (const float*)d_in[5];
  const float* wp_W1  = (const float*)d_in[6];
  const float* wp_b1  = (const float*)d_in[7];
  const float* wp_lng = (const float*)d_in[8];
  const float* wp_lnb = (const float*)d_in[9];
  const float* wp_W2  = (const float*)d_in[10];
  const float* wp_b2  = (const float*)d_in[11];
  const float* wp_W3  = (const float*)d_in[12];
  const float* wp_b3  = (const float*)d_in[13];
  const float* w_temp = (const float*)d_in[14];
  const float* W_out  = (const float*)d_in[15];
  const float* b_out  = (const float*)d_in[16];

  float* ws = (float*)d_ws;
  float* F    = ws;                                  // [0, 3SZ) fp32 f_q/f_k/f_v
  float* OUTF = ws + (size_t)3 * SZ;                 // [3SZ, 4SZ) fp32 attn output
  // A_bf overlaps OUTF + fq_n region: lifetime k_ln -> k_gemm_proj, both dead then
  unsigned short* A_bf = (unsigned short*)(ws + (size_t)3 * SZ);  // 12288*512 ushorts
  unsigned short* BF = (unsigned short*)(ws + (size_t)4 * SZ);    // 5*SZ ushorts
  unsigned short* FVT = BF + (size_t)4 * SZ;         // V^T slice within BF
  float* AUX  = ws + (size_t)13631488;               // = 6.5*SZ
  float* sums  = AUX;                                // 4096 floats (qsum, ksum)
  float* coefs = AUX + 4096;                         // 64 floats
  double* stats = (double*)(AUX + 4160);             // 72 doubles
  unsigned short* WT = (unsigned short*)(AUX + 8192);  // 2 x 512x512 bf16 (ends AUX+270336)
  float* partial = AUX + 270336;                     // 2*32*8*64 = 32768 floats

  k_zero<<<1, 128, 0, stream>>>(stats);
  k_cvt<<<dim3(64, 2), 256, 0, stream>>>(W_in, W_out, WT);
  k_ln<<<3072, 256, 0, stream>>>(q, k, v, ln_g, ln_b, A_bf);
  k_gemm_proj<<<dim3(192, 4), 256, 0, stream>>>(A_bf, WT, F);
  k_colsum_part<<<dim3(32, 2, 8), 256, 0, stream>>>(F, partial);
  k_colsum_fin<<<16, 256, 0, stream>>>(partial, sums);
  k_derived<<<dim3(8192, 2), 256, 0, stream>>>(F, sums, BF);
  k_vt<<<dim3(16, 32), 256, 0, stream>>>(F, FVT);
  k_stats<<<dim3(16, 32), 256, 0, stream>>>(BF, stats);
  k_finalize<<<1, 512, 0, stream>>>(sums, stats, wp_W1, wp_b1, wp_lng, wp_lnb,
                                    wp_W2, wp_b2, wp_W3, wp_b3, w_temp, coefs);
  k_attn<<<dim3(16, 32), 256, 0, stream>>>(BF, coefs, OUTF);
  k_gemm_out<<<dim3(64, 4), 256, 0, stream>>>(OUTF, WT + 262144, b_out, (float*)d_out);
}

// Round 6
// 191.965 us; speedup vs baseline: 4.9873x; 1.0487x over previous
//
#include <hip/hip_runtime.h>
#include <math.h>

#define SZ 2097152  // 32768 rows * 64 d, per tensor slice
#define COVS (1.0f/8.000001f)

typedef __attribute__((ext_vector_type(8))) short bf16x8;
typedef __attribute__((ext_vector_type(4))) float f32x4;
#define MFMA16(A,B,C) __builtin_amdgcn_mfma_f32_16x16x32_bf16(A,B,C,0,0,0)

__device__ __forceinline__ unsigned short f2b(float x) {
  unsigned int u = __float_as_uint(x);
  u = (u + 0x7fffu + ((u >> 16) & 1u)) >> 16;  // RNE
  return (unsigned short)u;
}
__device__ __forceinline__ unsigned int pk2(float a, float b) {
  return (unsigned int)f2b(a) | ((unsigned int)f2b(b) << 16);
}
#define B2FL(u) __uint_as_float(((unsigned)(u)) << 16)

__device__ __forceinline__ float wredsum(float v) {
  #pragma unroll
  for (int o = 32; o; o >>= 1) v += __shfl_xor(v, o);
  return v;
}

// swizzled ushort index into a [rows][64 col] bf16 LDS tile (row = 8 chunks of 16B)
__device__ __forceinline__ int swz(int r, int c) { return (r << 6) + ((c ^ (r & 7)) << 3); }

__device__ __forceinline__ bf16x8 ldfrag(const unsigned short* s, int row, int chunk) {
  return *reinterpret_cast<const bf16x8*>(&s[swz(row, chunk)]);
}

// ---------------- K0: zero stat accumulators ----------------
__global__ void k_zero(double* __restrict__ stats) {
  int i = threadIdx.x;
  if (i < 72) stats[i] = 0.0;
}

// ---------------- K_cvt: WT[n][k] = bf16(W[k][n]) for W_in and W_out ----------------
// grid (64, 2), block 256
__global__ void k_cvt(const float* __restrict__ Win, const float* __restrict__ Wout,
                      unsigned short* __restrict__ WT)
{
  __shared__ float t[64][65];
  const int k0 = (blockIdx.x & 7) << 6, n0 = (blockIdx.x >> 3) << 6;
  const float* W = blockIdx.y ? Wout : Win;
  unsigned short* dst = WT + (size_t)blockIdx.y * 262144;
  const int tid = threadIdx.x;
  for (int u = tid; u < 4096; u += 256) {
    const int r = u >> 6, c = u & 63;
    t[c][r] = W[(size_t)(k0 + r) * 512 + n0 + c];
  }
  __syncthreads();
  for (int u = tid; u < 4096; u += 256) {
    const int r = u >> 6, c = u & 63;
    dst[(size_t)(n0 + r) * 512 + k0 + c] = f2b(t[r][c]);
  }
}

// ---------------- K_ln: A_bf[row][512] = bf16(LN(x)) for q,k,v rows ----------------
// grid 3072, block 256 (1 wave per row)
__global__ __launch_bounds__(256) void k_ln(
    const float* __restrict__ q, const float* __restrict__ k, const float* __restrict__ v,
    const float* __restrict__ ln_g, const float* __restrict__ ln_b,
    unsigned short* __restrict__ A_bf)
{
  const int tid = threadIdx.x, wv = tid >> 6, lane = tid & 63;
  const int row = blockIdx.x * 4 + wv;
  const int t = row >> 12, g = row & 4095;
  const float* x = (t == 0) ? q : (t == 1) ? k : v;
  const float4* xr = reinterpret_cast<const float4*>(x + (size_t)g * 512);
  const float4 a0 = xr[2 * lane], a1 = xr[2 * lane + 1];
  float s  = a0.x + a0.y + a0.z + a0.w + a1.x + a1.y + a1.z + a1.w;
  float ss = a0.x*a0.x + a0.y*a0.y + a0.z*a0.z + a0.w*a0.w
           + a1.x*a1.x + a1.y*a1.y + a1.z*a1.z + a1.w*a1.w;
  #pragma unroll
  for (int o = 32; o; o >>= 1) { s += __shfl_xor(s, o); ss += __shfl_xor(ss, o); }
  const float mu = s * (1.f / 512.f);
  const float rstd = rsqrtf(ss * (1.f / 512.f) - mu * mu + 1e-5f);
  const float4* gg = reinterpret_cast<const float4*>(ln_g);
  const float4* bb = reinterpret_cast<const float4*>(ln_b);
  const float4 g0 = gg[2 * lane], g1 = gg[2 * lane + 1];
  const float4 b0 = bb[2 * lane], b1 = bb[2 * lane + 1];
  uint4 o4;
  o4.x = pk2((a0.x - mu) * rstd * g0.x + b0.x, (a0.y - mu) * rstd * g0.y + b0.y);
  o4.y = pk2((a0.z - mu) * rstd * g0.z + b0.z, (a0.w - mu) * rstd * g0.w + b0.w);
  o4.z = pk2((a1.x - mu) * rstd * g1.x + b1.x, (a1.y - mu) * rstd * g1.y + b1.y);
  o4.w = pk2((a1.z - mu) * rstd * g1.z + b1.z, (a1.w - mu) * rstd * g1.w + b1.w);
  *reinterpret_cast<uint4*>(&A_bf[(size_t)row * 512 + lane * 8]) = o4;
}

// ---------------- K_gemm_proj: F = A_bf @ W_inT^T  (MFMA) ----------------
// grid (192, 4), block 256 (2x2 waves, 64x128 tile, K=512 in chunks of 64)
__global__ __launch_bounds__(256) void k_gemm_proj(
    const unsigned short* __restrict__ A_bf, const unsigned short* __restrict__ WT,
    float* __restrict__ F)
{
  __shared__ __align__(16) unsigned short As[4096], Bs[8192];
  const int m0 = blockIdx.x * 64;
  const int n0b = blockIdx.y * 128;
  const int tid = threadIdx.x;
  const int w = tid >> 6, lane = tid & 63;
  const int wm = w >> 1, wn = w & 1;
  const int lr = lane & 15, lg = lane >> 4;
  f32x4 acc[2][4];
  #pragma unroll
  for (int mi = 0; mi < 2; ++mi)
    #pragma unroll
    for (int ni = 0; ni < 4; ++ni) acc[mi][ni] = f32x4{0.f, 0.f, 0.f, 0.f};

  for (int k0 = 0; k0 < 512; k0 += 64) {
    __syncthreads();
    for (int u = tid; u < 512; u += 256) {
      const int r = u >> 3, c = u & 7;
      *reinterpret_cast<uint4*>(&As[swz(r, c)]) =
        *reinterpret_cast<const uint4*>(&A_bf[(size_t)(m0 + r) * 512 + k0 + c * 8]);
    }
    for (int u = tid; u < 1024; u += 256) {
      const int r = u >> 3, c = u & 7;
      *reinterpret_cast<uint4*>(&Bs[swz(r, c)]) =
        *reinterpret_cast<const uint4*>(&WT[(size_t)(n0b + r) * 512 + k0 + c * 8]);
    }
    __syncthreads();
    bf16x8 a[2][2];
    #pragma unroll
    for (int mi = 0; mi < 2; ++mi) {
      const int ar = wm * 32 + mi * 16 + lr;
      a[mi][0] = ldfrag(As, ar, lg);
      a[mi][1] = ldfrag(As, ar, 4 + lg);
    }
    #pragma unroll
    for (int ni = 0; ni < 4; ++ni) {
      const int br = wn * 64 + ni * 16 + lr;
      const bf16x8 b0 = ldfrag(Bs, br, lg);
      const bf16x8 b1 = ldfrag(Bs, br, 4 + lg);
      acc[0][ni] = MFMA16(a[0][0], b0, acc[0][ni]);
      acc[0][ni] = MFMA16(a[0][1], b1, acc[0][ni]);
      acc[1][ni] = MFMA16(a[1][0], b0, acc[1][ni]);
      acc[1][ni] = MFMA16(a[1][1], b1, acc[1][ni]);
    }
  }
  const int trow = m0 >> 12;
  float* Fo = F + (size_t)trow * SZ;
  const int gmb = (m0 & 4095) + wm * 32;
  #pragma unroll
  for (int mi = 0; mi < 2; ++mi) {
    #pragma unroll
    for (int ni = 0; ni < 4; ++ni) {
      const int j = n0b + wn * 64 + ni * 16 + lr;
      const int h = j >> 6, d = j & 63;
      #pragma unroll
      for (int reg = 0; reg < 4; ++reg) {
        const int g = gmb + mi * 16 + lg * 4 + reg;
        Fo[(size_t)((((h << 2) + (g >> 10)) << 10) | (g & 1023)) * 64 + d] = acc[mi][ni][reg];
      }
    }
  }
}

// ---------------- K2a: split-K column-sum partials ----------------
// grid (32 pairs, 2 tensors, 8 segments), block 256; 128 rows per block
__global__ __launch_bounds__(256) void k_colsum_part(const float* __restrict__ F,
                                                     float* __restrict__ partial)
{
  const int pair = blockIdx.x, t = blockIdx.y, seg = blockIdx.z;
  const float* f = F + (size_t)t * SZ + (size_t)pair * 65536 + (size_t)seg * 128 * 64;
  const int tid = threadIdx.x, d = tid & 63, g = tid >> 6;
  float s = 0.f;
  #pragma unroll 4
  for (int n = g; n < 128; n += 4) s += f[((size_t)n << 6) + d];
  __shared__ float red[4][64];
  red[g][d] = s;
  __syncthreads();
  if (g == 0) {
    partial[(((size_t)t * 32 + pair) * 8 + seg) * 64 + d] =
        red[0][d] + red[1][d] + red[2][d] + red[3][d];
  }
}

// ---------------- K2b: reduce partials -> sums ----------------
// grid 16, block 256
__global__ void k_colsum_fin(const float* __restrict__ partial, float* __restrict__ sums)
{
  const int o = blockIdx.x * 256 + threadIdx.x;  // [0,4096)
  const int tp = o >> 6, d = o & 63;             // tp = t*32+pair
  const float* p = partial + ((size_t)tp * 8) * 64 + d;
  float s = 0.f;
  #pragma unroll
  for (int i = 0; i < 8; ++i) s += p[i * 64];
  sums[(size_t)tp * 64 + d] = s;
}

// ---------------- K3: derived bf16 arrays for q,k ----------------
// grid (8192, 2), block 256 (4 rows/block, one wave per row)
// BF layout (ushort): [0]=fq_n, [SZ]=fk_n, [2SZ]=f_q_c, [3SZ]=f_k_c, [4SZ]=f_v^T (from k_vt)
__global__ void k_derived(const float* __restrict__ F, const float* __restrict__ sums,
                          unsigned short* __restrict__ BF)
{
  const int t = blockIdx.y;
  const int tid = threadIdx.x, wv = tid >> 6, lane = tid & 63;
  const int row = blockIdx.x * 4 + wv;
  const float val = F[(size_t)t * SZ + ((size_t)row << 6) + lane];
  float s = val, ss = val * val;
  #pragma unroll
  for (int o = 32; o; o >>= 1) { s += __shfl_xor(s, o); ss += __shfl_xor(ss, o); }
  const float inv = 1.f / (sqrtf(ss) + 1e-8f);
  const float ctr = (t == 0) ? s * (1.f / 64.f)
                             : sums[2048 + (row >> 10) * 64 + lane] * (1.f / 1024.f);
  BF[(size_t)t * SZ + ((size_t)row << 6) + lane] = f2b(val * inv);
  BF[(size_t)(2 + t) * SZ + ((size_t)row << 6) + lane] = f2b(val - ctr);
}

// ---------------- K4: V transpose -> bf16 [pair][d=64][n=1024] ----------------
// grid (16, 32), block 256
__global__ void k_vt(const float* __restrict__ F, unsigned short* __restrict__ FVT)
{
  __shared__ float t[64][65];
  const int pair = blockIdx.y, n0 = blockIdx.x * 64;
  const int tid = threadIdx.x;
  const float* src = F + (size_t)2 * SZ + (size_t)pair * 65536 + (size_t)n0 * 64;
  for (int u = tid; u < 4096; u += 256) {
    const int r = u >> 6, d = u & 63;
    t[d][r] = src[r * 64 + d];
  }
  __syncthreads();
  unsigned short* dst = FVT + (size_t)pair * 65536;
  for (int u = tid; u < 4096; u += 256) {
    const int d = u >> 6, c = u & 63;
    dst[(size_t)d * 1024 + n0 + c] = f2b(t[d][c]);
  }
}

// ---------------- K5: score stats pass (MFMA), key-split 2-way ----------------
// grid (16 rowtiles, 32 pairs, 2 key-segs), block 256 (4 waves, 16 q-rows each).
// linear stats[h*9+0..4] via atomicAdd; per-row partials (margin,x,c) -> rowpart
__global__ __launch_bounds__(256) void k_stats(const unsigned short* __restrict__ BF,
                                               double* __restrict__ stats,
                                               float* __restrict__ rowpart)
{
  __shared__ __align__(16) unsigned short kn_s[4096], kc_s[4096];
  __shared__ float part[5][4];
  const int pair = blockIdx.y, h = pair >> 2, seg = blockIdx.z;
  const int r0 = blockIdx.x * 64;
  const int tid = threadIdx.x;
  const int w = tid >> 6, lane = tid & 63;
  const int lr = lane & 15, lg = lane >> 4;
  const size_t pb = (size_t)pair * 65536;
  const unsigned short* fqn = BF + pb;
  const unsigned short* fkn = BF + (size_t)SZ + pb;
  const unsigned short* fqc = BF + (size_t)2 * SZ + pb;
  const unsigned short* fkc = BF + (size_t)3 * SZ + pb;

  // Q fragments from global (loop-invariant)
  const int qrow = r0 + w * 16 + lr;
  const unsigned short* qnp = fqn + (size_t)qrow * 64;
  const unsigned short* qcp = fqc + (size_t)qrow * 64;
  const bf16x8 qn0 = *reinterpret_cast<const bf16x8*>(qnp + lg * 8);
  const bf16x8 qn1 = *reinterpret_cast<const bf16x8*>(qnp + 32 + lg * 8);
  const bf16x8 qc0 = *reinterpret_cast<const bf16x8*>(qcp + lg * 8);
  const bf16x8 qc1 = *reinterpret_cast<const bf16x8*>(qcp + 32 + lg * 8);

  float sx = 0.f, sxx = 0.f, scv = 0.f, scc = 0.f, sxc = 0.f;
  float rxs[4] = {0, 0, 0, 0}, rcs[4] = {0, 0, 0, 0}, rms[4] = {0, 0, 0, 0};

  const int mbeg = seg << 9;
  for (int m0 = mbeg; m0 < mbeg + 512; m0 += 64) {
    __syncthreads();
    for (int u = tid; u < 512; u += 256) {
      const int r = u >> 3, c = u & 7;
      const int li = swz(r, c);
      const size_t gi = ((size_t)(m0 + r) << 6) + (c << 3);
      *reinterpret_cast<uint4*>(&kn_s[li]) = *reinterpret_cast<const uint4*>(&fkn[gi]);
      *reinterpret_cast<uint4*>(&kc_s[li]) = *reinterpret_cast<const uint4*>(&fkc[gi]);
    }
    __syncthreads();
    #pragma unroll
    for (int nt = 0; nt < 4; ++nt) {
      const int krow = nt * 16 + lr;
      f32x4 dn = {0.f, 0.f, 0.f, 0.f}, dc = {0.f, 0.f, 0.f, 0.f};
      dn = MFMA16(qn0, ldfrag(kn_s, krow, lg), dn);
      dn = MFMA16(qn1, ldfrag(kn_s, krow, 4 + lg), dn);
      dc = MFMA16(qc0, ldfrag(kc_s, krow, lg), dc);
      dc = MFMA16(qc1, ldfrag(kc_s, krow, 4 + lg), dc);
      #pragma unroll
      for (int r = 0; r < 4; ++r) {
        const float X = fminf(fmaxf(dn[r], -0.98f), 0.98f);
        const float cv = dc[r] * COVS;
        sx += X; sxx += X * X; scv += cv; scc += cv * cv; sxc += X * cv;
        rxs[r] += X; rcs[r] += cv; rms[r] += fmaxf(0.01f - X, 0.f);
      }
    }
  }
  const float g0 = wredsum(sx), g1 = wredsum(sxx), g2 = wredsum(scv), g3 = wredsum(scc), g4 = wredsum(sxc);
  #pragma unroll
  for (int r = 0; r < 4; ++r) {
    #pragma unroll
    for (int o = 1; o < 16; o <<= 1) {
      rxs[r] += __shfl_xor(rxs[r], o);
      rcs[r] += __shfl_xor(rcs[r], o);
      rms[r] += __shfl_xor(rms[r], o);
    }
  }
  if (lr == 0) {
    #pragma unroll
    for (int r = 0; r < 4; ++r) {
      const int grow = pair * 1024 + r0 + w * 16 + 4 * lg + r;
      const int sb = seg * 98304;
      rowpart[sb + grow] = rms[r];
      rowpart[sb + 32768 + grow] = rxs[r];
      rowpart[sb + 65536 + grow] = rcs[r];
    }
  }
  if (lane == 0) {
    part[0][w] = g0; part[1][w] = g1; part[2][w] = g2; part[3][w] = g3; part[4][w] = g4;
  }
  __syncthreads();
  if (tid == 0) {
    #pragma unroll
    for (int i = 0; i < 5; ++i) {
      const double s = (double)part[i][0] + part[i][1] + part[i][2] + part[i][3];
      atomicAdd(&stats[h * 9 + i], s);
    }
  }
}

// ---------------- K5b: per-row Z moments -> stats[h*9+5..8] ----------------
// grid 128, block 256 (each block = 256 consecutive rows, single head)
__global__ __launch_bounds__(256) void k_stats_fin(const float* __restrict__ rp,
                                                   double* __restrict__ stats)
{
  __shared__ float red[4][4];
  const int tid = threadIdx.x;
  const int row = blockIdx.x * 256 + tid;
  const int h = row >> 12;
  const float rms = rp[row] + rp[98304 + row];
  const float rxs = rp[32768 + row] + rp[98304 + 32768 + row];
  const float rcs = rp[65536 + row] + rp[98304 + 65536 + row];
  const float Z = rms * (1.f / 1024.f);
  float z1 = Z, z2 = Z * Z, z3 = Z * rxs, z4 = Z * rcs;
  z1 = wredsum(z1); z2 = wredsum(z2); z3 = wredsum(z3); z4 = wredsum(z4);
  const int w = tid >> 6, lane = tid & 63;
  if (lane == 0) { red[0][w] = z1; red[1][w] = z2; red[2][w] = z3; red[3][w] = z4; }
  __syncthreads();
  if (tid == 0) {
    #pragma unroll
    for (int i = 0; i < 4; ++i) {
      const double s = (double)red[i][0] + red[i][1] + red[i][2] + red[i][3];
      atomicAdd(&stats[h * 9 + 5 + i], s);
    }
  }
}

// ---------------- K6: weight-MLP + global std finalize -> per-head coefs ----------------
// block 512 = 8 waves, one wave per head; then tid==0 fp64 epilogue.
__global__ __launch_bounds__(512) void k_finalize(
    const float* __restrict__ sums, const double* __restrict__ stats,
    const float* __restrict__ W1, const float* __restrict__ b1,
    const float* __restrict__ lng, const float* __restrict__ lnb,
    const float* __restrict__ W2, const float* __restrict__ b2,
    const float* __restrict__ W3, const float* __restrict__ b3,
    const float* __restrict__ w_temp, float* __restrict__ coefs)
{
  __shared__ float feat[8][128];
  __shared__ float h1[8][192];
  __shared__ float y2[8][128];
  __shared__ float wsm[8][3];
  const int tid = threadIdx.x;
  const int h = tid >> 6, lane = tid & 63;

  {
    float sq = 0.f, sk = 0.f;
    #pragma unroll
    for (int b = 0; b < 4; ++b) {
      sq += sums[(h * 4 + b) * 64 + lane];
      sk += sums[2048 + (h * 4 + b) * 64 + lane];
    }
    feat[h][lane] = sq * (1.f / 4096.f);
    feat[h][64 + lane] = sk * (1.f / 4096.f);
  }
  float y1v[3];
  {
    float a0 = b1[lane], a1 = b1[lane + 64], a2 = b1[lane + 128];
    for (int i = 0; i < 128; ++i) {
      const float fv = feat[h][i];
      const float* wr = W1 + (size_t)i * 192;
      a0 += fv * wr[lane];
      a1 += fv * wr[lane + 64];
      a2 += fv * wr[lane + 128];
    }
    y1v[0] = a0; y1v[1] = a1; y1v[2] = a2;
  }
  float s = y1v[0] + y1v[1] + y1v[2];
  float ss = y1v[0]*y1v[0] + y1v[1]*y1v[1] + y1v[2]*y1v[2];
  s = wredsum(s); ss = wredsum(ss);
  const float mu = s * (1.f / 192.f);
  const float rstd = rsqrtf(ss * (1.f / 192.f) - mu * mu + 1e-5f);
  #pragma unroll
  for (int u = 0; u < 3; ++u) {
    const int j = lane + u * 64;
    h1[h][j] = fmaxf((y1v[u] - mu) * rstd * lng[j] + lnb[j], 0.f);
  }
  {
    float a0 = b2[lane], a1 = b2[lane + 64];
    for (int i = 0; i < 192; ++i) {
      const float hv = h1[h][i];
      const float* wr = W2 + (size_t)i * 128;
      a0 += hv * wr[lane];
      a1 += hv * wr[lane + 64];
    }
    y2[h][lane] = fmaxf(a0, 0.f);
    y2[h][lane + 64] = fmaxf(a1, 0.f);
  }
  {
    float l0, l1, l2;
    const float va = y2[h][lane], vb = y2[h][lane + 64];
    const float* wa = W3 + (size_t)lane * 3;
    const float* wb = W3 + (size_t)(lane + 64) * 3;
    l0 = va * wa[0] + vb * wb[0];
    l1 = va * wa[1] + vb * wb[1];
    l2 = va * wa[2] + vb * wb[2];
    l0 = wredsum(l0); l1 = wredsum(l1); l2 = wredsum(l2);
    if (lane == 0) {
      l0 += b3[0]; l1 += b3[1]; l2 += b3[2];
      float mx = fmaxf(l0, fmaxf(l1, l2));
      float e0 = expf(l0 - mx), e1 = expf(l1 - mx), e2 = expf(l2 - mx);
      float se = e0 + e1 + e2;
      const float p0 = e0 / se, p1 = e1 / se, p2 = e2 / se;
      const float wt = fminf(fmaxf(w_temp[0], 0.05f), 3.f);
      const float q0 = p0 / wt, q1 = p1 / wt, q2 = p2 / wt;
      mx = fmaxf(q0, fmaxf(q1, q2));
      e0 = expf(q0 - mx); e1 = expf(q1 - mx); e2 = expf(q2 - mx);
      se = e0 + e1 + e2;
      float w0 = e0 / se, w1 = e1 / se, w2 = e2 / se;
      w0 = fminf(fmaxf(w0, 0.05f), 0.85f);
      w1 = fminf(fmaxf(w1, 0.05f), 0.85f);
      w2 = fminf(fmaxf(w2, 0.05f), 0.85f);
      const float swt = w0 + w1 + w2;
      wsm[h][0] = w0 / swt; wsm[h][1] = w1 / swt; wsm[h][2] = w2 / swt;
    }
  }
  __syncthreads();
  if (tid == 0) {
    const double n = 33554432.0, M = 1024.0;
    double S[8][9], T[9];
    for (int i = 0; i < 9; ++i) T[i] = 0.0;
    for (int hh = 0; hh < 8; ++hh)
      for (int i = 0; i < 9; ++i) { S[hh][i] = stats[hh * 9 + i]; T[i] += S[hh][i]; }
    const double cos_norm = sqrt(fmax((T[1] - T[0] * T[0] / n) / (n - 1.0), 0.0)) + 1e-6;
    const double health = sqrt(fmax((T[3] - T[2] * T[2] / n) / (n - 1.0), 0.0));
    const double base = 0.001 / 1024.0;
    const double reg = (health < 1e-5) ? base * 8.0 : ((health < 1e-3) ? base * 3.0 : base);
    const double cov_norm = reg * health + 1e-6;  // clip(+-30) provably inactive
    const double zvar = (M * T[6] - (M * T[5]) * (M * T[5]) / n) / (n - 1.0);
    const double var_norm = sqrt(fmax(zvar, 0.0)) + 1e-6;
    const double cos_h = fmin(cos_norm, 1.2);
    const double cov_h = fmin(cov_norm * 12.0, 1.2);
    const double var_h = fmin(var_norm * 12.0, 1.2);
    double D1 = 0.0, D2 = 0.0, Ah[8], Bh[8];
    for (int hh = 0; hh < 8; ++hh) {
      const double A = (double)wsm[hh][0] * cos_h / cos_norm;
      const double Bc = (double)wsm[hh][1] * 0.5 * cov_h / cov_norm * reg;
      const double C = (double)wsm[hh][2] * 0.5 * var_h / var_norm;
      Ah[hh] = A; Bh[hh] = Bc;
      D1 += A * S[hh][0] + Bc * S[hh][2] + C * M * S[hh][5];
      D2 += A * A * S[hh][1] + Bc * Bc * S[hh][3] + C * C * M * S[hh][6]
          + 2.0 * A * Bc * S[hh][4] + 2.0 * A * C * S[hh][7] + 2.0 * Bc * C * S[hh][8];
    }
    const double divv = sqrt(fmax((D2 - D1 * D1 / n) / (n - 1.0), 0.0));
    const double temp = (divv < 5e-6) ? 0.03 : ((divv < 5e-4) ? 0.15 : 0.4);
    for (int hh = 0; hh < 8; ++hh) {
      coefs[hh] = (float)(Ah[hh] / temp);       // multiplies X
      coefs[8 + hh] = (float)(Bh[hh] / temp);   // multiplies cov_b
    }
  }
}

// ---------------- K7: attention pass, key-split 2-way (flash partials) ----------------
// grid (16 rowtiles, 32 pairs, 2 key-segs), block 256 (4 waves x 16 q-rows).
__global__ __launch_bounds__(256) void k_attn(const unsigned short* __restrict__ BF,
                                              const float* __restrict__ coefs,
                                              float* __restrict__ po,
                                              float2* __restrict__ pml)
{
  __shared__ __align__(16) unsigned short kn_s[4096], kc_s[4096], vt_s[4096], P_s[4096];
  const int pair = blockIdx.y, h = pair >> 2, seg = blockIdx.z;
  const int r0 = blockIdx.x * 64;
  const int tid = threadIdx.x;
  const int w = tid >> 6, lane = tid & 63;
  const int lr = lane & 15, lg = lane >> 4;
  const size_t pb = (size_t)pair * 65536;
  const unsigned short* fqn = BF + pb;
  const unsigned short* fkn = BF + (size_t)SZ + pb;
  const unsigned short* fqc = BF + (size_t)2 * SZ + pb;
  const unsigned short* fkc = BF + (size_t)3 * SZ + pb;
  const unsigned short* fvt = BF + (size_t)4 * SZ + pb;  // [d=64][n=1024]
  const float P = coefs[h], Qc = coefs[8 + h];

  // Q fragments from global (loop-invariant)
  const int qrow = r0 + w * 16 + lr;
  const unsigned short* qnp = fqn + (size_t)qrow * 64;
  const unsigned short* qcp = fqc + (size_t)qrow * 64;
  const bf16x8 qn0 = *reinterpret_cast<const bf16x8*>(qnp + lg * 8);
  const bf16x8 qn1 = *reinterpret_cast<const bf16x8*>(qnp + 32 + lg * 8);
  const bf16x8 qc0 = *reinterpret_cast<const bf16x8*>(qcp + lg * 8);
  const bf16x8 qc1 = *reinterpret_cast<const bf16x8*>(qcp + 32 + lg * 8);

  float m_r[4] = {-1e30f, -1e30f, -1e30f, -1e30f};
  float l_r[4] = {0.f, 0.f, 0.f, 0.f};
  f32x4 o[4];
  #pragma unroll
  for (int i = 0; i < 4; ++i) o[i] = f32x4{0.f, 0.f, 0.f, 0.f};

  const int mbeg = seg << 9;
  for (int m0 = mbeg; m0 < mbeg + 512; m0 += 64) {
    __syncthreads();
    for (int u = tid; u < 512; u += 256) {
      const int r = u >> 3, c = u & 7;
      const int li = swz(r, c);
      const size_t gk = ((size_t)(m0 + r) << 6) + (c << 3);
      *reinterpret_cast<uint4*>(&kn_s[li]) = *reinterpret_cast<const uint4*>(&fkn[gk]);
      *reinterpret_cast<uint4*>(&kc_s[li]) = *reinterpret_cast<const uint4*>(&fkc[gk]);
      const size_t gv = (size_t)r * 1024 + m0 + (c << 3);
      *reinterpret_cast<uint4*>(&vt_s[li]) = *reinterpret_cast<const uint4*>(&fvt[gv]);
    }
    __syncthreads();

    // scores: sc[nt][r] for (q = 4*lg + r, key = nt*16 + lr)
    float sc[4][4];
    #pragma unroll
    for (int nt = 0; nt < 4; ++nt) {
      const int krow = nt * 16 + lr;
      f32x4 dn = {0.f, 0.f, 0.f, 0.f}, dc = {0.f, 0.f, 0.f, 0.f};
      dn = MFMA16(qn0, ldfrag(kn_s, krow, lg), dn);
      dn = MFMA16(qn1, ldfrag(kn_s, krow, 4 + lg), dn);
      dc = MFMA16(qc0, ldfrag(kc_s, krow, lg), dc);
      dc = MFMA16(qc1, ldfrag(kc_s, krow, 4 + lg), dc);
      #pragma unroll
      for (int r = 0; r < 4; ++r) {
        const float X = fminf(fmaxf(dn[r], -0.98f), 0.98f);
        const float cv = dc[r] * COVS;
        sc[nt][r] = P * X + Qc * cv;
      }
    }
    // online softmax over this 64-key tile
    float mxr[4], al[4], ps[4];
    #pragma unroll
    for (int r = 0; r < 4; ++r)
      mxr[r] = fmaxf(fmaxf(sc[0][r], sc[1][r]), fmaxf(sc[2][r], sc[3][r]));
    #pragma unroll
    for (int o2 = 1; o2 < 16; o2 <<= 1) {
      #pragma unroll
      for (int r = 0; r < 4; ++r) mxr[r] = fmaxf(mxr[r], __shfl_xor(mxr[r], o2));
    }
    #pragma unroll
    for (int r = 0; r < 4; ++r) {
      const float mn = fmaxf(m_r[r], mxr[r]);
      al[r] = __expf(m_r[r] - mn);
      m_r[r] = mn;
      ps[r] = 0.f;
    }
    // exp, write P (bf16) into A-frag-layout LDS tile, accumulate row sums
    #pragma unroll
    for (int nt = 0; nt < 4; ++nt) {
      #pragma unroll
      for (int r = 0; r < 4; ++r) {
        const float e = __expf(sc[nt][r] - m_r[r]);
        ps[r] += e;
        const int qb = w * 16 + 4 * lg + r;
        const int key = nt * 16 + lr;
        const int chunk = key >> 3;
        P_s[(qb << 6) + (((chunk ^ (qb & 7))) << 3) + (key & 7)] = f2b(e);
      }
    }
    #pragma unroll
    for (int o2 = 1; o2 < 16; o2 <<= 1) {
      #pragma unroll
      for (int r = 0; r < 4; ++r) ps[r] += __shfl_xor(ps[r], o2);
    }
    #pragma unroll
    for (int r = 0; r < 4; ++r) {
      l_r[r] = l_r[r] * al[r] + ps[r];
      #pragma unroll
      for (int nt2 = 0; nt2 < 4; ++nt2) o[nt2][r] *= al[r];
    }
    // PV: A = P (16q x 64key), B = V^T-tile (key x dv)
    const int parow = w * 16 + lr;
    const bf16x8 pa0 = ldfrag(P_s, parow, lg);
    const bf16x8 pa1 = ldfrag(P_s, parow, 4 + lg);
    #pragma unroll
    for (int nt2 = 0; nt2 < 4; ++nt2) {
      const int vrow = nt2 * 16 + lr;
      o[nt2] = MFMA16(pa0, ldfrag(vt_s, vrow, lg), o[nt2]);
      o[nt2] = MFMA16(pa1, ldfrag(vt_s, vrow, 4 + lg), o[nt2]);
    }
  }
  const size_t sb = (size_t)seg * SZ;
  #pragma unroll
  for (int r = 0; r < 4; ++r) {
    const int lrow = w * 16 + 4 * lg + r;
    const size_t orow = sb + pb + ((size_t)(r0 + lrow) << 6);
    #pragma unroll
    for (int nt2 = 0; nt2 < 4; ++nt2) {
      po[orow + nt2 * 16 + lr] = o[nt2][r];
    }
    if (lr == 0) {
      pml[(seg << 15) + pair * 1024 + r0 + lrow] = float2{m_r[r], l_r[r]};
    }
  }
}

// ---------------- K7b: combine the 2 key-seg partials ----------------
// grid 2048, block 256: 1024 elements (16 rows) per block, float4 per thread
__global__ __launch_bounds__(256) void k_attn_comb(const float* __restrict__ po,
                                                   const float2* __restrict__ pml,
                                                   float* __restrict__ OUTF)
{
  __shared__ float s0[16], s1[16];
  const int tid = threadIdx.x;
  const int row0 = (blockIdx.x * 1024) >> 6;
  if (tid < 16) {
    const int row = row0 + tid;
    const float2 a = pml[row], b = pml[32768 + row];
    const float M = fmaxf(a.x, b.x);
    const float ca = __expf(a.x - M), cb = __expf(b.x - M);
    const float L = a.y * ca + b.y * cb;
    s0[tid] = ca / L;
    s1[tid] = cb / L;
  }
  __syncthreads();
  const size_t idx = (size_t)blockIdx.x * 1024 + tid * 4;
  const int lrw = tid >> 4;
  const float4 oa = *reinterpret_cast<const float4*>(po + idx);
  const float4 ob = *reinterpret_cast<const float4*>(po + (size_t)SZ + idx);
  float4 oo;
  oo.x = oa.x * s0[lrw] + ob.x * s1[lrw];
  oo.y = oa.y * s0[lrw] + ob.y * s1[lrw];
  oo.z = oa.z * s0[lrw] + ob.z * s1[lrw];
  oo.w = oa.w * s0[lrw] + ob.w * s1[lrw];
  *reinterpret_cast<float4*>(OUTF + idx) = oo;
}

// ---------------- K_gemm_out: out = gather(OUTF) @ W_outT^T + b  (MFMA) ----------------
// grid (64, 4), block 256
__global__ __launch_bounds__(256) void k_gemm_out(
    const float* __restrict__ OUTF, const unsigned short* __restrict__ WT,
    const float* __restrict__ bias, float* __restrict__ out)
{
  __shared__ __align__(16) unsigned short As[4096], Bs[8192];
  const int m0 = blockIdx.x * 64;
  const int n0b = blockIdx.y * 128;
  const int tid = threadIdx.x;
  const int w = tid >> 6, lane = tid & 63;
  const int wm = w >> 1, wn = w & 1;
  const int lr = lane & 15, lg = lane >> 4;
  f32x4 acc[2][4];
  #pragma unroll
  for (int mi = 0; mi < 2; ++mi)
    #pragma unroll
    for (int ni = 0; ni < 4; ++ni) acc[mi][ni] = f32x4{0.f, 0.f, 0.f, 0.f};

  for (int k0 = 0; k0 < 512; k0 += 64) {
    __syncthreads();
    for (int u = tid; u < 512; u += 256) {
      const int r = u >> 3, c = u & 7;
      const int g = m0 + r;
      const int j = k0 + c * 8;
      const float4* src = reinterpret_cast<const float4*>(
          OUTF + (size_t)(((((j >> 6) << 2) + (g >> 10)) << 10) | (g & 1023)) * 64 + (j & 63));
      const float4 f0 = src[0], f1 = src[1];
      uint4 o4;
      o4.x = pk2(f0.x, f0.y); o4.y = pk2(f0.z, f0.w);
      o4.z = pk2(f1.x, f1.y); o4.w = pk2(f1.z, f1.w);
      *reinterpret_cast<uint4*>(&As[swz(r, c)]) = o4;
    }
    for (int u = tid; u < 1024; u += 256) {
      const int r = u >> 3, c = u & 7;
      *reinterpret_cast<uint4*>(&Bs[swz(r, c)]) =
        *reinterpret_cast<const uint4*>(&WT[(size_t)(n0b + r) * 512 + k0 + c * 8]);
    }
    __syncthreads();
    bf16x8 a[2][2];
    #pragma unroll
    for (int mi = 0; mi < 2; ++mi) {
      const int ar = wm * 32 + mi * 16 + lr;
      a[mi][0] = ldfrag(As, ar, lg);
      a[mi][1] = ldfrag(As, ar, 4 + lg);
    }
    #pragma unroll
    for (int ni = 0; ni < 4; ++ni) {
      const int br = wn * 64 + ni * 16 + lr;
      const bf16x8 b0 = ldfrag(Bs, br, lg);
      const bf16x8 b1 = ldfrag(Bs, br, 4 + lg);
      acc[0][ni] = MFMA16(a[0][0], b0, acc[0][ni]);
      acc[0][ni] = MFMA16(a[0][1], b1, acc[0][ni]);
      acc[1][ni] = MFMA16(a[1][0], b0, acc[1][ni]);
      acc[1][ni] = MFMA16(a[1][1], b1, acc[1][ni]);
    }
  }
  #pragma unroll
  for (int mi = 0; mi < 2; ++mi) {
    #pragma unroll
    for (int ni = 0; ni < 4; ++ni) {
      const int j = n0b + wn * 64 + ni * 16 + lr;
      const float bj = bias[j];
      #pragma unroll
      for (int reg = 0; reg < 4; ++reg) {
        const int g = m0 + wm * 32 + mi * 16 + lg * 4 + reg;
        out[(size_t)g * 512 + j] = acc[mi][ni][reg] + bj;
      }
    }
  }
}

extern "C" void kernel_launch(void* const* d_in, const int* in_sizes, int n_in,
                              void* d_out, int out_size, void* d_ws, size_t ws_size,
                              hipStream_t stream) {
  (void)in_sizes; (void)n_in; (void)out_size; (void)ws_size;
  const float* q      = (const float*)d_in[0];
  const float* k      = (const float*)d_in[1];
  const float* v      = (const float*)d_in[2];
  const float* ln_g   = (const float*)d_in[3];
  const float* ln_b   = (const float*)d_in[4];
  const float* W_in   = (const float*)d_in[5];
  const float* wp_W1  = (const float*)d_in[6];
  const float* wp_b1  = (const float*)d_in[7];
  const float* wp_lng = (const float*)d_in[8];
  const float* wp_lnb = (const float*)d_in[9];
  const float* wp_W2  = (const float*)d_in[10];
  const float* wp_b2  = (const float*)d_in[11];
  const float* wp_W3  = (const float*)d_in[12];
  const float* wp_b3  = (const float*)d_in[13];
  const float* w_temp = (const float*)d_in[14];
  const float* W_out  = (const float*)d_in[15];
  const float* b_out  = (const float*)d_in[16];

  float* ws = (float*)d_ws;
  float* F    = ws;                                  // [0, 3SZ) fp32 f_q/f_k/f_v
  float* OUTF = ws + (size_t)3 * SZ;                 // [3SZ, 4SZ) fp32 attn output
  // A_bf overlaps OUTF region: lifetime k_ln -> k_gemm_proj only
  unsigned short* A_bf = (unsigned short*)(ws + (size_t)3 * SZ);  // 12288*512 ushorts
  unsigned short* BF = (unsigned short*)(ws + (size_t)4 * SZ);    // 5*SZ ushorts
  unsigned short* FVT = BF + (size_t)4 * SZ;         // V^T slice within BF
  // attn partials overlap F (dead after k_vt/k_derived): po 2*SZ, pml 64K float2
  float* po = ws;                                    // [0, 2SZ)
  float2* pml = (float2*)(ws + (size_t)2 * SZ);      // 65536 float2
  float* rowpart = ws + (size_t)2 * SZ + 131072;     // 2*3*32768 floats (over f_v, dead post-vt)
  float* AUX  = ws + (size_t)13631488;               // = 6.5*SZ
  float* sums  = AUX;                                // 4096 floats (qsum, ksum)
  float* coefs = AUX + 4096;                         // 64 floats
  double* stats = (double*)(AUX + 4160);             // 72 doubles
  unsigned short* WT = (unsigned short*)(AUX + 8192);  // 2 x 512x512 bf16 (ends AUX+270336)
  float* partial = AUX + 270336;                     // 2*32*8*64 = 32768 floats

  k_zero<<<1, 128, 0, stream>>>(stats);
  k_cvt<<<dim3(64, 2), 256, 0, stream>>>(W_in, W_out, WT);
  k_ln<<<3072, 256, 0, stream>>>(q, k, v, ln_g, ln_b, A_bf);
  k_gemm_proj<<<dim3(192, 4), 256, 0, stream>>>(A_bf, WT, F);
  k_colsum_part<<<dim3(32, 2, 8), 256, 0, stream>>>(F, partial);
  k_colsum_fin<<<16, 256, 0, stream>>>(partial, sums);
  k_derived<<<dim3(8192, 2), 256, 0, stream>>>(F, sums, BF);
  k_vt<<<dim3(16, 32), 256, 0, stream>>>(F, FVT);
  k_stats<<<dim3(16, 32, 2), 256, 0, stream>>>(BF, stats, rowpart);
  k_stats_fin<<<128, 256, 0, stream>>>(rowpart, stats);
  k_finalize<<<1, 512, 0, stream>>>(sums, stats, wp_W1, wp_b1, wp_lng, wp_lnb,
                                    wp_W2, wp_b2, wp_W3, wp_b3, w_temp, coefs);
  k_attn<<<dim3(16, 32, 2), 256, 0, stream>>>(BF, coefs, po, pml);
  k_attn_comb<<<2048, 256, 0, stream>>>(po, pml, OUTF);
  k_gemm_out<<<dim3(64, 4), 256, 0, stream>>>(OUTF, WT + 262144, b_out, (float*)d_out);
}